// Round 1
// baseline (4685.530 us; speedup 1.0000x reference)
//
#include <hip/hip_runtime.h>
#include <hip/hip_bf16.h>
#include <math.h>

#define B_ 2
#define T_ 2048
#define D_ 1024
#define H_ 16
#define NL_ 6
#define DF_ 4096
#define HD_ 64
#define M_ (B_*T_)

typedef __bf16 bf16;
typedef __attribute__((ext_vector_type(8))) __bf16 bf16x8;
typedef __attribute__((ext_vector_type(4))) float f32x4;

// ---------------- LayerNorm (row = one block of 256 threads) ----------------
template<bool OUT_BF16>
__global__ __launch_bounds__(256) void ln_kernel(const float* __restrict__ x,
        const float* __restrict__ w, const float* __restrict__ b,
        void* __restrict__ out) {
    const int row = blockIdx.x;
    const int t = threadIdx.x;
    const float4 xv = *(const float4*)(x + (long)row * D_ + t * 4);
    float s  = xv.x + xv.y + xv.z + xv.w;
    float sq = xv.x*xv.x + xv.y*xv.y + xv.z*xv.z + xv.w*xv.w;
    #pragma unroll
    for (int m = 32; m; m >>= 1) { s += __shfl_xor(s, m); sq += __shfl_xor(sq, m); }
    __shared__ float red[8];
    const int wid = t >> 6, lid = t & 63;
    if (lid == 0) { red[wid] = s; red[wid + 4] = sq; }
    __syncthreads();
    s  = red[0] + red[1] + red[2] + red[3];
    sq = red[4] + red[5] + red[6] + red[7];
    const float mu   = s * (1.0f / D_);
    const float var  = sq * (1.0f / D_) - mu * mu;
    const float rstd = rsqrtf(var + 1e-5f);
    const float4 wv = *(const float4*)(w + t * 4);
    const float4 bv = *(const float4*)(b + t * 4);
    float o0 = (xv.x - mu) * rstd * wv.x + bv.x;
    float o1 = (xv.y - mu) * rstd * wv.y + bv.y;
    float o2 = (xv.z - mu) * rstd * wv.z + bv.z;
    float o3 = (xv.w - mu) * rstd * wv.w + bv.w;
    if (OUT_BF16) {
        bf16* o = (bf16*)out + (long)row * D_ + t * 4;
        o[0] = (bf16)o0; o[1] = (bf16)o1; o[2] = (bf16)o2; o[3] = (bf16)o3;
    } else {
        float* o = (float*)out + (long)row * D_ + t * 4;
        o[0] = o0; o[1] = o1; o[2] = o2; o[3] = o3;
    }
}

// ---------------- GEMM: C[M,N] = A[M,K](bf16) @ W[K,N](f32) + bias ----------------
enum { EPI_BF16 = 0, EPI_VT = 1, EPI_F32 = 2, EPI_SIG = 3, EPI_GELU = 4 };

template<int EPI>
__global__ __launch_bounds__(256) void gemm_kernel(const bf16* __restrict__ A,
        const float* __restrict__ W, const float* __restrict__ bias,
        void* __restrict__ out, int K, int N) {
    __shared__ bf16 sA[128][40];   // [m][k], +8 pad
    __shared__ bf16 sB[128][40];   // [n][k], transposed W tile
    const int tid  = threadIdx.x;
    const int m0   = blockIdx.y * 128, n0 = blockIdx.x * 128;
    const int lane = tid & 63, w = tid >> 6;
    const int wr = (w >> 1) * 64, wc = (w & 1) * 64;
    const int cl = lane & 15, gl = lane >> 4;

    f32x4 acc[4][4];
    #pragma unroll
    for (int i = 0; i < 4; i++)
        #pragma unroll
        for (int j = 0; j < 4; j++) acc[i][j] = (f32x4){0.f, 0.f, 0.f, 0.f};

    const int arow = tid >> 1,  akb = (tid & 1) * 16;
    const int bcol = tid & 127, bkb = (tid >> 7) * 16;

    for (int k0 = 0; k0 < K; k0 += 32) {
        __syncthreads();
        { // stage A tile (bf16 -> LDS direct)
            const bf16* src = A + (long)(m0 + arow) * K + k0 + akb;
            uint4 v0 = *(const uint4*)(src);
            uint4 v1 = *(const uint4*)(src + 8);
            *(uint4*)&sA[arow][akb]     = v0;
            *(uint4*)&sA[arow][akb + 8] = v1;
        }
        { // stage W tile: column strip, fp32 -> bf16, store transposed [n][k]
            const float* src = W + (long)(k0 + bkb) * N + n0 + bcol;
            bf16 tmp[16] __attribute__((aligned(16)));
            #pragma unroll
            for (int e = 0; e < 16; e++) tmp[e] = (bf16)src[(long)e * N];
            *(uint4*)&sB[bcol][bkb]     = *(uint4*)&tmp[0];
            *(uint4*)&sB[bcol][bkb + 8] = *(uint4*)&tmp[8];
        }
        __syncthreads();
        bf16x8 af[4], bfr[4];
        #pragma unroll
        for (int i = 0; i < 4; i++) af[i]  = *(const bf16x8*)&sA[wr + i*16 + cl][8 * gl];
        #pragma unroll
        for (int j = 0; j < 4; j++) bfr[j] = *(const bf16x8*)&sB[wc + j*16 + cl][8 * gl];
        #pragma unroll
        for (int i = 0; i < 4; i++)
            #pragma unroll
            for (int j = 0; j < 4; j++)
                acc[i][j] = __builtin_amdgcn_mfma_f32_16x16x32_bf16(af[i], bfr[j], acc[i][j], 0, 0, 0);
    }

    #pragma unroll
    for (int i = 0; i < 4; i++) {
        #pragma unroll
        for (int j = 0; j < 4; j++) {
            const int gcol = n0 + wc + j * 16 + cl;
            const float bv = bias[gcol];
            #pragma unroll
            for (int r = 0; r < 4; r++) {
                const int grow = m0 + wr + i * 16 + gl * 4 + r;
                float v = acc[i][j][r] + bv;
                if (EPI == EPI_SIG)  v = 1.0f / (1.0f + __expf(-v));
                if (EPI == EPI_GELU) v = 0.5f * v * (1.0f + erff(v * 0.70710678118f));
                if (EPI == EPI_F32 || EPI == EPI_SIG) {
                    ((float*)out)[(long)grow * N + gcol] = v;
                } else if (EPI == EPI_VT) {
                    // v[m][n] -> vT[b][n][t]   (b = m>>11, t = m&2047)
                    ((bf16*)out)[((long)(grow >> 11) * N + gcol) * T_ + (grow & 2047)] = (bf16)v;
                } else {
                    ((bf16*)out)[(long)grow * N + gcol] = (bf16)v;
                }
            }
        }
    }
}

// ---------------- Flash attention: 1 wave per (b,h,16-row q tile) ----------------
__global__ __launch_bounds__(64) void attn_kernel(const bf16* __restrict__ q,
        const bf16* __restrict__ k, const bf16* __restrict__ vT,
        bf16* __restrict__ y) {
    const int lane = threadIdx.x;
    const int cl = lane & 15, gl = lane >> 4;
    const int qb = blockIdx.x * 16;
    const int bh = blockIdx.y, b = bh >> 4, h = bh & 15;
    const bf16* qB = q  + (long)b * T_ * D_ + h * HD_;
    const bf16* kB = k  + (long)b * T_ * D_ + h * HD_;
    const bf16* vB = vT + (long)b * D_ * T_ + (long)h * HD_ * T_;

    __shared__ bf16 P[16][40];

    bf16x8 qf[2];
    #pragma unroll
    for (int c = 0; c < 2; c++)
        qf[c] = *(const bf16x8*)(qB + (long)(qb + cl) * D_ + c * 32 + 8 * gl);

    f32x4 o[4];
    #pragma unroll
    for (int dt = 0; dt < 4; dt++) o[dt] = (f32x4){0.f, 0.f, 0.f, 0.f};
    float mrow[4], lrow[4];
    #pragma unroll
    for (int r = 0; r < 4; r++) { mrow[r] = -INFINITY; lrow[r] = 0.f; }

    const int ntiles = (qb + 16 + 31) >> 5;
    for (int j = 0; j < ntiles; j++) {
        const int kvb = j << 5;
        const bool need_mask = (kvb + 31 > qb);
        f32x4 s[2];
        s[0] = (f32x4){0.f,0.f,0.f,0.f}; s[1] = (f32x4){0.f,0.f,0.f,0.f};
        #pragma unroll
        for (int t = 0; t < 2; t++)
            #pragma unroll
            for (int c = 0; c < 2; c++) {
                bf16x8 kf = *(const bf16x8*)(kB + (long)(kvb + 16*t + cl) * D_ + c * 32 + 8 * gl);
                s[t] = __builtin_amdgcn_mfma_f32_16x16x32_bf16(qf[c], kf, s[t], 0, 0, 0);
            }
        float p0[4], p1[4], tmax[4];
        #pragma unroll
        for (int r = 0; r < 4; r++) {
            float a  = s[0][r] * 0.125f;
            float bb = s[1][r] * 0.125f;
            if (need_mask) {
                const int qrow = qb + gl * 4 + r;
                if (kvb + cl > qrow)       a  = -3.0e38f;
                if (kvb + 16 + cl > qrow)  bb = -3.0e38f;
            }
            p0[r] = a; p1[r] = bb;
            tmax[r] = fmaxf(a, bb);
        }
        #pragma unroll
        for (int m = 1; m < 16; m <<= 1)
            #pragma unroll
            for (int r = 0; r < 4; r++) tmax[r] = fmaxf(tmax[r], __shfl_xor(tmax[r], m));
        float alpha[4];
        #pragma unroll
        for (int r = 0; r < 4; r++) {
            const float mn = fmaxf(mrow[r], tmax[r]);
            alpha[r] = __expf(mrow[r] - mn);
            mrow[r] = mn;
            p0[r] = __expf(p0[r] - mn);
            p1[r] = __expf(p1[r] - mn);
        }
        float tsum[4];
        #pragma unroll
        for (int r = 0; r < 4; r++) tsum[r] = p0[r] + p1[r];
        #pragma unroll
        for (int m = 1; m < 16; m <<= 1)
            #pragma unroll
            for (int r = 0; r < 4; r++) tsum[r] += __shfl_xor(tsum[r], m);
        #pragma unroll
        for (int r = 0; r < 4; r++) lrow[r] = lrow[r] * alpha[r] + tsum[r];
        #pragma unroll
        for (int dt = 0; dt < 4; dt++)
            #pragma unroll
            for (int r = 0; r < 4; r++) o[dt][r] *= alpha[r];

        __syncthreads();   // protect previous iteration's P reads
        #pragma unroll
        for (int r = 0; r < 4; r++) {
            P[gl * 4 + r][cl]      = (bf16)p0[r];
            P[gl * 4 + r][16 + cl] = (bf16)p1[r];
        }
        __syncthreads();
        bf16x8 pa = *(const bf16x8*)&P[cl][8 * gl];
        #pragma unroll
        for (int dt = 0; dt < 4; dt++) {
            bf16x8 vf = *(const bf16x8*)(vB + (long)(dt * 16 + cl) * T_ + kvb + 8 * gl);
            o[dt] = __builtin_amdgcn_mfma_f32_16x16x32_bf16(pa, vf, o[dt], 0, 0, 0);
        }
    }
    #pragma unroll
    for (int dt = 0; dt < 4; dt++)
        #pragma unroll
        for (int r = 0; r < 4; r++) {
            const float v = o[dt][r] / lrow[r];
            y[(long)(b * T_ + qb + gl * 4 + r) * D_ + h * HD_ + dt * 16 + cl] = (bf16)v;
        }
}

// ---------------- gates ----------------
__global__ __launch_bounds__(256) void gate1_kernel(float* __restrict__ x,
        const float* __restrict__ z, const float* __restrict__ r,
        const float* __restrict__ xa) {
    const long i = ((long)blockIdx.x * 256 + threadIdx.x) * 4;
    float4 xv = *(const float4*)(x + i);
    const float4 zv = *(const float4*)(z + i);
    const float4 rv = *(const float4*)(r + i);
    const float4 av = *(const float4*)(xa + i);
    xv.x = (1.f - zv.x) * xv.x + zv.x * tanhf(rv.x * av.x);
    xv.y = (1.f - zv.y) * xv.y + zv.y * tanhf(rv.y * av.y);
    xv.z = (1.f - zv.z) * xv.z + zv.z * tanhf(rv.z * av.z);
    xv.w = (1.f - zv.w) * xv.w + zv.w * tanhf(rv.w * av.w);
    *(float4*)(x + i) = xv;
}

__global__ __launch_bounds__(256) void gate2_kernel(float* __restrict__ x,
        const float* __restrict__ z, const float* __restrict__ m,
        const float* __restrict__ src) {
    const long i = ((long)blockIdx.x * 256 + threadIdx.x) * 4;
    float4 xv = *(const float4*)(x + i);
    const float4 zv = *(const float4*)(z + i);
    const float4 mv = *(const float4*)(m + i);
    const float4 sv = *(const float4*)(src + i);
    xv.x = (1.f - zv.x) * xv.x + zv.x * mv.x + sv.x;
    xv.y = (1.f - zv.y) * xv.y + zv.y * mv.y + sv.y;
    xv.z = (1.f - zv.z) * xv.z + zv.z * mv.z + sv.z;
    xv.w = (1.f - zv.w) * xv.w + zv.w * mv.w + sv.w;
    *(float4*)(x + i) = xv;
}

extern "C" void kernel_launch(void* const* d_in, const int* in_sizes, int n_in,
                              void* d_out, int out_size, void* d_ws, size_t ws_size,
                              hipStream_t stream) {
    const float* seq   = (const float*)d_in[0];
    const float* Wq    = (const float*)d_in[1];  const float* bq = (const float*)d_in[2];
    const float* Wk    = (const float*)d_in[3];  const float* bk = (const float*)d_in[4];
    const float* Wv    = (const float*)d_in[5];  const float* bv = (const float*)d_in[6];
    const float* Wo    = (const float*)d_in[7];  const float* bo = (const float*)d_in[8];
    const float* Wz    = (const float*)d_in[9];  const float* bz = (const float*)d_in[10];
    const float* Wr    = (const float*)d_in[11]; const float* br = (const float*)d_in[12];
    const float* W1    = (const float*)d_in[13]; const float* b1 = (const float*)d_in[14];
    const float* W2    = (const float*)d_in[15]; const float* b2 = (const float*)d_in[16];
    const float* ln1w  = (const float*)d_in[17]; const float* ln1b = (const float*)d_in[18];
    const float* ln2w  = (const float*)d_in[19]; const float* ln2b = (const float*)d_in[20];
    const float* lnfw  = (const float*)d_in[21]; const float* lnfb = (const float*)d_in[22];

    char* ws = (char*)d_ws;
    float* x   = (float*)(ws);                       // 16 MB
    float* z   = (float*)(ws + ((size_t)16 << 20));  // 16 MB
    float* r   = (float*)(ws + ((size_t)32 << 20));  // 16 MB
    float* xa  = (float*)(ws + ((size_t)48 << 20));  // 16 MB (x_attn / mlp)
    bf16*  xn  = (bf16*)(ws + ((size_t)64 << 20));   // 8 MB  (xn / xm)
    bf16*  qb_ = (bf16*)(ws + ((size_t)72 << 20));   // 8 MB
    bf16*  kb_ = (bf16*)(ws + ((size_t)80 << 20));   // 8 MB
    bf16*  vtb = (bf16*)(ws + ((size_t)88 << 20));   // 8 MB (V transposed)
    bf16*  yb  = (bf16*)(ws + ((size_t)96 << 20));   // 8 MB (attn out)
    bf16*  h1  = (bf16*)(ws + ((size_t)104 << 20));  // 32 MB (MLP hidden)

    hipMemcpyAsync(x, seq, (size_t)M_ * D_ * 4, hipMemcpyDeviceToDevice, stream);

    const dim3 gDD(D_ / 128, M_ / 128);   // (8, 32)
    const dim3 gDF(DF_ / 128, M_ / 128);  // (32, 32)

    for (int i = 0; i < NL_; i++) {
        const long dd = (long)i * D_ * D_;
        ln_kernel<true><<<M_, 256, 0, stream>>>(x, ln1w + i * D_, ln1b + i * D_, xn);
        gemm_kernel<EPI_BF16><<<gDD, 256, 0, stream>>>(xn, Wq + dd, bq + i * D_, qb_, D_, D_);
        gemm_kernel<EPI_BF16><<<gDD, 256, 0, stream>>>(xn, Wk + dd, bk + i * D_, kb_, D_, D_);
        gemm_kernel<EPI_VT  ><<<gDD, 256, 0, stream>>>(xn, Wv + dd, bv + i * D_, vtb, D_, D_);
        gemm_kernel<EPI_SIG ><<<gDD, 256, 0, stream>>>(xn, Wz + dd, bz + i * D_, z,  D_, D_);
        gemm_kernel<EPI_SIG ><<<gDD, 256, 0, stream>>>(xn, Wr + dd, br + i * D_, r,  D_, D_);
        attn_kernel<<<dim3(T_ / 16, B_ * H_), 64, 0, stream>>>(qb_, kb_, vtb, yb);
        gemm_kernel<EPI_F32 ><<<gDD, 256, 0, stream>>>(yb, Wo + dd, bo + i * D_, xa, D_, D_);
        gate1_kernel<<<(M_ * D_) / 1024, 256, 0, stream>>>(x, z, r, xa);
        ln_kernel<true><<<M_, 256, 0, stream>>>(x, ln2w + i * D_, ln2b + i * D_, xn);
        gemm_kernel<EPI_GELU><<<gDF, 256, 0, stream>>>(xn, W1 + (long)i * D_ * DF_, b1 + i * DF_, h1, D_, DF_);
        gemm_kernel<EPI_F32 ><<<gDD, 256, 0, stream>>>(h1, W2 + (long)i * DF_ * D_, b2 + i * D_, xa, DF_, D_);
        gate2_kernel<<<(M_ * D_) / 1024, 256, 0, stream>>>(x, z, xa, seq);
    }
    ln_kernel<false><<<M_, 256, 0, stream>>>(x, lnfw, lnfb, d_out);
}

// Round 2
// 2994.632 us; speedup vs baseline: 1.5646x; 1.5646x over previous
//
#include <hip/hip_runtime.h>
#include <hip/hip_bf16.h>
#include <math.h>

#define B_ 2
#define T_ 2048
#define D_ 1024
#define H_ 16
#define NL_ 6
#define DF_ 4096
#define HD_ 64
#define M_ (B_*T_)

typedef __bf16 bf16;
typedef __attribute__((ext_vector_type(8))) __bf16 bf16x8;
typedef __attribute__((ext_vector_type(4))) float f32x4;

__device__ __forceinline__ void gload_lds16(const void* g, void* l) {
    __builtin_amdgcn_global_load_lds((const __attribute__((address_space(1))) void*)g,
                                     (__attribute__((address_space(3))) void*)l, 16, 0, 0);
}

// ---------------- LayerNorm ----------------
template<bool OUT_BF16>
__global__ __launch_bounds__(256) void ln_kernel(const float* __restrict__ x,
        const float* __restrict__ w, const float* __restrict__ b,
        void* __restrict__ out) {
    const int row = blockIdx.x;
    const int t = threadIdx.x;
    const float4 xv = *(const float4*)(x + (long)row * D_ + t * 4);
    float s  = xv.x + xv.y + xv.z + xv.w;
    float sq = xv.x*xv.x + xv.y*xv.y + xv.z*xv.z + xv.w*xv.w;
    #pragma unroll
    for (int m = 32; m; m >>= 1) { s += __shfl_xor(s, m); sq += __shfl_xor(sq, m); }
    __shared__ float red[8];
    const int wid = t >> 6, lid = t & 63;
    if (lid == 0) { red[wid] = s; red[wid + 4] = sq; }
    __syncthreads();
    s  = red[0] + red[1] + red[2] + red[3];
    sq = red[4] + red[5] + red[6] + red[7];
    const float mu   = s * (1.0f / D_);
    const float var  = sq * (1.0f / D_) - mu * mu;
    const float rstd = rsqrtf(var + 1e-5f);
    const float4 wv = *(const float4*)(w + t * 4);
    const float4 bv = *(const float4*)(b + t * 4);
    float o0 = (xv.x - mu) * rstd * wv.x + bv.x;
    float o1 = (xv.y - mu) * rstd * wv.y + bv.y;
    float o2 = (xv.z - mu) * rstd * wv.z + bv.z;
    float o3 = (xv.w - mu) * rstd * wv.w + bv.w;
    if (OUT_BF16) {
        bf16* o = (bf16*)out + (long)row * D_ + t * 4;
        o[0] = (bf16)o0; o[1] = (bf16)o1; o[2] = (bf16)o2; o[3] = (bf16)o3;
    } else {
        float* o = (float*)out + (long)row * D_ + t * 4;
        o[0] = o0; o[1] = o1; o[2] = o2; o[3] = o3;
    }
}

// ---------------- weight convert+transpose: W[K,N] f32 -> WT[N,K] bf16 ----------------
__global__ __launch_bounds__(256) void wconv_kernel(const float* __restrict__ W,
        bf16* __restrict__ WT, int K, int N) {
    __shared__ float s[32][33];
    const int k0 = blockIdx.y * 32, n0 = blockIdx.x * 32;
    const int c = threadIdx.x & 31, r8 = threadIdx.x >> 5;
    #pragma unroll
    for (int it = 0; it < 4; it++)
        s[r8 + it*8][c] = W[(long)(k0 + r8 + it*8) * N + n0 + c];
    __syncthreads();
    #pragma unroll
    for (int it = 0; it < 4; it++)
        WT[(long)(n0 + r8 + it*8) * K + k0 + c] = (bf16)s[c][r8 + it*8];
}

// ---------------- GEMM: C[M,N] = A[M,K](bf16) @ WT[N,K](bf16)^T + bias ----------------
enum { EPI_BF16 = 0, EPI_VT = 1, EPI_F32 = 2, EPI_SIG = 3, EPI_GELU = 4 };

template<int EPI>
__global__ __launch_bounds__(256) void gemm_kernel(const bf16* __restrict__ A,
        const bf16* __restrict__ Bt, const float* __restrict__ bias,
        void* __restrict__ out, int K, int N, int gx) {
    __shared__ bf16 sA[128 * 32];
    __shared__ bf16 sB[128 * 32];
    const int tid = threadIdx.x;
    const int nwg = gridDim.x;
    int bid = blockIdx.x;
    bid = (bid & 7) * (nwg >> 3) + (bid >> 3);          // bijective XCD swizzle (nwg%8==0)
    const int m0 = (bid / gx) * 128, n0 = (bid % gx) * 128;
    const int lane = tid & 63, w = tid >> 6;
    const int wr = (w >> 1) * 64, wc = (w & 1) * 64;
    const int cl = lane & 15, gl = lane >> 4;

    f32x4 acc[4][4];
    #pragma unroll
    for (int i = 0; i < 4; i++)
        #pragma unroll
        for (int j = 0; j < 4; j++) acc[i][j] = (f32x4){0.f, 0.f, 0.f, 0.f};

    // staging: thread t covers 16B at LDS byte t*16 (row = t>>2, kelem = (t&3)*8)
    const int srow = tid >> 2, skoff = (tid & 3) * 8;
    const bf16* ga = A  + (long)(m0 + srow) * K + skoff;
    const bf16* gb = Bt + (long)(n0 + srow) * K + skoff;
    char* sAc = (char*)sA;
    char* sBc = (char*)sB;
    const int wb = w * 1024;   // wave-uniform LDS base offset

    for (int k0 = 0; k0 < K; k0 += 32) {
        if (k0) __syncthreads();
        gload_lds16(ga + k0,            sAc + wb);
        gload_lds16(ga + 64 * K + k0,   sAc + 4096 + wb);
        gload_lds16(gb + k0,            sBc + wb);
        gload_lds16(gb + 64 * K + k0,   sBc + 4096 + wb);
        __syncthreads();
        bf16x8 af[4], bfr[4];
        #pragma unroll
        for (int i = 0; i < 4; i++) af[i]  = *(const bf16x8*)(sA + (wr + i*16 + cl) * 32 + 8 * gl);
        #pragma unroll
        for (int j = 0; j < 4; j++) bfr[j] = *(const bf16x8*)(sB + (wc + j*16 + cl) * 32 + 8 * gl);
        #pragma unroll
        for (int i = 0; i < 4; i++)
            #pragma unroll
            for (int j = 0; j < 4; j++)
                acc[i][j] = __builtin_amdgcn_mfma_f32_16x16x32_bf16(af[i], bfr[j], acc[i][j], 0, 0, 0);
    }

    #pragma unroll
    for (int i = 0; i < 4; i++) {
        #pragma unroll
        for (int j = 0; j < 4; j++) {
            const int gcol = n0 + wc + j * 16 + cl;
            const float bv = bias[gcol];
            #pragma unroll
            for (int r = 0; r < 4; r++) {
                const int grow = m0 + wr + i * 16 + gl * 4 + r;
                float v = acc[i][j][r] + bv;
                if (EPI == EPI_SIG)  v = 1.0f / (1.0f + __expf(-v));
                if (EPI == EPI_GELU) v = 0.5f * v * (1.0f + erff(v * 0.70710678118f));
                if (EPI == EPI_F32 || EPI == EPI_SIG) {
                    ((float*)out)[(long)grow * N + gcol] = v;
                } else if (EPI == EPI_VT) {
                    ((bf16*)out)[((long)(grow >> 11) * N + gcol) * T_ + (grow & 2047)] = (bf16)v;
                } else {
                    ((bf16*)out)[(long)grow * N + gcol] = (bf16)v;
                }
            }
        }
    }
}

// ---------------- Flash attention: 4 waves/block, 1 wave per 16-row q tile ----------------
__global__ __launch_bounds__(256) void attn_kernel(const bf16* __restrict__ q,
        const bf16* __restrict__ k, const bf16* __restrict__ vT,
        bf16* __restrict__ y) {
    __shared__ bf16 P[4][16][40];
    const int tid = threadIdx.x, wid = tid >> 6, lane = tid & 63;
    const int cl = lane & 15, gl = lane >> 4;
    // block mapping: xcd-affine per bh, longest q-groups dispatched first
    const int x = blockIdx.x;
    const int xcd = x & 7, j = x >> 3;
    const int bh = xcd + 8 * (j & 3);
    const int g  = 31 - (j >> 2);
    const int qb = (g * 4 + wid) * 16;
    const int b = bh >> 4, h = bh & 15;

    const bf16* qB = q  + (long)b * T_ * D_ + h * HD_;
    const bf16* kB = k  + (long)b * T_ * D_ + h * HD_;
    const bf16* vB = vT + (long)b * D_ * T_ + (long)h * HD_ * T_;

    bf16x8 qf[2];
    #pragma unroll
    for (int c = 0; c < 2; c++)
        qf[c] = *(const bf16x8*)(qB + (long)(qb + cl) * D_ + c * 32 + 8 * gl);

    f32x4 o[4];
    #pragma unroll
    for (int dt = 0; dt < 4; dt++) o[dt] = (f32x4){0.f, 0.f, 0.f, 0.f};
    float mrow[4], lrow[4];
    #pragma unroll
    for (int r = 0; r < 4; r++) { mrow[r] = -INFINITY; lrow[r] = 0.f; }

    const int ntiles = (qb + 16 + 31) >> 5;
    for (int jj = 0; jj < ntiles; jj++) {
        const int kvb = jj << 5;
        const bool need_mask = (kvb + 31 > qb);
        f32x4 s[2];
        s[0] = (f32x4){0.f,0.f,0.f,0.f}; s[1] = (f32x4){0.f,0.f,0.f,0.f};
        #pragma unroll
        for (int t = 0; t < 2; t++)
            #pragma unroll
            for (int c = 0; c < 2; c++) {
                bf16x8 kf = *(const bf16x8*)(kB + (long)(kvb + 16*t + cl) * D_ + c * 32 + 8 * gl);
                s[t] = __builtin_amdgcn_mfma_f32_16x16x32_bf16(qf[c], kf, s[t], 0, 0, 0);
            }
        float p0[4], p1[4], tmax[4];
        #pragma unroll
        for (int r = 0; r < 4; r++) {
            float a  = s[0][r] * 0.125f;
            float bb = s[1][r] * 0.125f;
            if (need_mask) {
                const int qrow = qb + gl * 4 + r;
                if (kvb + cl > qrow)       a  = -3.0e38f;
                if (kvb + 16 + cl > qrow)  bb = -3.0e38f;
            }
            p0[r] = a; p1[r] = bb;
            tmax[r] = fmaxf(a, bb);
        }
        #pragma unroll
        for (int m = 1; m < 16; m <<= 1)
            #pragma unroll
            for (int r = 0; r < 4; r++) tmax[r] = fmaxf(tmax[r], __shfl_xor(tmax[r], m));
        float alpha[4];
        #pragma unroll
        for (int r = 0; r < 4; r++) {
            const float mn = fmaxf(mrow[r], tmax[r]);
            alpha[r] = __expf(mrow[r] - mn);
            mrow[r] = mn;
            p0[r] = __expf(p0[r] - mn);
            p1[r] = __expf(p1[r] - mn);
        }
        float tsum[4];
        #pragma unroll
        for (int r = 0; r < 4; r++) tsum[r] = p0[r] + p1[r];
        #pragma unroll
        for (int m = 1; m < 16; m <<= 1)
            #pragma unroll
            for (int r = 0; r < 4; r++) tsum[r] += __shfl_xor(tsum[r], m);
        #pragma unroll
        for (int r = 0; r < 4; r++) lrow[r] = lrow[r] * alpha[r] + tsum[r];
        #pragma unroll
        for (int dt = 0; dt < 4; dt++)
            #pragma unroll
            for (int r = 0; r < 4; r++) o[dt][r] *= alpha[r];

        __asm__ __volatile__("" ::: "memory");   // keep P writes/reads ordered (same-wave DS is in-order)
        #pragma unroll
        for (int r = 0; r < 4; r++) {
            P[wid][gl * 4 + r][cl]      = (bf16)p0[r];
            P[wid][gl * 4 + r][16 + cl] = (bf16)p1[r];
        }
        __asm__ __volatile__("" ::: "memory");
        bf16x8 pa = *(const bf16x8*)&P[wid][cl][8 * gl];
        #pragma unroll
        for (int dt = 0; dt < 4; dt++) {
            bf16x8 vf = *(const bf16x8*)(vB + (long)(dt * 16 + cl) * T_ + kvb + 8 * gl);
            o[dt] = __builtin_amdgcn_mfma_f32_16x16x32_bf16(pa, vf, o[dt], 0, 0, 0);
        }
    }
    #pragma unroll
    for (int dt = 0; dt < 4; dt++)
        #pragma unroll
        for (int r = 0; r < 4; r++) {
            const float v = o[dt][r] / lrow[r];
            y[(long)(b * T_ + qb + gl * 4 + r) * D_ + h * HD_ + dt * 16 + cl] = (bf16)v;
        }
}

// ---------------- gates ----------------
__global__ __launch_bounds__(256) void gate1_kernel(float* __restrict__ x,
        const float* __restrict__ z, const float* __restrict__ r,
        const float* __restrict__ xa) {
    const long i = ((long)blockIdx.x * 256 + threadIdx.x) * 4;
    float4 xv = *(const float4*)(x + i);
    const float4 zv = *(const float4*)(z + i);
    const float4 rv = *(const float4*)(r + i);
    const float4 av = *(const float4*)(xa + i);
    xv.x = (1.f - zv.x) * xv.x + zv.x * tanhf(rv.x * av.x);
    xv.y = (1.f - zv.y) * xv.y + zv.y * tanhf(rv.y * av.y);
    xv.z = (1.f - zv.z) * xv.z + zv.z * tanhf(rv.z * av.z);
    xv.w = (1.f - zv.w) * xv.w + zv.w * tanhf(rv.w * av.w);
    *(float4*)(x + i) = xv;
}

__global__ __launch_bounds__(256) void gate2_kernel(float* __restrict__ x,
        const float* __restrict__ z, const float* __restrict__ m,
        const float* __restrict__ src) {
    const long i = ((long)blockIdx.x * 256 + threadIdx.x) * 4;
    float4 xv = *(const float4*)(x + i);
    const float4 zv = *(const float4*)(z + i);
    const float4 mv = *(const float4*)(m + i);
    const float4 sv = *(const float4*)(src + i);
    xv.x = (1.f - zv.x) * xv.x + zv.x * mv.x + sv.x;
    xv.y = (1.f - zv.y) * xv.y + zv.y * mv.y + sv.y;
    xv.z = (1.f - zv.z) * xv.z + zv.z * mv.z + sv.z;
    xv.w = (1.f - zv.w) * xv.w + zv.w * mv.w + sv.w;
    *(float4*)(x + i) = xv;
}

extern "C" void kernel_launch(void* const* d_in, const int* in_sizes, int n_in,
                              void* d_out, int out_size, void* d_ws, size_t ws_size,
                              hipStream_t stream) {
    const float* seq   = (const float*)d_in[0];
    const float* Wq    = (const float*)d_in[1];  const float* bq = (const float*)d_in[2];
    const float* Wk    = (const float*)d_in[3];  const float* bk = (const float*)d_in[4];
    const float* Wv    = (const float*)d_in[5];  const float* bv = (const float*)d_in[6];
    const float* Wo    = (const float*)d_in[7];  const float* bo = (const float*)d_in[8];
    const float* Wz    = (const float*)d_in[9];  const float* bz = (const float*)d_in[10];
    const float* Wr    = (const float*)d_in[11]; const float* br = (const float*)d_in[12];
    const float* W1    = (const float*)d_in[13]; const float* b1 = (const float*)d_in[14];
    const float* W2    = (const float*)d_in[15]; const float* b2 = (const float*)d_in[16];
    const float* ln1w  = (const float*)d_in[17]; const float* ln1b = (const float*)d_in[18];
    const float* ln2w  = (const float*)d_in[19]; const float* ln2b = (const float*)d_in[20];
    const float* lnfw  = (const float*)d_in[21]; const float* lnfb = (const float*)d_in[22];

    char* ws = (char*)d_ws;
    float* x   = (float*)(ws);                       // 16 MB
    float* z   = (float*)(ws + ((size_t)16 << 20));  // 16 MB
    float* r   = (float*)(ws + ((size_t)32 << 20));  // 16 MB
    float* xa  = (float*)(ws + ((size_t)48 << 20));  // 16 MB
    bf16*  xn  = (bf16*)(ws + ((size_t)64 << 20));   // 8 MB
    bf16*  qb_ = (bf16*)(ws + ((size_t)72 << 20));   // 8 MB
    bf16*  kb_ = (bf16*)(ws + ((size_t)80 << 20));   // 8 MB
    bf16*  vtb = (bf16*)(ws + ((size_t)88 << 20));   // 8 MB
    bf16*  yb  = (bf16*)(ws + ((size_t)96 << 20));   // 8 MB
    bf16*  h1  = (bf16*)(ws + ((size_t)104 << 20));  // 32 MB
    bf16*  wt  = (bf16*)(ws + ((size_t)136 << 20));  // 30 MB (per-layer WT pool)

    bf16* wtq = wt;                 // [D][D]
    bf16* wtk = wt + (1u << 20);
    bf16* wtv = wt + (2u << 20);
    bf16* wtz = wt + (3u << 20);
    bf16* wtr = wt + (4u << 20);
    bf16* wto = wt + (5u << 20);
    bf16* wt1 = wt + (6u << 20);    // [DF][D]
    bf16* wt2 = wt + (10u << 20);   // [D][DF]

    hipMemcpyAsync(x, seq, (size_t)M_ * D_ * 4, hipMemcpyDeviceToDevice, stream);

    const int gDDn = (M_ / 128) * (D_ / 128);    // 256
    const int gDFn = (M_ / 128) * (DF_ / 128);   // 1024
    const dim3 cDD(D_ / 32, D_ / 32);            // (32,32)
    const dim3 cDF(DF_ / 32, D_ / 32);           // (128,32)
    const dim3 cFD(D_ / 32, DF_ / 32);           // (32,128)

    for (int i = 0; i < NL_; i++) {
        const long dd = (long)i * D_ * D_;
        // convert this layer's weights
        wconv_kernel<<<cDD, 256, 0, stream>>>(Wq + dd, wtq, D_, D_);
        wconv_kernel<<<cDD, 256, 0, stream>>>(Wk + dd, wtk, D_, D_);
        wconv_kernel<<<cDD, 256, 0, stream>>>(Wv + dd, wtv, D_, D_);
        wconv_kernel<<<cDD, 256, 0, stream>>>(Wz + dd, wtz, D_, D_);
        wconv_kernel<<<cDD, 256, 0, stream>>>(Wr + dd, wtr, D_, D_);
        wconv_kernel<<<cDD, 256, 0, stream>>>(Wo + dd, wto, D_, D_);
        wconv_kernel<<<cDF, 256, 0, stream>>>(W1 + (long)i * D_ * DF_, wt1, D_, DF_);
        wconv_kernel<<<cFD, 256, 0, stream>>>(W2 + (long)i * DF_ * D_, wt2, DF_, D_);

        ln_kernel<true><<<M_, 256, 0, stream>>>(x, ln1w + i * D_, ln1b + i * D_, xn);
        gemm_kernel<EPI_BF16><<<gDDn, 256, 0, stream>>>(xn, wtq, bq + i * D_, qb_, D_, D_, D_/128);
        gemm_kernel<EPI_BF16><<<gDDn, 256, 0, stream>>>(xn, wtk, bk + i * D_, kb_, D_, D_, D_/128);
        gemm_kernel<EPI_VT  ><<<gDDn, 256, 0, stream>>>(xn, wtv, bv + i * D_, vtb, D_, D_, D_/128);
        gemm_kernel<EPI_SIG ><<<gDDn, 256, 0, stream>>>(xn, wtz, bz + i * D_, z,  D_, D_, D_/128);
        gemm_kernel<EPI_SIG ><<<gDDn, 256, 0, stream>>>(xn, wtr, br + i * D_, r,  D_, D_, D_/128);
        attn_kernel<<<1024, 256, 0, stream>>>(qb_, kb_, vtb, yb);
        gemm_kernel<EPI_F32 ><<<gDDn, 256, 0, stream>>>(yb, wto, bo + i * D_, xa, D_, D_, D_/128);
        gate1_kernel<<<(M_ * D_) / 1024, 256, 0, stream>>>(x, z, r, xa);
        ln_kernel<true><<<M_, 256, 0, stream>>>(x, ln2w + i * D_, ln2b + i * D_, xn);
        gemm_kernel<EPI_GELU><<<gDFn, 256, 0, stream>>>(xn, wt1, b1 + i * DF_, h1, D_, DF_, DF_/128);
        gemm_kernel<EPI_F32 ><<<gDDn, 256, 0, stream>>>(h1, wt2, b2 + i * D_, xa, DF_, D_, D_/128);
        gate2_kernel<<<(M_ * D_) / 1024, 256, 0, stream>>>(x, z, xa, seq);
    }
    ln_kernel<false><<<M_, 256, 0, stream>>>(x, lnfw, lnfb, d_out);
}

// Round 3
// 2250.976 us; speedup vs baseline: 2.0816x; 1.3304x over previous
//
#include <hip/hip_runtime.h>
#include <hip/hip_bf16.h>
#include <math.h>

#define B_ 2
#define T_ 2048
#define D_ 1024
#define H_ 16
#define NL_ 6
#define DF_ 4096
#define HD_ 64
#define M_ (B_*T_)

typedef __bf16 bf16;
typedef __attribute__((ext_vector_type(8))) __bf16 bf16x8;
typedef __attribute__((ext_vector_type(4))) float f32x4;
typedef __attribute__((ext_vector_type(16))) float f32x16;
typedef __attribute__((ext_vector_type(4))) unsigned u32x4;

__device__ __forceinline__ void gload_lds16(const void* g, void* l) {
    __builtin_amdgcn_global_load_lds((const __attribute__((address_space(1))) void*)g,
                                     (__attribute__((address_space(3))) void*)l, 16, 0, 0);
}

__device__ __forceinline__ unsigned pk2(float a, float b) {
    bf16 lo = (bf16)a, hb = (bf16)b;
    return (unsigned)__builtin_bit_cast(unsigned short, lo) |
           ((unsigned)__builtin_bit_cast(unsigned short, hb) << 16);
}

// ---------------- LayerNorm ----------------
template<bool OUT_BF16>
__global__ __launch_bounds__(256) void ln_kernel(const float* __restrict__ x,
        const float* __restrict__ w, const float* __restrict__ b,
        void* __restrict__ out) {
    const int row = blockIdx.x;
    const int t = threadIdx.x;
    const float4 xv = *(const float4*)(x + (long)row * D_ + t * 4);
    float s  = xv.x + xv.y + xv.z + xv.w;
    float sq = xv.x*xv.x + xv.y*xv.y + xv.z*xv.z + xv.w*xv.w;
    #pragma unroll
    for (int m = 32; m; m >>= 1) { s += __shfl_xor(s, m); sq += __shfl_xor(sq, m); }
    __shared__ float red[8];
    const int wid = t >> 6, lid = t & 63;
    if (lid == 0) { red[wid] = s; red[wid + 4] = sq; }
    __syncthreads();
    s  = red[0] + red[1] + red[2] + red[3];
    sq = red[4] + red[5] + red[6] + red[7];
    const float mu   = s * (1.0f / D_);
    const float var  = sq * (1.0f / D_) - mu * mu;
    const float rstd = rsqrtf(var + 1e-5f);
    const float4 wv = *(const float4*)(w + t * 4);
    const float4 bv = *(const float4*)(b + t * 4);
    float o0 = (xv.x - mu) * rstd * wv.x + bv.x;
    float o1 = (xv.y - mu) * rstd * wv.y + bv.y;
    float o2 = (xv.z - mu) * rstd * wv.z + bv.z;
    float o3 = (xv.w - mu) * rstd * wv.w + bv.w;
    if (OUT_BF16) {
        bf16* o = (bf16*)out + (long)row * D_ + t * 4;
        o[0] = (bf16)o0; o[1] = (bf16)o1; o[2] = (bf16)o2; o[3] = (bf16)o3;
    } else {
        float* o = (float*)out + (long)row * D_ + t * 4;
        o[0] = o0; o[1] = o1; o[2] = o2; o[3] = o3;
    }
}

// ------------- merged weight convert+transpose for one layer -------------
// wt layout (elements): q:0 k:1M v:2M z:3M r:4M o:5M W1t:6M W2t:10M
__global__ __launch_bounds__(256) void wconv_all(
        const float* __restrict__ Wq, const float* __restrict__ Wk,
        const float* __restrict__ Wv, const float* __restrict__ Wz,
        const float* __restrict__ Wr, const float* __restrict__ Wo,
        const float* __restrict__ W1, const float* __restrict__ W2,
        bf16* __restrict__ wt) {
    __shared__ float s[32][33];
    const int bid = blockIdx.x;
    const float* src; bf16* dst; int t, K, nlg;
    if (bid < 6144) {
        const int m = bid >> 10; t = bid & 1023; K = 1024; nlg = 5;
        switch (m) {
            case 0: src = Wq; dst = wt; break;
            case 1: src = Wk; dst = wt + (1u << 20); break;
            case 2: src = Wv; dst = wt + (2u << 20); break;
            case 3: src = Wz; dst = wt + (3u << 20); break;
            case 4: src = Wr; dst = wt + (4u << 20); break;
            default: src = Wo; dst = wt + (5u << 20); break;
        }
    } else if (bid < 10240) {
        t = bid - 6144; K = 1024; nlg = 7; src = W1; dst = wt + (6u << 20);
    } else {
        t = bid - 10240; K = 4096; nlg = 5; src = W2; dst = wt + (10u << 20);
    }
    const int N = 1 << (nlg + 5);
    const int k0 = (t >> nlg) * 32, n0 = (t & ((1 << nlg) - 1)) * 32;
    const int c = threadIdx.x & 31, r8 = threadIdx.x >> 5;
    #pragma unroll
    for (int it = 0; it < 4; it++)
        s[r8 + it*8][c] = src[(long)(k0 + r8 + it*8) * N + n0 + c];
    __syncthreads();
    #pragma unroll
    for (int it = 0; it < 4; it++)
        dst[(long)(n0 + r8 + it*8) * K + k0 + c] = (bf16)s[c][r8 + it*8];
}

// ---------------- GEMM core loop (128x128 tile, m97 structure) ----------------
#define GEMM_CORE(A_, Bt_, K_) \
    f32x4 acc[4][4]; \
    _Pragma("unroll") for (int i = 0; i < 4; i++) \
        _Pragma("unroll") for (int j = 0; j < 4; j++) acc[i][j] = (f32x4){0.f,0.f,0.f,0.f}; \
    const int lane = tid & 63, w = tid >> 6; \
    const int wr = (w >> 1) * 64, wc = (w & 1) * 64; \
    const int cl = lane & 15, gl = lane >> 4; \
    const int srow = tid >> 2, skoff = (tid & 3) * 8; \
    const bf16* ga = (A_)  + (long)(m0 + srow) * (K_) + skoff; \
    const bf16* gb = (Bt_) + (long)(n0 + srow) * (K_) + skoff; \
    char* sAc = (char*)sA; char* sBc = (char*)sB; \
    const int wb = w * 1024; \
    for (int k0 = 0; k0 < (K_); k0 += 32) { \
        if (k0) __syncthreads(); \
        gload_lds16(ga + k0,              sAc + wb); \
        gload_lds16(ga + 64 * (K_) + k0,  sAc + 4096 + wb); \
        gload_lds16(gb + k0,              sBc + wb); \
        gload_lds16(gb + 64 * (K_) + k0,  sBc + 4096 + wb); \
        __syncthreads(); \
        bf16x8 af[4], bfr[4]; \
        _Pragma("unroll") for (int i = 0; i < 4; i++) af[i]  = *(const bf16x8*)(sA + (wr + i*16 + cl) * 32 + 8 * gl); \
        _Pragma("unroll") for (int j = 0; j < 4; j++) bfr[j] = *(const bf16x8*)(sB + (wc + j*16 + cl) * 32 + 8 * gl); \
        _Pragma("unroll") for (int i = 0; i < 4; i++) \
            _Pragma("unroll") for (int j = 0; j < 4; j++) \
                acc[i][j] = __builtin_amdgcn_mfma_f32_16x16x32_bf16(af[i], bfr[j], acc[i][j], 0, 0, 0); \
    }

enum { EPI_BF16 = 0, EPI_VT = 1, EPI_F32 = 2, EPI_SIG = 3, EPI_GELU = 4 };

template<int EPI>
__global__ __launch_bounds__(256) void gemm_kernel(const bf16* __restrict__ A,
        const bf16* __restrict__ Bt, const float* __restrict__ bias,
        void* __restrict__ out, int K, int N, int gx) {
    __shared__ bf16 sA[128 * 32];
    __shared__ bf16 sB[128 * 32];
    const int tid = threadIdx.x;
    const int nwg = gridDim.x;
    int bid = blockIdx.x;
    bid = (bid & 7) * (nwg >> 3) + (bid >> 3);
    const int m0 = (bid / gx) * 128, n0 = (bid % gx) * 128;
    GEMM_CORE(A, Bt, K)
    #pragma unroll
    for (int i = 0; i < 4; i++) {
        #pragma unroll
        for (int j = 0; j < 4; j++) {
            const int gcol = n0 + wc + j * 16 + cl;
            const float bv = bias[gcol];
            #pragma unroll
            for (int r = 0; r < 4; r++) {
                const int grow = m0 + wr + i * 16 + gl * 4 + r;
                float v = acc[i][j][r] + bv;
                if (EPI == EPI_SIG)  v = 1.0f / (1.0f + __expf(-v));
                if (EPI == EPI_GELU) v = 0.5f * v * (1.0f + erff(v * 0.70710678118f));
                if (EPI == EPI_F32 || EPI == EPI_SIG) {
                    ((float*)out)[(long)grow * N + gcol] = v;
                } else if (EPI == EPI_VT) {
                    ((bf16*)out)[((long)(grow >> 11) * N + gcol) * T_ + (grow & 2047)] = (bf16)v;
                } else {
                    ((bf16*)out)[(long)grow * N + gcol] = (bf16)v;
                }
            }
        }
    }
}

// ---------------- fused QKVZR GEMM: A[4096,1024] @ WT[5120,1024]^T ----------------
__global__ __launch_bounds__(256) void gemm5_kernel(const bf16* __restrict__ A,
        const bf16* __restrict__ Bt,
        const float* __restrict__ bq, const float* __restrict__ bk,
        const float* __restrict__ bv_, const float* __restrict__ bz,
        const float* __restrict__ br,
        bf16* __restrict__ oq, bf16* __restrict__ ok, bf16* __restrict__ ov,
        float* __restrict__ oz, float* __restrict__ orr) {
    __shared__ bf16 sA[128 * 32];
    __shared__ bf16 sB[128 * 32];
    const int tid = threadIdx.x;
    int bid = blockIdx.x;
    bid = (bid & 7) * 160 + (bid >> 3);      // 1280 blocks
    const int m0 = (bid / 40) * 128, n0 = (bid % 40) * 128;
    GEMM_CORE(A, Bt, D_)
    const int seg = n0 >> 10, lc0 = n0 & 1023;
    const float* bias; int mode; void* outp;
    switch (seg) {
        case 0:  bias = bq;  mode = 0; outp = oq;  break;
        case 1:  bias = bk;  mode = 0; outp = ok;  break;
        case 2:  bias = bv_; mode = 1; outp = ov;  break;
        case 3:  bias = bz;  mode = 2; outp = oz;  break;
        default: bias = br;  mode = 2; outp = orr; break;
    }
    #pragma unroll
    for (int i = 0; i < 4; i++) {
        #pragma unroll
        for (int j = 0; j < 4; j++) {
            const int lcol = lc0 + wc + j * 16 + cl;
            const float bv = bias[lcol];
            #pragma unroll
            for (int r = 0; r < 4; r++) {
                const int grow = m0 + wr + i * 16 + gl * 4 + r;
                const float v = acc[i][j][r] + bv;
                if (mode == 0) {
                    ((bf16*)outp)[(long)grow * 1024 + lcol] = (bf16)v;
                } else if (mode == 1) {
                    ((bf16*)outp)[((long)(grow >> 11) * 1024 + lcol) * T_ + (grow & 2047)] = (bf16)v;
                } else {
                    ((float*)outp)[(long)grow * 1024 + lcol] = 1.0f / (1.0f + __expf(-v));
                }
            }
        }
    }
}

// ---------------- Flash attention: 32x32 MFMA, swapped QK, in-register softmax ----
// block = 2 waves; wave handles 32 q rows; pair (g, 63-g) balances blocks.
#define LOADKV(K0,K1,K2,K3,V00,V01,V10,V11,KVB) do { \
    const long kro_ = (long)((KVB) + col) * D_ + 8 * hi; \
    K0 = *(const bf16x8*)(kB + kro_); \
    K1 = *(const bf16x8*)(kB + kro_ + 16); \
    K2 = *(const bf16x8*)(kB + kro_ + 32); \
    K3 = *(const bf16x8*)(kB + kro_ + 48); \
    const long vro_ = (long)col * T_ + (KVB) + 8 * hi; \
    V00 = *(const bf16x8*)(vB + vro_); \
    V10 = *(const bf16x8*)(vB + vro_ + 16); \
    V01 = *(const bf16x8*)(vB + vro_ + (long)32 * T_); \
    V11 = *(const bf16x8*)(vB + vro_ + (long)32 * T_ + 16); \
} while (0)

#define PROC(K0,K1,K2,K3,V00,V01,V10,V11,JJ) do { \
    f32x16 S; \
    _Pragma("unroll") for (int i_ = 0; i_ < 16; i_++) S[i_] = 0.f; \
    S = __builtin_amdgcn_mfma_f32_32x32x16_bf16(K0, qf0, S, 0, 0, 0); \
    S = __builtin_amdgcn_mfma_f32_32x32x16_bf16(K1, qf1, S, 0, 0, 0); \
    S = __builtin_amdgcn_mfma_f32_32x32x16_bf16(K2, qf2, S, 0, 0, 0); \
    S = __builtin_amdgcn_mfma_f32_32x32x16_bf16(K3, qf3, S, 0, 0, 0); \
    float p_[16]; \
    const bool dg_ = (JJ) == nt - 1; \
    _Pragma("unroll") for (int r_ = 0; r_ < 16; r_++) { \
        p_[r_] = S[r_] * 0.125f; \
        const int kvl_ = (r_ & 3) + 8 * (r_ >> 2) + 4 * hi; \
        if (dg_ && kvl_ > col) p_[r_] = -3.0e38f; \
    } \
    float tm_ = p_[0]; \
    _Pragma("unroll") for (int r_ = 1; r_ < 16; r_++) tm_ = fmaxf(tm_, p_[r_]); \
    tm_ = fmaxf(tm_, __shfl_xor(tm_, 32)); \
    const float mn_ = fmaxf(mrun, tm_); \
    const float al_ = __expf(mrun - mn_); \
    mrun = mn_; \
    float ts_ = 0.f; \
    _Pragma("unroll") for (int r_ = 0; r_ < 16; r_++) { p_[r_] = __expf(p_[r_] - mn_); ts_ += p_[r_]; } \
    ts_ += __shfl_xor(ts_, 32); \
    lrun = lrun * al_ + ts_; \
    _Pragma("unroll") for (int i_ = 0; i_ < 16; i_++) { Od0[i_] *= al_; Od1[i_] *= al_; } \
    const unsigned w0_ = pk2(p_[0],  p_[1]),  w1_ = pk2(p_[2],  p_[3]); \
    const unsigned w2_ = pk2(p_[4],  p_[5]),  w3_ = pk2(p_[6],  p_[7]); \
    const unsigned w4_ = pk2(p_[8],  p_[9]),  w5_ = pk2(p_[10], p_[11]); \
    const unsigned w6_ = pk2(p_[12], p_[13]), w7_ = pk2(p_[14], p_[15]); \
    const unsigned x0_ = __shfl_xor((int)w0_, 32), x1_ = __shfl_xor((int)w1_, 32); \
    const unsigned x2_ = __shfl_xor((int)w2_, 32), x3_ = __shfl_xor((int)w3_, 32); \
    const unsigned x4_ = __shfl_xor((int)w4_, 32), x5_ = __shfl_xor((int)w5_, 32); \
    const unsigned x6_ = __shfl_xor((int)w6_, 32), x7_ = __shfl_xor((int)w7_, 32); \
    const u32x4 c0_ = hi ? (u32x4){x2_, x3_, w2_, w3_} : (u32x4){w0_, w1_, x0_, x1_}; \
    const u32x4 c1_ = hi ? (u32x4){x6_, x7_, w6_, w7_} : (u32x4){w4_, w5_, x4_, x5_}; \
    const bf16x8 pb0_ = __builtin_bit_cast(bf16x8, c0_); \
    const bf16x8 pb1_ = __builtin_bit_cast(bf16x8, c1_); \
    Od0 = __builtin_amdgcn_mfma_f32_32x32x16_bf16(V00, pb0_, Od0, 0, 0, 0); \
    Od0 = __builtin_amdgcn_mfma_f32_32x32x16_bf16(V10, pb1_, Od0, 0, 0, 0); \
    Od1 = __builtin_amdgcn_mfma_f32_32x32x16_bf16(V01, pb0_, Od1, 0, 0, 0); \
    Od1 = __builtin_amdgcn_mfma_f32_32x32x16_bf16(V11, pb1_, Od1, 0, 0, 0); \
} while (0)

__global__ __launch_bounds__(128) void attn_kernel(const bf16* __restrict__ q,
        const bf16* __restrict__ k, const bf16* __restrict__ vT,
        bf16* __restrict__ y) {
    const int tid = threadIdx.x, wid = tid >> 6, lane = tid & 63;
    const int col = lane & 31, hi = lane >> 5;
    const int bid = blockIdx.x;
    const int xcd = bid & 7, idx = bid >> 3;
    const int bh = xcd + 8 * (idx & 3);
    const int g = idx >> 2;                 // 0..31
    const int qt = wid ? (63 - g) : g;      // q-tile 0..63
    const int qb = qt * 32;
    const int b = bh >> 4, h = bh & 15;

    const bf16* qB = q  + (long)b * T_ * D_ + h * HD_;
    const bf16* kB = k  + (long)b * T_ * D_ + h * HD_;
    const bf16* vB = vT + (long)b * D_ * T_ + (long)h * HD_ * T_;

    bf16x8 qf0, qf1, qf2, qf3;
    {
        const long qo = (long)(qb + col) * D_ + 8 * hi;
        qf0 = *(const bf16x8*)(qB + qo);
        qf1 = *(const bf16x8*)(qB + qo + 16);
        qf2 = *(const bf16x8*)(qB + qo + 32);
        qf3 = *(const bf16x8*)(qB + qo + 48);
    }

    f32x16 Od0, Od1;
    #pragma unroll
    for (int i = 0; i < 16; i++) { Od0[i] = 0.f; Od1[i] = 0.f; }
    float mrun = -INFINITY, lrun = 0.f;

    bf16x8 ka0, ka1, ka2, ka3, va00, va01, va10, va11;
    bf16x8 kb0, kb1, kb2, kb3, vb00, vb01, vb10, vb11;
    const int nt = qt + 1;

    int jj = 0;
    LOADKV(ka0, ka1, ka2, ka3, va00, va01, va10, va11, 0);
    while (true) {
        if (jj + 1 < nt) LOADKV(kb0, kb1, kb2, kb3, vb00, vb01, vb10, vb11, (jj + 1) * 32);
        PROC(ka0, ka1, ka2, ka3, va00, va01, va10, va11, jj);
        if (++jj >= nt) break;
        if (jj + 1 < nt) LOADKV(ka0, ka1, ka2, ka3, va00, va01, va10, va11, (jj + 1) * 32);
        PROC(kb0, kb1, kb2, kb3, vb00, vb01, vb10, vb11, jj);
        if (++jj >= nt) break;
    }

    const float inv = 1.0f / lrun;
    bf16* yr = y + (long)(b * T_ + qb + col) * D_ + h * HD_;
    #pragma unroll
    for (int rg = 0; rg < 4; rg++) {
        const int d0 = 8 * rg + 4 * hi;
        uint2 s0 = { pk2(Od0[4*rg] * inv, Od0[4*rg+1] * inv), pk2(Od0[4*rg+2] * inv, Od0[4*rg+3] * inv) };
        *(uint2*)(yr + d0) = s0;
        uint2 s1 = { pk2(Od1[4*rg] * inv, Od1[4*rg+1] * inv), pk2(Od1[4*rg+2] * inv, Od1[4*rg+3] * inv) };
        *(uint2*)(yr + 32 + d0) = s1;
    }
}

// ---------------- gates ----------------
__global__ __launch_bounds__(256) void gate1_kernel(float* __restrict__ x,
        const float* __restrict__ z, const float* __restrict__ r,
        const float* __restrict__ xa) {
    const long i = ((long)blockIdx.x * 256 + threadIdx.x) * 4;
    float4 xv = *(const float4*)(x + i);
    const float4 zv = *(const float4*)(z + i);
    const float4 rv = *(const float4*)(r + i);
    const float4 av = *(const float4*)(xa + i);
    xv.x = (1.f - zv.x) * xv.x + zv.x * tanhf(rv.x * av.x);
    xv.y = (1.f - zv.y) * xv.y + zv.y * tanhf(rv.y * av.y);
    xv.z = (1.f - zv.z) * xv.z + zv.z * tanhf(rv.z * av.z);
    xv.w = (1.f - zv.w) * xv.w + zv.w * tanhf(rv.w * av.w);
    *(float4*)(x + i) = xv;
}

__global__ __launch_bounds__(256) void gate2_kernel(float* __restrict__ x,
        const float* __restrict__ z, const float* __restrict__ m,
        const float* __restrict__ src) {
    const long i = ((long)blockIdx.x * 256 + threadIdx.x) * 4;
    float4 xv = *(const float4*)(x + i);
    const float4 zv = *(const float4*)(z + i);
    const float4 mv = *(const float4*)(m + i);
    const float4 sv = *(const float4*)(src + i);
    xv.x = (1.f - zv.x) * xv.x + zv.x * mv.x + sv.x;
    xv.y = (1.f - zv.y) * xv.y + zv.y * mv.y + sv.y;
    xv.z = (1.f - zv.z) * xv.z + zv.z * mv.z + sv.z;
    xv.w = (1.f - zv.w) * xv.w + zv.w * mv.w + sv.w;
    *(float4*)(x + i) = xv;
}

extern "C" void kernel_launch(void* const* d_in, const int* in_sizes, int n_in,
                              void* d_out, int out_size, void* d_ws, size_t ws_size,
                              hipStream_t stream) {
    const float* seq   = (const float*)d_in[0];
    const float* Wq    = (const float*)d_in[1];  const float* bq = (const float*)d_in[2];
    const float* Wk    = (const float*)d_in[3];  const float* bk = (const float*)d_in[4];
    const float* Wv    = (const float*)d_in[5];  const float* bv = (const float*)d_in[6];
    const float* Wo    = (const float*)d_in[7];  const float* bo = (const float*)d_in[8];
    const float* Wz    = (const float*)d_in[9];  const float* bz = (const float*)d_in[10];
    const float* Wr    = (const float*)d_in[11]; const float* br = (const float*)d_in[12];
    const float* W1    = (const float*)d_in[13]; const float* b1 = (const float*)d_in[14];
    const float* W2    = (const float*)d_in[15]; const float* b2 = (const float*)d_in[16];
    const float* ln1w  = (const float*)d_in[17]; const float* ln1b = (const float*)d_in[18];
    const float* ln2w  = (const float*)d_in[19]; const float* ln2b = (const float*)d_in[20];
    const float* lnfw  = (const float*)d_in[21]; const float* lnfb = (const float*)d_in[22];

    char* ws = (char*)d_ws;
    float* x   = (float*)(ws);                       // 16 MB
    float* z   = (float*)(ws + ((size_t)16 << 20));  // 16 MB
    float* r   = (float*)(ws + ((size_t)32 << 20));  // 16 MB
    float* xa  = (float*)(ws + ((size_t)48 << 20));  // 16 MB
    bf16*  xn  = (bf16*)(ws + ((size_t)64 << 20));   // 8 MB
    bf16*  qb_ = (bf16*)(ws + ((size_t)72 << 20));   // 8 MB
    bf16*  kb_ = (bf16*)(ws + ((size_t)80 << 20));   // 8 MB
    bf16*  vtb = (bf16*)(ws + ((size_t)88 << 20));   // 8 MB
    bf16*  yb  = (bf16*)(ws + ((size_t)96 << 20));   // 8 MB
    bf16*  h1  = (bf16*)(ws + ((size_t)104 << 20));  // 32 MB
    bf16*  wt  = (bf16*)(ws + ((size_t)136 << 20));  // 36 MB weight pool

    bf16* wto = wt + (5u << 20);
    bf16* wt1 = wt + (6u << 20);
    bf16* wt2 = wt + (10u << 20);

    hipMemcpyAsync(x, seq, (size_t)M_ * D_ * 4, hipMemcpyDeviceToDevice, stream);

    const int gDDn = (M_ / 128) * (D_ / 128);    // 256
    const int gDFn = (M_ / 128) * (DF_ / 128);   // 1024

    for (int i = 0; i < NL_; i++) {
        const long dd = (long)i * D_ * D_;
        wconv_all<<<14336, 256, 0, stream>>>(Wq + dd, Wk + dd, Wv + dd, Wz + dd,
                                             Wr + dd, Wo + dd,
                                             W1 + (long)i * D_ * DF_,
                                             W2 + (long)i * DF_ * D_, wt);
        ln_kernel<true><<<M_, 256, 0, stream>>>(x, ln1w + i * D_, ln1b + i * D_, xn);
        gemm5_kernel<<<1280, 256, 0, stream>>>(xn, wt,
                bq + i * D_, bk + i * D_, bv + i * D_, bz + i * D_, br + i * D_,
                qb_, kb_, vtb, z, r);
        attn_kernel<<<1024, 128, 0, stream>>>(qb_, kb_, vtb, yb);
        gemm_kernel<EPI_F32 ><<<gDDn, 256, 0, stream>>>(yb, wto, bo + i * D_, xa, D_, D_, D_/128);
        gate1_kernel<<<(M_ * D_) / 1024, 256, 0, stream>>>(x, z, r, xa);
        ln_kernel<true><<<M_, 256, 0, stream>>>(x, ln2w + i * D_, ln2b + i * D_, xn);
        gemm_kernel<EPI_GELU><<<gDFn, 256, 0, stream>>>(xn, wt1, b1 + i * DF_, h1, D_, DF_, DF_/128);
        gemm_kernel<EPI_F32 ><<<gDDn, 256, 0, stream>>>(h1, wt2, b2 + i * D_, xa, DF_, D_, D_/128);
        gate2_kernel<<<(M_ * D_) / 1024, 256, 0, stream>>>(x, z, xa, seq);
    }
    ln_kernel<false><<<M_, 256, 0, stream>>>(x, lnfw, lnfb, d_out);
}

// Round 5
// 1968.860 us; speedup vs baseline: 2.3798x; 1.1433x over previous
//
#include <hip/hip_runtime.h>
#include <hip/hip_bf16.h>
#include <math.h>

#define B_ 2
#define T_ 2048
#define D_ 1024
#define H_ 16
#define NL_ 6
#define DF_ 4096
#define HD_ 64
#define M_ (B_*T_)

typedef __bf16 bf16;
typedef __attribute__((ext_vector_type(8))) __bf16 bf16x8;
typedef __attribute__((ext_vector_type(4))) float f32x4;
typedef __attribute__((ext_vector_type(16))) float f32x16;
typedef __attribute__((ext_vector_type(4))) unsigned u32x4;

#define BAR() __builtin_amdgcn_s_barrier()
#define LGKM0() asm volatile("s_waitcnt lgkmcnt(0)" ::: "memory")
#define VMC(n) asm volatile("s_waitcnt vmcnt(" #n ")" ::: "memory")

__device__ __forceinline__ void gload_lds16(const void* g, void* l) {
    __builtin_amdgcn_global_load_lds((const __attribute__((address_space(1))) void*)g,
                                     (__attribute__((address_space(3))) void*)l, 16, 0, 0);
}

__device__ __forceinline__ unsigned pk2(float a, float b) {
    bf16 lo = (bf16)a, hb = (bf16)b;
    return (unsigned)__builtin_bit_cast(unsigned short, lo) |
           ((unsigned)__builtin_bit_cast(unsigned short, hb) << 16);
}

// ---------------- LayerNorm ----------------
template<bool OUT_BF16>
__global__ __launch_bounds__(256) void ln_kernel(const float* __restrict__ x,
        const float* __restrict__ w, const float* __restrict__ b,
        void* __restrict__ out) {
    const int row = blockIdx.x;
    const int t = threadIdx.x;
    const float4 xv = *(const float4*)(x + (long)row * D_ + t * 4);
    float s  = xv.x + xv.y + xv.z + xv.w;
    float sq = xv.x*xv.x + xv.y*xv.y + xv.z*xv.z + xv.w*xv.w;
    #pragma unroll
    for (int m = 32; m; m >>= 1) { s += __shfl_xor(s, m); sq += __shfl_xor(sq, m); }
    __shared__ float red[8];
    const int wid = t >> 6, lid = t & 63;
    if (lid == 0) { red[wid] = s; red[wid + 4] = sq; }
    __syncthreads();
    s  = red[0] + red[1] + red[2] + red[3];
    sq = red[4] + red[5] + red[6] + red[7];
    const float mu   = s * (1.0f / D_);
    const float var  = sq * (1.0f / D_) - mu * mu;
    const float rstd = rsqrtf(var + 1e-5f);
    const float4 wv = *(const float4*)(w + t * 4);
    const float4 bv = *(const float4*)(b + t * 4);
    float o0 = (xv.x - mu) * rstd * wv.x + bv.x;
    float o1 = (xv.y - mu) * rstd * wv.y + bv.y;
    float o2 = (xv.z - mu) * rstd * wv.z + bv.z;
    float o3 = (xv.w - mu) * rstd * wv.w + bv.w;
    if (OUT_BF16) {
        bf16* o = (bf16*)out + (long)row * D_ + t * 4;
        o[0] = (bf16)o0; o[1] = (bf16)o1; o[2] = (bf16)o2; o[3] = (bf16)o3;
    } else {
        float* o = (float*)out + (long)row * D_ + t * 4;
        o[0] = o0; o[1] = o1; o[2] = o2; o[3] = o3;
    }
}

// ------------- merged weight convert+transpose for one layer -------------
__global__ __launch_bounds__(256) void wconv_all(
        const float* __restrict__ Wq, const float* __restrict__ Wk,
        const float* __restrict__ Wv, const float* __restrict__ Wz,
        const float* __restrict__ Wr, const float* __restrict__ Wo,
        const float* __restrict__ W1, const float* __restrict__ W2,
        bf16* __restrict__ wt) {
    __shared__ float s[32][33];
    const int bid = blockIdx.x;
    const float* src; bf16* dst; int t, K, nlg;
    if (bid < 6144) {
        const int m = bid >> 10; t = bid & 1023; K = 1024; nlg = 5;
        switch (m) {
            case 0: src = Wq; dst = wt; break;
            case 1: src = Wk; dst = wt + (1u << 20); break;
            case 2: src = Wv; dst = wt + (2u << 20); break;
            case 3: src = Wz; dst = wt + (3u << 20); break;
            case 4: src = Wr; dst = wt + (4u << 20); break;
            default: src = Wo; dst = wt + (5u << 20); break;
        }
    } else if (bid < 10240) {
        t = bid - 6144; K = 1024; nlg = 7; src = W1; dst = wt + (6u << 20);
    } else {
        t = bid - 10240; K = 4096; nlg = 5; src = W2; dst = wt + (10u << 20);
    }
    const int N = 1 << (nlg + 5);
    const int k0 = (t >> nlg) * 32, n0 = (t & ((1 << nlg) - 1)) * 32;
    const int c = threadIdx.x & 31, r8 = threadIdx.x >> 5;
    #pragma unroll
    for (int it = 0; it < 4; it++)
        s[r8 + it*8][c] = src[(long)(k0 + r8 + it*8) * N + n0 + c];
    __syncthreads();
    #pragma unroll
    for (int it = 0; it < 4; it++)
        dst[(long)(n0 + r8 + it*8) * K + k0 + c] = (bf16)s[c][r8 + it*8];
}

// =============== 256x256 8-phase GEMM core (BK=64, 8 waves, 128 KiB LDS) ===============
// LDS: A dbuf [2][256][64] bf16 at 0, B dbuf at 65536. K-bytes XOR-swizzled by (row&7)<<4.
// Staging discipline: a stage into the CURRENT buf region R only in a phase strictly
// after the last phase whose ds_reads touch R (A fully read after phase1 -> STGA in
// phases 2/3; B fully read after phase2 -> STGB(0) in phase 3). Next-buf stages any phase.
#define MFMA16(a, b, c) __builtin_amdgcn_mfma_f32_16x16x32_bf16(a, b, c, 0, 0, 0)

__device__ __forceinline__ void gemm256_core(const bf16* __restrict__ A, const bf16* __restrict__ Bt,
        const int Ks, const int NT, const int m0, const int n0, char* lds, f32x4 (&acc)[8][4]) {
    const int tid = threadIdx.x;
    const int lane = tid & 63, w = tid >> 6;
    const int wm = w >> 2, wn = w & 3;
    const int cl = lane & 15, gl = lane >> 4;
    const int srow = lane >> 3;
    const int scol = ((lane & 7) ^ srow) * 8;     // pre-swizzled source column (elements)
    const bf16* pa0 = A  + (size_t)(m0 + w * 16 + srow) * Ks + scol;
    const bf16* pa1 = pa0 + (size_t)8 * Ks;
    const bf16* pb0 = Bt + (size_t)(n0 + w * 16 + srow) * Ks + scol;
    const bf16* pb1 = pb0 + (size_t)8 * Ks;
    char* la = lds + w * 2048;
    char* lb = lds + 65536 + w * 2048;
    const size_t hA = (size_t)128 * Ks;

#define STGA(H, KT, BUF) do { \
    gload_lds16(pa0 + (size_t)(H) * hA + (size_t)(KT) * 64, la + (BUF) * 32768 + (H) * 16384); \
    gload_lds16(pa1 + (size_t)(H) * hA + (size_t)(KT) * 64, la + (BUF) * 32768 + (H) * 16384 + 1024); } while (0)
#define STGB(H, KT, BUF) do { \
    gload_lds16(pb0 + (size_t)(H) * hA + (size_t)(KT) * 64, lb + (BUF) * 32768 + (H) * 16384); \
    gload_lds16(pb1 + (size_t)(H) * hA + (size_t)(KT) * 64, lb + (BUF) * 32768 + (H) * 16384 + 1024); } while (0)

    // prologue: kt0 {A0,A1,B0,B1}; kt1 {B0,A0,A1}  -> vmcnt(6) drains kt0, leaves kt1's 3
    STGA(0, 0, 0); STGA(1, 0, 0); STGB(0, 0, 0); STGB(1, 0, 0);
    STGB(0, 1, 1); STGA(0, 1, 1); STGA(1, 1, 1);
    VMC(6);
    BAR();

    const int X0  = (gl * 16) ^ ((cl & 7) << 4);
    const int rdA = (wm * 128 + cl) * 128 + X0;
    const int rdB = (wn * 64  + cl) * 128 + X0;

    for (int kt = 0; kt < NT; ++kt) {
        const int buf = kt & 1;
        const char* sAb = lds + buf * 32768;
        const char* sBb = lds + 65536 + buf * 32768;
        const bool st1 = (kt + 1 < NT), st2 = (kt + 2 < NT);
        bf16x8 a0[4][2], a4[4][2], b01[2][2], b23[2][2];
        // ---- phase 0: read A(m0-3), B(n0-1); stage kt+1's B1 (other buf); mfma m0-3 x n0-1
        #pragma unroll
        for (int mi = 0; mi < 4; mi++) {
            a0[mi][0] = *(const bf16x8*)(sAb + rdA + mi * 2048);
            a0[mi][1] = *(const bf16x8*)(sAb + (rdA ^ 64) + mi * 2048);
        }
        #pragma unroll
        for (int ni = 0; ni < 2; ni++) {
            b01[ni][0] = *(const bf16x8*)(sBb + rdB + ni * 2048);
            b01[ni][1] = *(const bf16x8*)(sBb + (rdB ^ 64) + ni * 2048);
        }
        if (st1) STGB(1, kt + 1, buf ^ 1);
        BAR(); LGKM0();
        __builtin_amdgcn_s_setprio(1);
        #pragma unroll
        for (int mi = 0; mi < 4; mi++)
            #pragma unroll
            for (int ni = 0; ni < 2; ni++) {
                acc[mi][ni] = MFMA16(a0[mi][0], b01[ni][0], acc[mi][ni]);
                acc[mi][ni] = MFMA16(a0[mi][1], b01[ni][1], acc[mi][ni]);
            }
        __builtin_amdgcn_s_setprio(0);
        BAR();
        // ---- phase 1: read A(m4-7); mfma m4-7 x n0-1   (no stage: B not fully read yet)
        #pragma unroll
        for (int mi = 0; mi < 4; mi++) {
            a4[mi][0] = *(const bf16x8*)(sAb + rdA + (mi + 4) * 2048);
            a4[mi][1] = *(const bf16x8*)(sAb + (rdA ^ 64) + (mi + 4) * 2048);
        }
        BAR(); LGKM0();
        __builtin_amdgcn_s_setprio(1);
        #pragma unroll
        for (int mi = 0; mi < 4; mi++)
            #pragma unroll
            for (int ni = 0; ni < 2; ni++) {
                acc[mi + 4][ni] = MFMA16(a4[mi][0], b01[ni][0], acc[mi + 4][ni]);
                acc[mi + 4][ni] = MFMA16(a4[mi][1], b01[ni][1], acc[mi + 4][ni]);
            }
        __builtin_amdgcn_s_setprio(0);
        BAR();
        // ---- phase 2: read B(n2-3); stage kt+2's A0 (A fully read after ph1); mfma m4-7 x n2-3
        #pragma unroll
        for (int ni = 0; ni < 2; ni++) {
            b23[ni][0] = *(const bf16x8*)(sBb + rdB + (ni + 2) * 2048);
            b23[ni][1] = *(const bf16x8*)(sBb + (rdB ^ 64) + (ni + 2) * 2048);
        }
        if (st2) STGA(0, kt + 2, buf);
        BAR(); LGKM0();
        __builtin_amdgcn_s_setprio(1);
        #pragma unroll
        for (int mi = 0; mi < 4; mi++)
            #pragma unroll
            for (int ni = 0; ni < 2; ni++) {
                acc[mi + 4][ni + 2] = MFMA16(a4[mi][0], b23[ni][0], acc[mi + 4][ni + 2]);
                acc[mi + 4][ni + 2] = MFMA16(a4[mi][1], b23[ni][1], acc[mi + 4][ni + 2]);
            }
        __builtin_amdgcn_s_setprio(0);
        BAR();
        // ---- phase 3: stage kt+2's A1 + B0 (B fully read after ph2); mfma m0-3 x n2-3; boundary vmcnt
        if (st2) { STGA(1, kt + 2, buf); STGB(0, kt + 2, buf); }
        __builtin_amdgcn_s_setprio(1);
        #pragma unroll
        for (int mi = 0; mi < 4; mi++)
            #pragma unroll
            for (int ni = 0; ni < 2; ni++) {
                acc[mi][ni + 2] = MFMA16(a0[mi][0], b23[ni][0], acc[mi][ni + 2]);
                acc[mi][ni + 2] = MFMA16(a0[mi][1], b23[ni][1], acc[mi][ni + 2]);
            }
        __builtin_amdgcn_s_setprio(0);
        if (st2)      { VMC(6); }
        else if (st1) { VMC(0); }
        BAR();
    }
#undef STGA
#undef STGB
}

// ---- gemm5: xn[4096,1024] @ wt[5120,1024]^T, segmented epilogue ----
__global__ __launch_bounds__(512, 2) void gemm5_256(const bf16* __restrict__ A, const bf16* __restrict__ Bt,
        const float* __restrict__ bq, const float* __restrict__ bk, const float* __restrict__ bvv,
        const float* __restrict__ bz, const float* __restrict__ br,
        bf16* __restrict__ oq, bf16* __restrict__ ok, bf16* __restrict__ ov,
        float* __restrict__ oz, float* __restrict__ orr) {
    __shared__ __align__(16) char lds[131072];
    int bid = blockIdx.x;
    bid = (bid & 7) * 40 + (bid >> 3);
    const int m0 = (bid / 20) * 256, n0 = (bid % 20) * 256;
    f32x4 acc[8][4];
    #pragma unroll
    for (int i = 0; i < 8; i++)
        #pragma unroll
        for (int j = 0; j < 4; j++) acc[i][j] = (f32x4){0.f, 0.f, 0.f, 0.f};
    gemm256_core(A, Bt, 1024, 16, m0, n0, lds, acc);
    const int tid = threadIdx.x, lane = tid & 63, w = tid >> 6;
    const int wm = w >> 2, wn = w & 3, cl = lane & 15, gl = lane >> 4;
    const int seg = n0 >> 10;
    const int lc0 = (n0 & 1023) + wn * 64;
    const float* bias; int mode; void* outp;
    switch (seg) {
        case 0:  bias = bq;  mode = 0; outp = oq;  break;
        case 1:  bias = bk;  mode = 0; outp = ok;  break;
        case 2:  bias = bvv; mode = 1; outp = ov;  break;
        case 3:  bias = bz;  mode = 2; outp = oz;  break;
        default: bias = br;  mode = 2; outp = orr; break;
    }
    #pragma unroll
    for (int mi = 0; mi < 8; mi++) {
        #pragma unroll
        for (int ni = 0; ni < 4; ni++) {
            const int lcol = lc0 + ni * 16 + cl;
            const float bv = bias[lcol];
            #pragma unroll
            for (int r = 0; r < 4; r++) {
                const int row = m0 + wm * 128 + mi * 16 + gl * 4 + r;
                const float v = acc[mi][ni][r] + bv;
                if (mode == 0) {
                    ((bf16*)outp)[(long)row * 1024 + lcol] = (bf16)v;
                } else if (mode == 1) {
                    ((bf16*)outp)[((long)(row >> 11) * 1024 + lcol) * T_ + (row & 2047)] = (bf16)v;
                } else {
                    ((float*)outp)[(long)row * 1024 + lcol] = 1.0f / (1.0f + __expf(-v));
                }
            }
        }
    }
}

// ---- W1: xn[4096,1024] @ wt1[4096,1024]^T, gelu -> bf16 h1 ----
__global__ __launch_bounds__(512, 2) void gemmG_256(const bf16* __restrict__ A, const bf16* __restrict__ Bt,
        const float* __restrict__ bias, bf16* __restrict__ out) {
    __shared__ __align__(16) char lds[131072];
    int bid = blockIdx.x;
    bid = (bid & 7) * 32 + (bid >> 3);
    const int m0 = (bid >> 4) * 256, n0 = (bid & 15) * 256;
    f32x4 acc[8][4];
    #pragma unroll
    for (int i = 0; i < 8; i++)
        #pragma unroll
        for (int j = 0; j < 4; j++) acc[i][j] = (f32x4){0.f, 0.f, 0.f, 0.f};
    gemm256_core(A, Bt, 1024, 16, m0, n0, lds, acc);
    const int tid = threadIdx.x, lane = tid & 63, w = tid >> 6;
    const int wm = w >> 2, wn = w & 3, cl = lane & 15, gl = lane >> 4;
    #pragma unroll
    for (int mi = 0; mi < 8; mi++) {
        #pragma unroll
        for (int ni = 0; ni < 4; ni++) {
            const int col = n0 + wn * 64 + ni * 16 + cl;
            const float bv = bias[col];
            #pragma unroll
            for (int r = 0; r < 4; r++) {
                const int row = m0 + wm * 128 + mi * 16 + gl * 4 + r;
                float v = acc[mi][ni][r] + bv;
                v = 0.5f * v * (1.0f + erff(v * 0.70710678118f));
                out[(long)row * DF_ + col] = (bf16)v;
            }
        }
    }
}

// ---- W2 split-K=4: h1[4096,4096] @ wt2[1024,4096]^T -> 4 f32 partials ----
__global__ __launch_bounds__(512, 2) void gemmP_256(const bf16* __restrict__ A, const bf16* __restrict__ Bt,
        float* __restrict__ p0, float* __restrict__ p1, float* __restrict__ p2, float* __restrict__ p3) {
    __shared__ __align__(16) char lds[131072];
    int bid = blockIdx.x;
    bid = (bid & 7) * 32 + (bid >> 3);
    const int mt = bid >> 4, rest = bid & 15;
    const int nt = rest >> 2, s = rest & 3;
    const int m0 = mt * 256, n0 = nt * 256;
    f32x4 acc[8][4];
    #pragma unroll
    for (int i = 0; i < 8; i++)
        #pragma unroll
        for (int j = 0; j < 4; j++) acc[i][j] = (f32x4){0.f, 0.f, 0.f, 0.f};
    gemm256_core(A + s * 1024, Bt + s * 1024, 4096, 16, m0, n0, lds, acc);
    float* outp = (s == 0) ? p0 : (s == 1) ? p1 : (s == 2) ? p2 : p3;
    const int tid = threadIdx.x, lane = tid & 63, w = tid >> 6;
    const int wm = w >> 2, wn = w & 3, cl = lane & 15, gl = lane >> 4;
    #pragma unroll
    for (int mi = 0; mi < 8; mi++) {
        #pragma unroll
        for (int ni = 0; ni < 4; ni++) {
            const int col = n0 + wn * 64 + ni * 16 + cl;
            #pragma unroll
            for (int r = 0; r < 4; r++) {
                const int row = m0 + wm * 128 + mi * 16 + gl * 4 + r;
                outp[(long)row * 1024 + col] = acc[mi][ni][r];
            }
        }
    }
}

// ---------------- old 128^2 GEMM (Wo only) ----------------
__global__ __launch_bounds__(256) void gemmWo_kernel(const bf16* __restrict__ A,
        const bf16* __restrict__ Bt, const float* __restrict__ bias,
        float* __restrict__ out) {
    __shared__ bf16 sA[128 * 32];
    __shared__ bf16 sB[128 * 32];
    const int tid = threadIdx.x;
    int bid = blockIdx.x;
    bid = (bid & 7) * 32 + (bid >> 3);
    const int m0 = (bid >> 3) * 128, n0 = (bid & 7) * 128;
    f32x4 acc[4][4];
    #pragma unroll
    for (int i = 0; i < 4; i++)
        #pragma unroll
        for (int j = 0; j < 4; j++) acc[i][j] = (f32x4){0.f, 0.f, 0.f, 0.f};
    const int lane = tid & 63, w = tid >> 6;
    const int wr = (w >> 1) * 64, wc = (w & 1) * 64;
    const int cl = lane & 15, gl = lane >> 4;
    const int srow = tid >> 2, skoff = (tid & 3) * 8;
    const bf16* ga = A  + (long)(m0 + srow) * D_ + skoff;
    const bf16* gb = Bt + (long)(n0 + srow) * D_ + skoff;
    char* sAc = (char*)sA;
    char* sBc = (char*)sB;
    const int wb = w * 1024;
    for (int k0 = 0; k0 < D_; k0 += 32) {
        if (k0) __syncthreads();
        gload_lds16(ga + k0,            sAc + wb);
        gload_lds16(ga + 64 * D_ + k0,  sAc + 4096 + wb);
        gload_lds16(gb + k0,            sBc + wb);
        gload_lds16(gb + 64 * D_ + k0,  sBc + 4096 + wb);
        __syncthreads();
        bf16x8 af[4], bfr[4];
        #pragma unroll
        for (int i = 0; i < 4; i++) af[i]  = *(const bf16x8*)(sA + (wr + i*16 + cl) * 32 + 8 * gl);
        #pragma unroll
        for (int j = 0; j < 4; j++) bfr[j] = *(const bf16x8*)(sB + (wc + j*16 + cl) * 32 + 8 * gl);
        #pragma unroll
        for (int i = 0; i < 4; i++)
            #pragma unroll
            for (int j = 0; j < 4; j++)
                acc[i][j] = MFMA16(af[i], bfr[j], acc[i][j]);
    }
    #pragma unroll
    for (int i = 0; i < 4; i++) {
        #pragma unroll
        for (int j = 0; j < 4; j++) {
            const int gcol = n0 + wc + j * 16 + cl;
            const float bv = bias[gcol];
            #pragma unroll
            for (int r = 0; r < 4; r++) {
                const int grow = m0 + wr + i * 16 + gl * 4 + r;
                out[(long)grow * D_ + gcol] = acc[i][j][r] + bv;
            }
        }
    }
}

// ---------------- Flash attention (unchanged) ----------------
#define LOADKV(K0,K1,K2,K3,V00,V01,V10,V11,KVB) do { \
    const long kro_ = (long)((KVB) + col) * D_ + 8 * hi; \
    K0 = *(const bf16x8*)(kB + kro_); \
    K1 = *(const bf16x8*)(kB + kro_ + 16); \
    K2 = *(const bf16x8*)(kB + kro_ + 32); \
    K3 = *(const bf16x8*)(kB + kro_ + 48); \
    const long vro_ = (long)col * T_ + (KVB) + 8 * hi; \
    V00 = *(const bf16x8*)(vB + vro_); \
    V10 = *(const bf16x8*)(vB + vro_ + 16); \
    V01 = *(const bf16x8*)(vB + vro_ + (long)32 * T_); \
    V11 = *(const bf16x8*)(vB + vro_ + (long)32 * T_ + 16); \
} while (0)

#define PROC(K0,K1,K2,K3,V00,V01,V10,V11,JJ) do { \
    f32x16 S; \
    _Pragma("unroll") for (int i_ = 0; i_ < 16; i_++) S[i_] = 0.f; \
    S = __builtin_amdgcn_mfma_f32_32x32x16_bf16(K0, qf0, S, 0, 0, 0); \
    S = __builtin_amdgcn_mfma_f32_32x32x16_bf16(K1, qf1, S, 0, 0, 0); \
    S = __builtin_amdgcn_mfma_f32_32x32x16_bf16(K2, qf2, S, 0, 0, 0); \
    S = __builtin_amdgcn_mfma_f32_32x32x16_bf16(K3, qf3, S, 0, 0, 0); \
    float p_[16]; \
    const bool dg_ = (JJ) == nt - 1; \
    _Pragma("unroll") for (int r_ = 0; r_ < 16; r_++) { \
        p_[r_] = S[r_] * 0.125f; \
        const int kvl_ = (r_ & 3) + 8 * (r_ >> 2) + 4 * hi; \
        if (dg_ && kvl_ > col) p_[r_] = -3.0e38f; \
    } \
    float tm_ = p_[0]; \
    _Pragma("unroll") for (int r_ = 1; r_ < 16; r_++) tm_ = fmaxf(tm_, p_[r_]); \
    tm_ = fmaxf(tm_, __shfl_xor(tm_, 32)); \
    const float mn_ = fmaxf(mrun, tm_); \
    const float al_ = __expf(mrun - mn_); \
    mrun = mn_; \
    float ts_ = 0.f; \
    _Pragma("unroll") for (int r_ = 0; r_ < 16; r_++) { p_[r_] = __expf(p_[r_] - mn_); ts_ += p_[r_]; } \
    ts_ += __shfl_xor(ts_, 32); \
    lrun = lrun * al_ + ts_; \
    _Pragma("unroll") for (int i_ = 0; i_ < 16; i_++) { Od0[i_] *= al_; Od1[i_] *= al_; } \
    const unsigned w0_ = pk2(p_[0],  p_[1]),  w1_ = pk2(p_[2],  p_[3]); \
    const unsigned w2_ = pk2(p_[4],  p_[5]),  w3_ = pk2(p_[6],  p_[7]); \
    const unsigned w4_ = pk2(p_[8],  p_[9]),  w5_ = pk2(p_[10], p_[11]); \
    const unsigned w6_ = pk2(p_[12], p_[13]), w7_ = pk2(p_[14], p_[15]); \
    const unsigned x0_ = __shfl_xor((int)w0_, 32), x1_ = __shfl_xor((int)w1_, 32); \
    const unsigned x2_ = __shfl_xor((int)w2_, 32), x3_ = __shfl_xor((int)w3_, 32); \
    const unsigned x4_ = __shfl_xor((int)w4_, 32), x5_ = __shfl_xor((int)w5_, 32); \
    const unsigned x6_ = __shfl_xor((int)w6_, 32), x7_ = __shfl_xor((int)w7_, 32); \
    const u32x4 c0_ = hi ? (u32x4){x2_, x3_, w2_, w3_} : (u32x4){w0_, w1_, x0_, x1_}; \
    const u32x4 c1_ = hi ? (u32x4){x6_, x7_, w6_, w7_} : (u32x4){w4_, w5_, x4_, x5_}; \
    const bf16x8 pb0_ = __builtin_bit_cast(bf16x8, c0_); \
    const bf16x8 pb1_ = __builtin_bit_cast(bf16x8, c1_); \
    Od0 = __builtin_amdgcn_mfma_f32_32x32x16_bf16(V00, pb0_, Od0, 0, 0, 0); \
    Od0 = __builtin_amdgcn_mfma_f32_32x32x16_bf16(V10, pb1_, Od0, 0, 0, 0); \
    Od1 = __builtin_amdgcn_mfma_f32_32x32x16_bf16(V01, pb0_, Od1, 0, 0, 0); \
    Od1 = __builtin_amdgcn_mfma_f32_32x32x16_bf16(V11, pb1_, Od1, 0, 0, 0); \
} while (0)

__global__ __launch_bounds__(128) void attn_kernel(const bf16* __restrict__ q,
        const bf16* __restrict__ k, const bf16* __restrict__ vT,
        bf16* __restrict__ y) {
    const int tid = threadIdx.x, wid = tid >> 6, lane = tid & 63;
    const int col = lane & 31, hi = lane >> 5;
    const int bid = blockIdx.x;
    const int xcd = bid & 7, idx = bid >> 3;
    const int bh = xcd + 8 * (idx & 3);
    const int g = idx >> 2;
    const int qt = wid ? (63 - g) : g;
    const int qb = qt * 32;
    const int b = bh >> 4, h = bh & 15;

    const bf16* qB = q  + (long)b * T_ * D_ + h * HD_;
    const bf16* kB = k  + (long)b * T_ * D_ + h * HD_;
    const bf16* vB = vT + (long)b * D_ * T_ + (long)h * HD_ * T_;

    bf16x8 qf0, qf1, qf2, qf3;
    {
        const long qo = (long)(qb + col) * D_ + 8 * hi;
        qf0 = *(const bf16x8*)(qB + qo);
        qf1 = *(const bf16x8*)(qB + qo + 16);
        qf2 = *(const bf16x8*)(qB + qo + 32);
        qf3 = *(const bf16x8*)(qB + qo + 48);
    }

    f32x16 Od0, Od1;
    #pragma unroll
    for (int i = 0; i < 16; i++) { Od0[i] = 0.f; Od1[i] = 0.f; }
    float mrun = -INFINITY, lrun = 0.f;

    bf16x8 ka0, ka1, ka2, ka3, va00, va01, va10, va11;
    bf16x8 kb0, kb1, kb2, kb3, vb00, vb01, vb10, vb11;
    const int nt = qt + 1;

    int jj = 0;
    LOADKV(ka0, ka1, ka2, ka3, va00, va01, va10, va11, 0);
    while (true) {
        if (jj + 1 < nt) LOADKV(kb0, kb1, kb2, kb3, vb00, vb01, vb10, vb11, (jj + 1) * 32);
        PROC(ka0, ka1, ka2, ka3, va00, va01, va10, va11, jj);
        if (++jj >= nt) break;
        if (jj + 1 < nt) LOADKV(ka0, ka1, ka2, ka3, va00, va01, va10, va11, (jj + 1) * 32);
        PROC(kb0, kb1, kb2, kb3, vb00, vb01, vb10, vb11, jj);
        if (++jj >= nt) break;
    }

    const float inv = 1.0f / lrun;
    bf16* yr = y + (long)(b * T_ + qb + col) * D_ + h * HD_;
    #pragma unroll
    for (int rg = 0; rg < 4; rg++) {
        const int d0 = 8 * rg + 4 * hi;
        uint2 s0 = { pk2(Od0[4*rg] * inv, Od0[4*rg+1] * inv), pk2(Od0[4*rg+2] * inv, Od0[4*rg+3] * inv) };
        *(uint2*)(yr + d0) = s0;
        uint2 s1 = { pk2(Od1[4*rg] * inv, Od1[4*rg+1] * inv), pk2(Od1[4*rg+2] * inv, Od1[4*rg+3] * inv) };
        *(uint2*)(yr + 32 + d0) = s1;
    }
}

// ---------------- gates ----------------
__global__ __launch_bounds__(256) void gate1_kernel(float* __restrict__ x,
        const float* __restrict__ z, const float* __restrict__ r,
        const float* __restrict__ xa) {
    const long i = ((long)blockIdx.x * 256 + threadIdx.x) * 4;
    float4 xv = *(const float4*)(x + i);
    const float4 zv = *(const float4*)(z + i);
    const float4 rv = *(const float4*)(r + i);
    const float4 av = *(const float4*)(xa + i);
    xv.x = (1.f - zv.x) * xv.x + zv.x * tanhf(rv.x * av.x);
    xv.y = (1.f - zv.y) * xv.y + zv.y * tanhf(rv.y * av.y);
    xv.z = (1.f - zv.z) * xv.z + zv.z * tanhf(rv.z * av.z);
    xv.w = (1.f - zv.w) * xv.w + zv.w * tanhf(rv.w * av.w);
    *(float4*)(x + i) = xv;
}

__global__ __launch_bounds__(256) void gate2_kernel(float* __restrict__ x,
        const float* __restrict__ z,
        const float* __restrict__ p0, const float* __restrict__ p1,
        const float* __restrict__ p2, const float* __restrict__ p3,
        const float* __restrict__ src, const float* __restrict__ b2) {
    const long i = ((long)blockIdx.x * 256 + threadIdx.x) * 4;
    float4 xv = *(const float4*)(x + i);
    const float4 zv = *(const float4*)(z + i);
    const float4 a0 = *(const float4*)(p0 + i);
    const float4 a1 = *(const float4*)(p1 + i);
    const float4 a2 = *(const float4*)(p2 + i);
    const float4 a3 = *(const float4*)(p3 + i);
    const float4 sv = *(const float4*)(src + i);
    const float4 bb = *(const float4*)(b2 + (i & 1023));
    const float mx = a0.x + a1.x + a2.x + a3.x + bb.x;
    const float my = a0.y + a1.y + a2.y + a3.y + bb.y;
    const float mz = a0.z + a1.z + a2.z + a3.z + bb.z;
    const float mw = a0.w + a1.w + a2.w + a3.w + bb.w;
    xv.x = (1.f - zv.x) * xv.x + zv.x * mx + sv.x;
    xv.y = (1.f - zv.y) * xv.y + zv.y * my + sv.y;
    xv.z = (1.f - zv.z) * xv.z + zv.z * mz + sv.z;
    xv.w = (1.f - zv.w) * xv.w + zv.w * mw + sv.w;
    *(float4*)(x + i) = xv;
}

extern "C" void kernel_launch(void* const* d_in, const int* in_sizes, int n_in,
                              void* d_out, int out_size, void* d_ws, size_t ws_size,
                              hipStream_t stream) {
    const float* seq   = (const float*)d_in[0];
    const float* Wq    = (const float*)d_in[1];  const float* bq = (const float*)d_in[2];
    const float* Wk    = (const float*)d_in[3];  const float* bk = (const float*)d_in[4];
    const float* Wv    = (const float*)d_in[5];  const float* bv = (const float*)d_in[6];
    const float* Wo    = (const float*)d_in[7];  const float* bo = (const float*)d_in[8];
    const float* Wz    = (const float*)d_in[9];  const float* bz = (const float*)d_in[10];
    const float* Wr    = (const float*)d_in[11]; const float* br = (const float*)d_in[12];
    const float* W1    = (const float*)d_in[13]; const float* b1 = (const float*)d_in[14];
    const float* W2    = (const float*)d_in[15]; const float* b2 = (const float*)d_in[16];
    const float* ln1w  = (const float*)d_in[17]; const float* ln1b = (const float*)d_in[18];
    const float* ln2w  = (const float*)d_in[19]; const float* ln2b = (const float*)d_in[20];
    const float* lnfw  = (const float*)d_in[21]; const float* lnfb = (const float*)d_in[22];

    char* ws = (char*)d_ws;
    float* x   = (float*)(ws);                       // 16 MB
    float* z   = (float*)(ws + ((size_t)16 << 20));  // 16 MB
    float* r   = (float*)(ws + ((size_t)32 << 20));  // 16 MB (part1 after gate1)
    float* xa  = (float*)(ws + ((size_t)48 << 20));  // 16 MB (x_attn; part0 after gate1)
    bf16*  xn  = (bf16*)(ws + ((size_t)64 << 20));   // 8 MB
    bf16*  qb_ = (bf16*)(ws + ((size_t)72 << 20));   // 8 MB
    bf16*  kb_ = (bf16*)(ws + ((size_t)80 << 20));   // 8 MB
    bf16*  vtb = (bf16*)(ws + ((size_t)88 << 20));   // 8 MB
    bf16*  yb  = (bf16*)(ws + ((size_t)96 << 20));   // 8 MB
    bf16*  h1  = (bf16*)(ws + ((size_t)104 << 20));  // 32 MB
    bf16*  wt  = (bf16*)(ws + ((size_t)136 << 20));  // 36 MB weight pool
    float* pt2 = (float*)(ws + ((size_t)172 << 20)); // 16 MB (W2 partial 2)
    float* pt3 = (float*)(ws + ((size_t)188 << 20)); // 16 MB (W2 partial 3)

    bf16* wto = wt + (5u << 20);
    bf16* wt1 = wt + (6u << 20);
    bf16* wt2 = wt + (10u << 20);

    hipMemcpyAsync(x, seq, (size_t)M_ * D_ * 4, hipMemcpyDeviceToDevice, stream);

    for (int i = 0; i < NL_; i++) {
        const long dd = (long)i * D_ * D_;
        wconv_all<<<14336, 256, 0, stream>>>(Wq + dd, Wk + dd, Wv + dd, Wz + dd,
                                             Wr + dd, Wo + dd,
                                             W1 + (long)i * D_ * DF_,
                                             W2 + (long)i * DF_ * D_, wt);
        ln_kernel<true><<<M_, 256, 0, stream>>>(x, ln1w + i * D_, ln1b + i * D_, xn);
        gemm5_256<<<320, 512, 0, stream>>>(xn, wt,
                bq + i * D_, bk + i * D_, bv + i * D_, bz + i * D_, br + i * D_,
                qb_, kb_, vtb, z, r);
        attn_kernel<<<1024, 128, 0, stream>>>(qb_, kb_, vtb, yb);
        gemmWo_kernel<<<256, 256, 0, stream>>>(yb, wto, bo + i * D_, xa);
        gate1_kernel<<<(M_ * D_) / 1024, 256, 0, stream>>>(x, z, r, xa);
        ln_kernel<true><<<M_, 256, 0, stream>>>(x, ln2w + i * D_, ln2b + i * D_, xn);
        gemmG_256<<<256, 512, 0, stream>>>(xn, wt1, b1 + i * DF_, h1);
        gemmP_256<<<256, 512, 0, stream>>>(h1, wt2, xa, r, pt2, pt3);
        gate2_kernel<<<(M_ * D_) / 1024, 256, 0, stream>>>(x, z, xa, r, pt2, pt3, seq, b2 + i * D_);
    }
    ln_kernel<false><<<M_, 256, 0, stream>>>(x, lnfw, lnfb, d_out);
}

// Round 6
// 1932.772 us; speedup vs baseline: 2.4243x; 1.0187x over previous
//
#include <hip/hip_runtime.h>
#include <hip/hip_bf16.h>
#include <math.h>

#define B_ 2
#define T_ 2048
#define D_ 1024
#define H_ 16
#define NL_ 6
#define DF_ 4096
#define HD_ 64
#define M_ (B_*T_)

typedef __bf16 bf16;
typedef __attribute__((ext_vector_type(8))) __bf16 bf16x8;
typedef __attribute__((ext_vector_type(4))) float f32x4;
typedef __attribute__((ext_vector_type(16))) float f32x16;
typedef __attribute__((ext_vector_type(4))) unsigned u32x4;

#define BAR() __builtin_amdgcn_s_barrier()
#define LGKM0() asm volatile("s_waitcnt lgkmcnt(0)" ::: "memory")
#define VMC(n) asm volatile("s_waitcnt vmcnt(" #n ")" ::: "memory")

__device__ __forceinline__ void gload_lds16(const void* g, void* l) {
    __builtin_amdgcn_global_load_lds((const __attribute__((address_space(1))) void*)g,
                                     (__attribute__((address_space(3))) void*)l, 16, 0, 0);
}

__device__ __forceinline__ unsigned pk2(float a, float b) {
    bf16 lo = (bf16)a, hb = (bf16)b;
    return (unsigned)__builtin_bit_cast(unsigned short, lo) |
           ((unsigned)__builtin_bit_cast(unsigned short, hb) << 16);
}

// ---------------- LayerNorm ----------------
template<bool OUT_BF16>
__global__ __launch_bounds__(256) void ln_kernel(const float* __restrict__ x,
        const float* __restrict__ w, const float* __restrict__ b,
        void* __restrict__ out) {
    const int row = blockIdx.x;
    const int t = threadIdx.x;
    const float4 xv = *(const float4*)(x + (long)row * D_ + t * 4);
    float s  = xv.x + xv.y + xv.z + xv.w;
    float sq = xv.x*xv.x + xv.y*xv.y + xv.z*xv.z + xv.w*xv.w;
    #pragma unroll
    for (int m = 32; m; m >>= 1) { s += __shfl_xor(s, m); sq += __shfl_xor(sq, m); }
    __shared__ float red[8];
    const int wid = t >> 6, lid = t & 63;
    if (lid == 0) { red[wid] = s; red[wid + 4] = sq; }
    __syncthreads();
    s  = red[0] + red[1] + red[2] + red[3];
    sq = red[4] + red[5] + red[6] + red[7];
    const float mu   = s * (1.0f / D_);
    const float var  = sq * (1.0f / D_) - mu * mu;
    const float rstd = rsqrtf(var + 1e-5f);
    const float4 wv = *(const float4*)(w + t * 4);
    const float4 bv = *(const float4*)(b + t * 4);
    float o0 = (xv.x - mu) * rstd * wv.x + bv.x;
    float o1 = (xv.y - mu) * rstd * wv.y + bv.y;
    float o2 = (xv.z - mu) * rstd * wv.z + bv.z;
    float o3 = (xv.w - mu) * rstd * wv.w + bv.w;
    if (OUT_BF16) {
        bf16* o = (bf16*)out + (long)row * D_ + t * 4;
        o[0] = (bf16)o0; o[1] = (bf16)o1; o[2] = (bf16)o2; o[3] = (bf16)o3;
    } else {
        float* o = (float*)out + (long)row * D_ + t * 4;
        o[0] = o0; o[1] = o1; o[2] = o2; o[3] = o3;
    }
}

// ------------- merged weight convert+transpose for one layer -------------
__global__ __launch_bounds__(256) void wconv_all(
        const float* __restrict__ Wq, const float* __restrict__ Wk,
        const float* __restrict__ Wv, const float* __restrict__ Wz,
        const float* __restrict__ Wr, const float* __restrict__ Wo,
        const float* __restrict__ W1, const float* __restrict__ W2,
        bf16* __restrict__ wt) {
    __shared__ float s[32][33];
    const int bid = blockIdx.x;
    const float* src; bf16* dst; int t, K, nlg;
    if (bid < 6144) {
        const int m = bid >> 10; t = bid & 1023; K = 1024; nlg = 5;
        switch (m) {
            case 0: src = Wq; dst = wt; break;
            case 1: src = Wk; dst = wt + (1u << 20); break;
            case 2: src = Wv; dst = wt + (2u << 20); break;
            case 3: src = Wz; dst = wt + (3u << 20); break;
            case 4: src = Wr; dst = wt + (4u << 20); break;
            default: src = Wo; dst = wt + (5u << 20); break;
        }
    } else if (bid < 10240) {
        t = bid - 6144; K = 1024; nlg = 7; src = W1; dst = wt + (6u << 20);
    } else {
        t = bid - 10240; K = 4096; nlg = 5; src = W2; dst = wt + (10u << 20);
    }
    const int N = 1 << (nlg + 5);
    const int k0 = (t >> nlg) * 32, n0 = (t & ((1 << nlg) - 1)) * 32;
    const int c = threadIdx.x & 31, r8 = threadIdx.x >> 5;
    #pragma unroll
    for (int it = 0; it < 4; it++)
        s[r8 + it*8][c] = src[(long)(k0 + r8 + it*8) * N + n0 + c];
    __syncthreads();
    #pragma unroll
    for (int it = 0; it < 4; it++)
        dst[(long)(n0 + r8 + it*8) * K + k0 + c] = (bf16)s[c][r8 + it*8];
}

// =============== 256x128 2-phase GEMM core (BK=32, 8 waves, 48 KiB LDS) ===============
// LDS: A dbuf [2][256 rows][64B] at 0 (16KB/buf), B dbuf [2][128][64B] at 32768 (8KB/buf).
// Rows are 64B (16 banks) -> adjacent rows alternate bank halves. Within-row 16B chunks
// XOR-swizzled by (row&3) on both stage-source and read side.
// Stage discipline: kt+2 staged into buf[kt&1] only in ph1, which is after the BAR that
// follows every wave's LGKM0 of this tile's reads. vmcnt: 3 loads/kt, VMC(3) steady.
#define MFMA16(a, b, c) __builtin_amdgcn_mfma_f32_16x16x32_bf16(a, b, c, 0, 0, 0)

__device__ __forceinline__ void gemm128_core(const bf16* __restrict__ A, const bf16* __restrict__ Bt,
        const int Ks, const int NT, const int m0, const int n0, char* lds, f32x4 (&acc)[4][4]) {
    const int tid = threadIdx.x;
    const int lane = tid & 63, w = tid >> 6;
    const int wm = w >> 1, wn = w & 1;
    const int cl = lane & 15, gl = lane >> 4;
    const int srow = lane >> 2;
    const int sxc = (((lane & 3) ^ (srow & 3)) << 3);   // pre-swizzled src chunk (elements)
    const bf16* pa0 = A  + (size_t)(m0 + w * 32 + srow) * Ks + sxc;
    const bf16* pa1 = pa0 + (size_t)16 * Ks;
    const bf16* pb  = Bt + (size_t)(n0 + w * 16 + srow) * Ks + sxc;
    char* laA = lds + w * 2048;
    char* laB = lds + 32768 + w * 1024;

#define STG(KT, BUF) do { \
    gload_lds16(pa0 + (size_t)(KT) * 32, laA + (BUF) * 16384); \
    gload_lds16(pa1 + (size_t)(KT) * 32, laA + (BUF) * 16384 + 1024); \
    gload_lds16(pb  + (size_t)(KT) * 32, laB + (BUF) * 8192); } while (0)

    STG(0, 0); STG(1, 1);
    VMC(3);
    BAR();

    const int xo  = ((gl ^ (cl & 3)) << 4);
    const int rdA = (wm * 64 + cl) * 64 + xo;    // + mi*1024, + buf*16384
    const int rdB = (wn * 64 + cl) * 64 + xo;    // + ni*1024, + buf*8192 (+32768)

    for (int kt = 0; kt < NT; ++kt) {
        const int buf = kt & 1;
        const char* sA = lds + buf * 16384;
        const char* sB = lds + 32768 + buf * 8192;
        bf16x8 a[4], b[4];
        // ---- ph0: read all frags; barrier; mfma mi0-1
        #pragma unroll
        for (int mi = 0; mi < 4; mi++) a[mi] = *(const bf16x8*)(sA + rdA + mi * 1024);
        #pragma unroll
        for (int ni = 0; ni < 4; ni++) b[ni] = *(const bf16x8*)(sB + rdB + ni * 1024);
        BAR(); LGKM0();
        __builtin_amdgcn_s_setprio(1);
        #pragma unroll
        for (int mi = 0; mi < 2; mi++)
            #pragma unroll
            for (int ni = 0; ni < 4; ni++)
                acc[mi][ni] = MFMA16(a[mi], b[ni], acc[mi][ni]);
        __builtin_amdgcn_s_setprio(0);
        BAR();
        // ---- ph1: stage kt+2 into buf[kt&1] (safe: all reads of this buf retired); mfma mi2-3
        if (kt + 2 < NT) STG(kt + 2, buf);
        __builtin_amdgcn_s_setprio(1);
        #pragma unroll
        for (int mi = 2; mi < 4; mi++)
            #pragma unroll
            for (int ni = 0; ni < 4; ni++)
                acc[mi][ni] = MFMA16(a[mi], b[ni], acc[mi][ni]);
        __builtin_amdgcn_s_setprio(0);
        if (kt + 2 < NT)      { VMC(3); }
        else if (kt + 1 < NT) { VMC(0); }
        BAR();
    }
#undef STG
}

// ---- gemm5: xn[4096,1024] @ wt[5120,1024]^T, segmented epilogue. grid 640 ----
__global__ __launch_bounds__(512, 4) void gemm5_k(const bf16* __restrict__ A, const bf16* __restrict__ Bt,
        const float* __restrict__ bq, const float* __restrict__ bk, const float* __restrict__ bvv,
        const float* __restrict__ bz, const float* __restrict__ br,
        bf16* __restrict__ oq, bf16* __restrict__ ok, bf16* __restrict__ ov,
        float* __restrict__ oz, float* __restrict__ orr) {
    __shared__ __align__(16) char lds[49152];
    int bid = blockIdx.x;
    bid = (bid & 7) * 80 + (bid >> 3);
    const int m0 = (bid / 40) * 256, n0 = (bid % 40) * 128;
    f32x4 acc[4][4];
    #pragma unroll
    for (int i = 0; i < 4; i++)
        #pragma unroll
        for (int j = 0; j < 4; j++) acc[i][j] = (f32x4){0.f, 0.f, 0.f, 0.f};
    gemm128_core(A, Bt, 1024, 32, m0, n0, lds, acc);
    const int tid = threadIdx.x, lane = tid & 63, w = tid >> 6;
    const int wm = w >> 1, wn = w & 1, cl = lane & 15, gl = lane >> 4;
    const int seg = n0 >> 10;
    const int lc0 = (n0 & 1023) + wn * 64;
    const float* bias; int mode; void* outp;
    switch (seg) {
        case 0:  bias = bq;  mode = 0; outp = oq;  break;
        case 1:  bias = bk;  mode = 0; outp = ok;  break;
        case 2:  bias = bvv; mode = 1; outp = ov;  break;
        case 3:  bias = bz;  mode = 2; outp = oz;  break;
        default: bias = br;  mode = 2; outp = orr; break;
    }
    #pragma unroll
    for (int mi = 0; mi < 4; mi++) {
        #pragma unroll
        for (int ni = 0; ni < 4; ni++) {
            const int lcol = lc0 + ni * 16 + cl;
            const float bv = bias[lcol];
            #pragma unroll
            for (int r = 0; r < 4; r++) {
                const int row = m0 + wm * 64 + mi * 16 + gl * 4 + r;
                const float v = acc[mi][ni][r] + bv;
                if (mode == 0) {
                    ((bf16*)outp)[(long)row * 1024 + lcol] = (bf16)v;
                } else if (mode == 1) {
                    ((bf16*)outp)[((long)(row >> 11) * 1024 + lcol) * T_ + (row & 2047)] = (bf16)v;
                } else {
                    ((float*)outp)[(long)row * 1024 + lcol] = 1.0f / (1.0f + __expf(-v));
                }
            }
        }
    }
}

// ---- W1: xn[4096,1024] @ wt1[4096,1024]^T, gelu -> bf16 h1. grid 512 ----
__global__ __launch_bounds__(512, 4) void gemmG_k(const bf16* __restrict__ A, const bf16* __restrict__ Bt,
        const float* __restrict__ bias, bf16* __restrict__ out) {
    __shared__ __align__(16) char lds[49152];
    int bid = blockIdx.x;
    bid = (bid & 7) * 64 + (bid >> 3);
    const int m0 = (bid >> 5) * 256, n0 = (bid & 31) * 128;
    f32x4 acc[4][4];
    #pragma unroll
    for (int i = 0; i < 4; i++)
        #pragma unroll
        for (int j = 0; j < 4; j++) acc[i][j] = (f32x4){0.f, 0.f, 0.f, 0.f};
    gemm128_core(A, Bt, 1024, 32, m0, n0, lds, acc);
    const int tid = threadIdx.x, lane = tid & 63, w = tid >> 6;
    const int wm = w >> 1, wn = w & 1, cl = lane & 15, gl = lane >> 4;
    #pragma unroll
    for (int mi = 0; mi < 4; mi++) {
        #pragma unroll
        for (int ni = 0; ni < 4; ni++) {
            const int col = n0 + wn * 64 + ni * 16 + cl;
            const float bv = bias[col];
            #pragma unroll
            for (int r = 0; r < 4; r++) {
                const int row = m0 + wm * 64 + mi * 16 + gl * 4 + r;
                float v = acc[mi][ni][r] + bv;
                v = 0.5f * v * (1.0f + erff(v * 0.70710678118f));
                out[(long)row * DF_ + col] = (bf16)v;
            }
        }
    }
}

// ---- W2 split-K=4: h1[4096,4096] @ wt2[1024,4096]^T -> 4 f32 partials. grid 512 ----
__global__ __launch_bounds__(512, 4) void gemmP_k(const bf16* __restrict__ A, const bf16* __restrict__ Bt,
        float* __restrict__ p0, float* __restrict__ p1, float* __restrict__ p2, float* __restrict__ p3) {
    __shared__ __align__(16) char lds[49152];
    int bid = blockIdx.x;
    bid = (bid & 7) * 64 + (bid >> 3);
    const int mt = bid >> 5, s = (bid >> 3) & 3, ntl = bid & 7;
    const int m0 = mt * 256, n0 = ntl * 128;
    f32x4 acc[4][4];
    #pragma unroll
    for (int i = 0; i < 4; i++)
        #pragma unroll
        for (int j = 0; j < 4; j++) acc[i][j] = (f32x4){0.f, 0.f, 0.f, 0.f};
    gemm128_core(A + s * 1024, Bt + s * 1024, 4096, 32, m0, n0, lds, acc);
    float* outp = (s == 0) ? p0 : (s == 1) ? p1 : (s == 2) ? p2 : p3;
    const int tid = threadIdx.x, lane = tid & 63, w = tid >> 6;
    const int wm = w >> 1, wn = w & 1, cl = lane & 15, gl = lane >> 4;
    #pragma unroll
    for (int mi = 0; mi < 4; mi++) {
        #pragma unroll
        for (int ni = 0; ni < 4; ni++) {
            const int col = n0 + wn * 64 + ni * 16 + cl;
            #pragma unroll
            for (int r = 0; r < 4; r++) {
                const int row = m0 + wm * 64 + mi * 16 + gl * 4 + r;
                outp[(long)row * 1024 + col] = acc[mi][ni][r];
            }
        }
    }
}

// ---------------- old 128^2 GEMM (Wo only) ----------------
__global__ __launch_bounds__(256) void gemmWo_kernel(const bf16* __restrict__ A,
        const bf16* __restrict__ Bt, const float* __restrict__ bias,
        float* __restrict__ out) {
    __shared__ bf16 sA[128 * 32];
    __shared__ bf16 sB[128 * 32];
    const int tid = threadIdx.x;
    int bid = blockIdx.x;
    bid = (bid & 7) * 32 + (bid >> 3);
    const int m0 = (bid >> 3) * 128, n0 = (bid & 7) * 128;
    f32x4 acc[4][4];
    #pragma unroll
    for (int i = 0; i < 4; i++)
        #pragma unroll
        for (int j = 0; j < 4; j++) acc[i][j] = (f32x4){0.f, 0.f, 0.f, 0.f};
    const int lane = tid & 63, w = tid >> 6;
    const int wr = (w >> 1) * 64, wc = (w & 1) * 64;
    const int cl = lane & 15, gl = lane >> 4;
    const int srow = tid >> 2, skoff = (tid & 3) * 8;
    const bf16* ga = A  + (long)(m0 + srow) * D_ + skoff;
    const bf16* gb = Bt + (long)(n0 + srow) * D_ + skoff;
    char* sAc = (char*)sA;
    char* sBc = (char*)sB;
    const int wb = w * 1024;
    for (int k0 = 0; k0 < D_; k0 += 32) {
        if (k0) __syncthreads();
        gload_lds16(ga + k0,            sAc + wb);
        gload_lds16(ga + 64 * D_ + k0,  sAc + 4096 + wb);
        gload_lds16(gb + k0,            sBc + wb);
        gload_lds16(gb + 64 * D_ + k0,  sBc + 4096 + wb);
        __syncthreads();
        bf16x8 af[4], bfr[4];
        #pragma unroll
        for (int i = 0; i < 4; i++) af[i]  = *(const bf16x8*)(sA + (wr + i*16 + cl) * 32 + 8 * gl);
        #pragma unroll
        for (int j = 0; j < 4; j++) bfr[j] = *(const bf16x8*)(sB + (wc + j*16 + cl) * 32 + 8 * gl);
        #pragma unroll
        for (int i = 0; i < 4; i++)
            #pragma unroll
            for (int j = 0; j < 4; j++)
                acc[i][j] = MFMA16(af[i], bfr[j], acc[i][j]);
    }
    #pragma unroll
    for (int i = 0; i < 4; i++) {
        #pragma unroll
        for (int j = 0; j < 4; j++) {
            const int gcol = n0 + wc + j * 16 + cl;
            const float bv = bias[gcol];
            #pragma unroll
            for (int r = 0; r < 4; r++) {
                const int grow = m0 + wr + i * 16 + gl * 4 + r;
                out[(long)grow * D_ + gcol] = acc[i][j][r] + bv;
            }
        }
    }
}

// ---------------- Flash attention (unchanged) ----------------
#define LOADKV(K0,K1,K2,K3,V00,V01,V10,V11,KVB) do { \
    const long kro_ = (long)((KVB) + col) * D_ + 8 * hi; \
    K0 = *(const bf16x8*)(kB + kro_); \
    K1 = *(const bf16x8*)(kB + kro_ + 16); \
    K2 = *(const bf16x8*)(kB + kro_ + 32); \
    K3 = *(const bf16x8*)(kB + kro_ + 48); \
    const long vro_ = (long)col * T_ + (KVB) + 8 * hi; \
    V00 = *(const bf16x8*)(vB + vro_); \
    V10 = *(const bf16x8*)(vB + vro_ + 16); \
    V01 = *(const bf16x8*)(vB + vro_ + (long)32 * T_); \
    V11 = *(const bf16x8*)(vB + vro_ + (long)32 * T_ + 16); \
} while (0)

#define PROC(K0,K1,K2,K3,V00,V01,V10,V11,JJ) do { \
    f32x16 S; \
    _Pragma("unroll") for (int i_ = 0; i_ < 16; i_++) S[i_] = 0.f; \
    S = __builtin_amdgcn_mfma_f32_32x32x16_bf16(K0, qf0, S, 0, 0, 0); \
    S = __builtin_amdgcn_mfma_f32_32x32x16_bf16(K1, qf1, S, 0, 0, 0); \
    S = __builtin_amdgcn_mfma_f32_32x32x16_bf16(K2, qf2, S, 0, 0, 0); \
    S = __builtin_amdgcn_mfma_f32_32x32x16_bf16(K3, qf3, S, 0, 0, 0); \
    float p_[16]; \
    const bool dg_ = (JJ) == nt - 1; \
    _Pragma("unroll") for (int r_ = 0; r_ < 16; r_++) { \
        p_[r_] = S[r_] * 0.125f; \
        const int kvl_ = (r_ & 3) + 8 * (r_ >> 2) + 4 * hi; \
        if (dg_ && kvl_ > col) p_[r_] = -3.0e38f; \
    } \
    float tm_ = p_[0]; \
    _Pragma("unroll") for (int r_ = 1; r_ < 16; r_++) tm_ = fmaxf(tm_, p_[r_]); \
    tm_ = fmaxf(tm_, __shfl_xor(tm_, 32)); \
    const float mn_ = fmaxf(mrun, tm_); \
    const float al_ = __expf(mrun - mn_); \
    mrun = mn_; \
    float ts_ = 0.f; \
    _Pragma("unroll") for (int r_ = 0; r_ < 16; r_++) { p_[r_] = __expf(p_[r_] - mn_); ts_ += p_[r_]; } \
    ts_ += __shfl_xor(ts_, 32); \
    lrun = lrun * al_ + ts_; \
    _Pragma("unroll") for (int i_ = 0; i_ < 16; i_++) { Od0[i_] *= al_; Od1[i_] *= al_; } \
    const unsigned w0_ = pk2(p_[0],  p_[1]),  w1_ = pk2(p_[2],  p_[3]); \
    const unsigned w2_ = pk2(p_[4],  p_[5]),  w3_ = pk2(p_[6],  p_[7]); \
    const unsigned w4_ = pk2(p_[8],  p_[9]),  w5_ = pk2(p_[10], p_[11]); \
    const unsigned w6_ = pk2(p_[12], p_[13]), w7_ = pk2(p_[14], p_[15]); \
    const unsigned x0_ = __shfl_xor((int)w0_, 32), x1_ = __shfl_xor((int)w1_, 32); \
    const unsigned x2_ = __shfl_xor((int)w2_, 32), x3_ = __shfl_xor((int)w3_, 32); \
    const unsigned x4_ = __shfl_xor((int)w4_, 32), x5_ = __shfl_xor((int)w5_, 32); \
    const unsigned x6_ = __shfl_xor((int)w6_, 32), x7_ = __shfl_xor((int)w7_, 32); \
    const u32x4 c0_ = hi ? (u32x4){x2_, x3_, w2_, w3_} : (u32x4){w0_, w1_, x0_, x1_}; \
    const u32x4 c1_ = hi ? (u32x4){x6_, x7_, w6_, w7_} : (u32x4){w4_, w5_, x4_, x5_}; \
    const bf16x8 pb0_ = __builtin_bit_cast(bf16x8, c0_); \
    const bf16x8 pb1_ = __builtin_bit_cast(bf16x8, c1_); \
    Od0 = __builtin_amdgcn_mfma_f32_32x32x16_bf16(V00, pb0_, Od0, 0, 0, 0); \
    Od0 = __builtin_amdgcn_mfma_f32_32x32x16_bf16(V10, pb1_, Od0, 0, 0, 0); \
    Od1 = __builtin_amdgcn_mfma_f32_32x32x16_bf16(V01, pb0_, Od1, 0, 0, 0); \
    Od1 = __builtin_amdgcn_mfma_f32_32x32x16_bf16(V11, pb1_, Od1, 0, 0, 0); \
} while (0)

__global__ __launch_bounds__(128) void attn_kernel(const bf16* __restrict__ q,
        const bf16* __restrict__ k, const bf16* __restrict__ vT,
        bf16* __restrict__ y) {
    const int tid = threadIdx.x, wid = tid >> 6, lane = tid & 63;
    const int col = lane & 31, hi = lane >> 5;
    const int bid = blockIdx.x;
    const int xcd = bid & 7, idx = bid >> 3;
    const int bh = xcd + 8 * (idx & 3);
    const int g = idx >> 2;
    const int qt = wid ? (63 - g) : g;
    const int qb = qt * 32;
    const int b = bh >> 4, h = bh & 15;

    const bf16* qB = q  + (long)b * T_ * D_ + h * HD_;
    const bf16* kB = k  + (long)b * T_ * D_ + h * HD_;
    const bf16* vB = vT + (long)b * D_ * T_ + (long)h * HD_ * T_;

    bf16x8 qf0, qf1, qf2, qf3;
    {
        const long qo = (long)(qb + col) * D_ + 8 * hi;
        qf0 = *(const bf16x8*)(qB + qo);
        qf1 = *(const bf16x8*)(qB + qo + 16);
        qf2 = *(const bf16x8*)(qB + qo + 32);
        qf3 = *(const bf16x8*)(qB + qo + 48);
    }

    f32x16 Od0, Od1;
    #pragma unroll
    for (int i = 0; i < 16; i++) { Od0[i] = 0.f; Od1[i] = 0.f; }
    float mrun = -INFINITY, lrun = 0.f;

    bf16x8 ka0, ka1, ka2, ka3, va00, va01, va10, va11;
    bf16x8 kb0, kb1, kb2, kb3, vb00, vb01, vb10, vb11;
    const int nt = qt + 1;

    int jj = 0;
    LOADKV(ka0, ka1, ka2, ka3, va00, va01, va10, va11, 0);
    while (true) {
        if (jj + 1 < nt) LOADKV(kb0, kb1, kb2, kb3, vb00, vb01, vb10, vb11, (jj + 1) * 32);
        PROC(ka0, ka1, ka2, ka3, va00, va01, va10, va11, jj);
        if (++jj >= nt) break;
        if (jj + 1 < nt) LOADKV(ka0, ka1, ka2, ka3, va00, va01, va10, va11, (jj + 1) * 32);
        PROC(kb0, kb1, kb2, kb3, vb00, vb01, vb10, vb11, jj);
        if (++jj >= nt) break;
    }

    const float inv = 1.0f / lrun;
    bf16* yr = y + (long)(b * T_ + qb + col) * D_ + h * HD_;
    #pragma unroll
    for (int rg = 0; rg < 4; rg++) {
        const int d0 = 8 * rg + 4 * hi;
        uint2 s0 = { pk2(Od0[4*rg] * inv, Od0[4*rg+1] * inv), pk2(Od0[4*rg+2] * inv, Od0[4*rg+3] * inv) };
        *(uint2*)(yr + d0) = s0;
        uint2 s1 = { pk2(Od1[4*rg] * inv, Od1[4*rg+1] * inv), pk2(Od1[4*rg+2] * inv, Od1[4*rg+3] * inv) };
        *(uint2*)(yr + 32 + d0) = s1;
    }
}

// ---------------- gates ----------------
__global__ __launch_bounds__(256) void gate1_kernel(float* __restrict__ x,
        const float* __restrict__ z, const float* __restrict__ r,
        const float* __restrict__ xa) {
    const long i = ((long)blockIdx.x * 256 + threadIdx.x) * 4;
    float4 xv = *(const float4*)(x + i);
    const float4 zv = *(const float4*)(z + i);
    const float4 rv = *(const float4*)(r + i);
    const float4 av = *(const float4*)(xa + i);
    xv.x = (1.f - zv.x) * xv.x + zv.x * tanhf(rv.x * av.x);
    xv.y = (1.f - zv.y) * xv.y + zv.y * tanhf(rv.y * av.y);
    xv.z = (1.f - zv.z) * xv.z + zv.z * tanhf(rv.z * av.z);
    xv.w = (1.f - zv.w) * xv.w + zv.w * tanhf(rv.w * av.w);
    *(float4*)(x + i) = xv;
}

__global__ __launch_bounds__(256) void gate2_kernel(float* __restrict__ x,
        const float* __restrict__ z,
        const float* __restrict__ p0, const float* __restrict__ p1,
        const float* __restrict__ p2, const float* __restrict__ p3,
        const float* __restrict__ src, const float* __restrict__ b2) {
    const long i = ((long)blockIdx.x * 256 + threadIdx.x) * 4;
    float4 xv = *(const float4*)(x + i);
    const float4 zv = *(const float4*)(z + i);
    const float4 a0 = *(const float4*)(p0 + i);
    const float4 a1 = *(const float4*)(p1 + i);
    const float4 a2 = *(const float4*)(p2 + i);
    const float4 a3 = *(const float4*)(p3 + i);
    const float4 sv = *(const float4*)(src + i);
    const float4 bb = *(const float4*)(b2 + (i & 1023));
    const float mx = a0.x + a1.x + a2.x + a3.x + bb.x;
    const float my = a0.y + a1.y + a2.y + a3.y + bb.y;
    const float mz = a0.z + a1.z + a2.z + a3.z + bb.z;
    const float mw = a0.w + a1.w + a2.w + a3.w + bb.w;
    xv.x = (1.f - zv.x) * xv.x + zv.x * mx + sv.x;
    xv.y = (1.f - zv.y) * xv.y + zv.y * my + sv.y;
    xv.z = (1.f - zv.z) * xv.z + zv.z * mz + sv.z;
    xv.w = (1.f - zv.w) * xv.w + zv.w * mw + sv.w;
    *(float4*)(x + i) = xv;
}

extern "C" void kernel_launch(void* const* d_in, const int* in_sizes, int n_in,
                              void* d_out, int out_size, void* d_ws, size_t ws_size,
                              hipStream_t stream) {
    const float* seq   = (const float*)d_in[0];
    const float* Wq    = (const float*)d_in[1];  const float* bq = (const float*)d_in[2];
    const float* Wk    = (const float*)d_in[3];  const float* bk = (const float*)d_in[4];
    const float* Wv    = (const float*)d_in[5];  const float* bv = (const float*)d_in[6];
    const float* Wo    = (const float*)d_in[7];  const float* bo = (const float*)d_in[8];
    const float* Wz    = (const float*)d_in[9];  const float* bz = (const float*)d_in[10];
    const float* Wr    = (const float*)d_in[11]; const float* br = (const float*)d_in[12];
    const float* W1    = (const float*)d_in[13]; const float* b1 = (const float*)d_in[14];
    const float* W2    = (const float*)d_in[15]; const float* b2 = (const float*)d_in[16];
    const float* ln1w  = (const float*)d_in[17]; const float* ln1b = (const float*)d_in[18];
    const float* ln2w  = (const float*)d_in[19]; const float* ln2b = (const float*)d_in[20];
    const float* lnfw  = (const float*)d_in[21]; const float* lnfb = (const float*)d_in[22];

    char* ws = (char*)d_ws;
    float* x   = (float*)(ws);                       // 16 MB
    float* z   = (float*)(ws + ((size_t)16 << 20));  // 16 MB
    float* r   = (float*)(ws + ((size_t)32 << 20));  // 16 MB (W2 partial 1)
    float* xa  = (float*)(ws + ((size_t)48 << 20));  // 16 MB (x_attn; W2 partial 0)
    bf16*  xn  = (bf16*)(ws + ((size_t)64 << 20));   // 8 MB
    bf16*  qb_ = (bf16*)(ws + ((size_t)72 << 20));   // 8 MB
    bf16*  kb_ = (bf16*)(ws + ((size_t)80 << 20));   // 8 MB
    bf16*  vtb = (bf16*)(ws + ((size_t)88 << 20));   // 8 MB
    bf16*  yb  = (bf16*)(ws + ((size_t)96 << 20));   // 8 MB
    bf16*  h1  = (bf16*)(ws + ((size_t)104 << 20));  // 32 MB
    bf16*  wt  = (bf16*)(ws + ((size_t)136 << 20));  // 36 MB weight pool
    float* pt2 = (float*)(ws + ((size_t)172 << 20)); // 16 MB (W2 partial 2)
    float* pt3 = (float*)(ws + ((size_t)188 << 20)); // 16 MB (W2 partial 3)

    bf16* wto = wt + (5u << 20);
    bf16* wt1 = wt + (6u << 20);
    bf16* wt2 = wt + (10u << 20);

    hipMemcpyAsync(x, seq, (size_t)M_ * D_ * 4, hipMemcpyDeviceToDevice, stream);

    for (int i = 0; i < NL_; i++) {
        const long dd = (long)i * D_ * D_;
        wconv_all<<<14336, 256, 0, stream>>>(Wq + dd, Wk + dd, Wv + dd, Wz + dd,
                                             Wr + dd, Wo + dd,
                                             W1 + (long)i * D_ * DF_,
                                             W2 + (long)i * DF_ * D_, wt);
        ln_kernel<true><<<M_, 256, 0, stream>>>(x, ln1w + i * D_, ln1b + i * D_, xn);
        gemm5_k<<<640, 512, 0, stream>>>(xn, wt,
                bq + i * D_, bk + i * D_, bv + i * D_, bz + i * D_, br + i * D_,
                qb_, kb_, vtb, z, r);
        attn_kernel<<<1024, 128, 0, stream>>>(qb_, kb_, vtb, yb);
        gemmWo_kernel<<<256, 256, 0, stream>>>(yb, wto, bo + i * D_, xa);
        gate1_kernel<<<(M_ * D_) / 1024, 256, 0, stream>>>(x, z, r, xa);
        ln_kernel<true><<<M_, 256, 0, stream>>>(x, ln2w + i * D_, ln2b + i * D_, xn);
        gemmG_k<<<512, 512, 0, stream>>>(xn, wt1, b1 + i * DF_, h1);
        gemmP_k<<<512, 512, 0, stream>>>(h1, wt2, xa, r, pt2, pt3);
        gate2_kernel<<<(M_ * D_) / 1024, 256, 0, stream>>>(x, z, xa, r, pt2, pt3, seq, b2 + i * D_);
    }
    ln_kernel<false><<<M_, 256, 0, stream>>>(x, lnfw, lnfb, d_out);
}

// Round 7
// 1794.674 us; speedup vs baseline: 2.6108x; 1.0769x over previous
//
#include <hip/hip_runtime.h>
#include <hip/hip_bf16.h>
#include <math.h>

#define B_ 2
#define T_ 2048
#define D_ 1024
#define H_ 16
#define NL_ 6
#define DF_ 4096
#define HD_ 64
#define M_ (B_*T_)

typedef __bf16 bf16;
typedef __attribute__((ext_vector_type(8))) __bf16 bf16x8;
typedef __attribute__((ext_vector_type(4))) float f32x4;
typedef __attribute__((ext_vector_type(16))) float f32x16;
typedef __attribute__((ext_vector_type(4))) unsigned u32x4;

#define BAR() __builtin_amdgcn_s_barrier()
#define LGKM0() asm volatile("s_waitcnt lgkmcnt(0)" ::: "memory")
#define VMC(n) asm volatile("s_waitcnt vmcnt(" #n ")" ::: "memory")

__device__ __forceinline__ void gload_lds16(const void* g, void* l) {
    __builtin_amdgcn_global_load_lds((const __attribute__((address_space(1))) void*)g,
                                     (__attribute__((address_space(3))) void*)l, 16, 0, 0);
}

__device__ __forceinline__ unsigned pk2(float a, float b) {
    bf16 lo = (bf16)a, hb = (bf16)b;
    return (unsigned)__builtin_bit_cast(unsigned short, lo) |
           ((unsigned)__builtin_bit_cast(unsigned short, hb) << 16);
}

// ---------------- LayerNorm ----------------
template<bool OUT_BF16>
__global__ __launch_bounds__(256) void ln_kernel(const float* __restrict__ x,
        const float* __restrict__ w, const float* __restrict__ b,
        void* __restrict__ out) {
    const int row = blockIdx.x;
    const int t = threadIdx.x;
    const float4 xv = *(const float4*)(x + (long)row * D_ + t * 4);
    float s  = xv.x + xv.y + xv.z + xv.w;
    float sq = xv.x*xv.x + xv.y*xv.y + xv.z*xv.z + xv.w*xv.w;
    #pragma unroll
    for (int m = 32; m; m >>= 1) { s += __shfl_xor(s, m); sq += __shfl_xor(sq, m); }
    __shared__ float red[8];
    const int wid = t >> 6, lid = t & 63;
    if (lid == 0) { red[wid] = s; red[wid + 4] = sq; }
    __syncthreads();
    s  = red[0] + red[1] + red[2] + red[3];
    sq = red[4] + red[5] + red[6] + red[7];
    const float mu   = s * (1.0f / D_);
    const float var  = sq * (1.0f / D_) - mu * mu;
    const float rstd = rsqrtf(var + 1e-5f);
    const float4 wv = *(const float4*)(w + t * 4);
    const float4 bv = *(const float4*)(b + t * 4);
    float o0 = (xv.x - mu) * rstd * wv.x + bv.x;
    float o1 = (xv.y - mu) * rstd * wv.y + bv.y;
    float o2 = (xv.z - mu) * rstd * wv.z + bv.z;
    float o3 = (xv.w - mu) * rstd * wv.w + bv.w;
    if (OUT_BF16) {
        bf16* o = (bf16*)out + (long)row * D_ + t * 4;
        o[0] = (bf16)o0; o[1] = (bf16)o1; o[2] = (bf16)o2; o[3] = (bf16)o3;
    } else {
        float* o = (float*)out + (long)row * D_ + t * 4;
        o[0] = o0; o[1] = o1; o[2] = o2; o[3] = o3;
    }
}

// ------------- merged weight convert+transpose for one layer -------------
__global__ __launch_bounds__(256) void wconv_all(
        const float* __restrict__ Wq, const float* __restrict__ Wk,
        const float* __restrict__ Wv, const float* __restrict__ Wz,
        const float* __restrict__ Wr, const float* __restrict__ Wo,
        const float* __restrict__ W1, const float* __restrict__ W2,
        bf16* __restrict__ wt) {
    __shared__ float s[32][33];
    const int bid = blockIdx.x;
    const float* src; bf16* dst; int t, K, nlg;
    if (bid < 6144) {
        const int m = bid >> 10; t = bid & 1023; K = 1024; nlg = 5;
        switch (m) {
            case 0: src = Wq; dst = wt; break;
            case 1: src = Wk; dst = wt + (1u << 20); break;
            case 2: src = Wv; dst = wt + (2u << 20); break;
            case 3: src = Wz; dst = wt + (3u << 20); break;
            case 4: src = Wr; dst = wt + (4u << 20); break;
            default: src = Wo; dst = wt + (5u << 20); break;
        }
    } else if (bid < 10240) {
        t = bid - 6144; K = 1024; nlg = 7; src = W1; dst = wt + (6u << 20);
    } else {
        t = bid - 10240; K = 4096; nlg = 5; src = W2; dst = wt + (10u << 20);
    }
    const int N = 1 << (nlg + 5);
    const int k0 = (t >> nlg) * 32, n0 = (t & ((1 << nlg) - 1)) * 32;
    const int c = threadIdx.x & 31, r8 = threadIdx.x >> 5;
    #pragma unroll
    for (int it = 0; it < 4; it++)
        s[r8 + it*8][c] = src[(long)(k0 + r8 + it*8) * N + n0 + c];
    __syncthreads();
    #pragma unroll
    for (int it = 0; it < 4; it++)
        dst[(long)(n0 + r8 + it*8) * K + k0 + c] = (bf16)s[c][r8 + it*8];
}

// =============== 256x128 2-phase GEMM core (BK=32, 8 waves, 48 KiB LDS) ===============
#define MFMA16(a, b, c) __builtin_amdgcn_mfma_f32_16x16x32_bf16(a, b, c, 0, 0, 0)
#define MFMA32(a, b, c) __builtin_amdgcn_mfma_f32_32x32x16_bf16(a, b, c, 0, 0, 0)

__device__ __forceinline__ void gemm128_core(const bf16* __restrict__ A, const bf16* __restrict__ Bt,
        const int Ks, const int NT, const int m0, const int n0, char* lds, f32x4 (&acc)[4][4]) {
    const int tid = threadIdx.x;
    const int lane = tid & 63, w = tid >> 6;
    const int wm = w >> 1, wn = w & 1;
    const int cl = lane & 15, gl = lane >> 4;
    const int srow = lane >> 2;
    const int sxc = (((lane & 3) ^ (srow & 3)) << 3);   // pre-swizzled src chunk (elements)
    const bf16* pa0 = A  + (size_t)(m0 + w * 32 + srow) * Ks + sxc;
    const bf16* pa1 = pa0 + (size_t)16 * Ks;
    const bf16* pb  = Bt + (size_t)(n0 + w * 16 + srow) * Ks + sxc;
    char* laA = lds + w * 2048;
    char* laB = lds + 32768 + w * 1024;

#define STG(KT, BUF) do { \
    gload_lds16(pa0 + (size_t)(KT) * 32, laA + (BUF) * 16384); \
    gload_lds16(pa1 + (size_t)(KT) * 32, laA + (BUF) * 16384 + 1024); \
    gload_lds16(pb  + (size_t)(KT) * 32, laB + (BUF) * 8192); } while (0)

    STG(0, 0); STG(1, 1);
    VMC(3);
    BAR();

    const int xo  = ((gl ^ (cl & 3)) << 4);
    const int rdA = (wm * 64 + cl) * 64 + xo;
    const int rdB = (wn * 64 + cl) * 64 + xo;

    for (int kt = 0; kt < NT; ++kt) {
        const int buf = kt & 1;
        const char* sA = lds + buf * 16384;
        const char* sB = lds + 32768 + buf * 8192;
        bf16x8 a[4], b[4];
        #pragma unroll
        for (int mi = 0; mi < 4; mi++) a[mi] = *(const bf16x8*)(sA + rdA + mi * 1024);
        #pragma unroll
        for (int ni = 0; ni < 4; ni++) b[ni] = *(const bf16x8*)(sB + rdB + ni * 1024);
        BAR(); LGKM0();
        __builtin_amdgcn_s_setprio(1);
        #pragma unroll
        for (int mi = 0; mi < 2; mi++)
            #pragma unroll
            for (int ni = 0; ni < 4; ni++)
                acc[mi][ni] = MFMA16(a[mi], b[ni], acc[mi][ni]);
        __builtin_amdgcn_s_setprio(0);
        BAR();
        if (kt + 2 < NT) STG(kt + 2, buf);
        __builtin_amdgcn_s_setprio(1);
        #pragma unroll
        for (int mi = 2; mi < 4; mi++)
            #pragma unroll
            for (int ni = 0; ni < 4; ni++)
                acc[mi][ni] = MFMA16(a[mi], b[ni], acc[mi][ni]);
        __builtin_amdgcn_s_setprio(0);
        if (kt + 2 < NT)      { VMC(3); }
        else if (kt + 1 < NT) { VMC(0); }
        BAR();
    }
#undef STG
}

// ---- gemm5: xn[4096,1024] @ wt[5120,1024]^T, segmented epilogue. grid 640 ----
__global__ __launch_bounds__(512, 4) void gemm5_k(const bf16* __restrict__ A, const bf16* __restrict__ Bt,
        const float* __restrict__ bq, const float* __restrict__ bk, const float* __restrict__ bvv,
        const float* __restrict__ bz, const float* __restrict__ br,
        bf16* __restrict__ oq, bf16* __restrict__ ok, bf16* __restrict__ ov,
        float* __restrict__ oz, float* __restrict__ orr) {
    __shared__ __align__(16) char lds[49152];
    int bid = blockIdx.x;
    bid = (bid & 7) * 80 + (bid >> 3);
    const int m0 = (bid / 40) * 256, n0 = (bid % 40) * 128;
    f32x4 acc[4][4];
    #pragma unroll
    for (int i = 0; i < 4; i++)
        #pragma unroll
        for (int j = 0; j < 4; j++) acc[i][j] = (f32x4){0.f, 0.f, 0.f, 0.f};
    gemm128_core(A, Bt, 1024, 32, m0, n0, lds, acc);
    const int tid = threadIdx.x, lane = tid & 63, w = tid >> 6;
    const int wm = w >> 1, wn = w & 1, cl = lane & 15, gl = lane >> 4;
    const int seg = n0 >> 10;
    const int lc0 = (n0 & 1023) + wn * 64;
    const float* bias; int mode; void* outp;
    switch (seg) {
        case 0:  bias = bq;  mode = 0; outp = oq;  break;
        case 1:  bias = bk;  mode = 0; outp = ok;  break;
        case 2:  bias = bvv; mode = 1; outp = ov;  break;
        case 3:  bias = bz;  mode = 2; outp = oz;  break;
        default: bias = br;  mode = 2; outp = orr; break;
    }
    const float scl = (seg == 0) ? 0.125f : 1.0f;   // pre-scale Q for attention
    #pragma unroll
    for (int mi = 0; mi < 4; mi++) {
        #pragma unroll
        for (int ni = 0; ni < 4; ni++) {
            const int lcol = lc0 + ni * 16 + cl;
            const float bv = bias[lcol];
            #pragma unroll
            for (int r = 0; r < 4; r++) {
                const int row = m0 + wm * 64 + mi * 16 + gl * 4 + r;
                const float v = (acc[mi][ni][r] + bv) * scl;
                if (mode == 0) {
                    ((bf16*)outp)[(long)row * 1024 + lcol] = (bf16)v;
                } else if (mode == 1) {
                    ((bf16*)outp)[((long)(row >> 11) * 1024 + lcol) * T_ + (row & 2047)] = (bf16)v;
                } else {
                    ((float*)outp)[(long)row * 1024 + lcol] = 1.0f / (1.0f + __expf(-v));
                }
            }
        }
    }
}

// ---- W1: gelu -> bf16 h1. grid 512 ----
__global__ __launch_bounds__(512, 4) void gemmG_k(const bf16* __restrict__ A, const bf16* __restrict__ Bt,
        const float* __restrict__ bias, bf16* __restrict__ out) {
    __shared__ __align__(16) char lds[49152];
    int bid = blockIdx.x;
    bid = (bid & 7) * 64 + (bid >> 3);
    const int m0 = (bid >> 5) * 256, n0 = (bid & 31) * 128;
    f32x4 acc[4][4];
    #pragma unroll
    for (int i = 0; i < 4; i++)
        #pragma unroll
        for (int j = 0; j < 4; j++) acc[i][j] = (f32x4){0.f, 0.f, 0.f, 0.f};
    gemm128_core(A, Bt, 1024, 32, m0, n0, lds, acc);
    const int tid = threadIdx.x, lane = tid & 63, w = tid >> 6;
    const int wm = w >> 1, wn = w & 1, cl = lane & 15, gl = lane >> 4;
    #pragma unroll
    for (int mi = 0; mi < 4; mi++) {
        #pragma unroll
        for (int ni = 0; ni < 4; ni++) {
            const int col = n0 + wn * 64 + ni * 16 + cl;
            const float bv = bias[col];
            #pragma unroll
            for (int r = 0; r < 4; r++) {
                const int row = m0 + wm * 64 + mi * 16 + gl * 4 + r;
                float v = acc[mi][ni][r] + bv;
                v = 0.5f * v * (1.0f + erff(v * 0.70710678118f));
                out[(long)row * DF_ + col] = (bf16)v;
            }
        }
    }
}

// ---- W2 split-K=4 -> 4 f32 partials. grid 512 ----
__global__ __launch_bounds__(512, 4) void gemmP_k(const bf16* __restrict__ A, const bf16* __restrict__ Bt,
        float* __restrict__ p0, float* __restrict__ p1, float* __restrict__ p2, float* __restrict__ p3) {
    __shared__ __align__(16) char lds[49152];
    int bid = blockIdx.x;
    bid = (bid & 7) * 64 + (bid >> 3);
    const int mt = bid >> 5, s = (bid >> 3) & 3, ntl = bid & 7;
    const int m0 = mt * 256, n0 = ntl * 128;
    f32x4 acc[4][4];
    #pragma unroll
    for (int i = 0; i < 4; i++)
        #pragma unroll
        for (int j = 0; j < 4; j++) acc[i][j] = (f32x4){0.f, 0.f, 0.f, 0.f};
    gemm128_core(A + s * 1024, Bt + s * 1024, 4096, 32, m0, n0, lds, acc);
    float* outp = (s == 0) ? p0 : (s == 1) ? p1 : (s == 2) ? p2 : p3;
    const int tid = threadIdx.x, lane = tid & 63, w = tid >> 6;
    const int wm = w >> 1, wn = w & 1, cl = lane & 15, gl = lane >> 4;
    #pragma unroll
    for (int mi = 0; mi < 4; mi++) {
        #pragma unroll
        for (int ni = 0; ni < 4; ni++) {
            const int col = n0 + wn * 64 + ni * 16 + cl;
            #pragma unroll
            for (int r = 0; r < 4; r++) {
                const int row = m0 + wm * 64 + mi * 16 + gl * 4 + r;
                outp[(long)row * 1024 + col] = acc[mi][ni][r];
            }
        }
    }
}

// ---------------- old 128^2 GEMM (Wo only) ----------------
__global__ __launch_bounds__(256) void gemmWo_kernel(const bf16* __restrict__ A,
        const bf16* __restrict__ Bt, const float* __restrict__ bias,
        float* __restrict__ out) {
    __shared__ bf16 sA[128 * 32];
    __shared__ bf16 sB[128 * 32];
    const int tid = threadIdx.x;
    int bid = blockIdx.x;
    bid = (bid & 7) * 32 + (bid >> 3);
    const int m0 = (bid >> 3) * 128, n0 = (bid & 7) * 128;
    f32x4 acc[4][4];
    #pragma unroll
    for (int i = 0; i < 4; i++)
        #pragma unroll
        for (int j = 0; j < 4; j++) acc[i][j] = (f32x4){0.f, 0.f, 0.f, 0.f};
    const int lane = tid & 63, w = tid >> 6;
    const int wr = (w >> 1) * 64, wc = (w & 1) * 64;
    const int cl = lane & 15, gl = lane >> 4;
    const int srow = tid >> 2, skoff = (tid & 3) * 8;
    const bf16* ga = A  + (long)(m0 + srow) * D_ + skoff;
    const bf16* gb = Bt + (long)(n0 + srow) * D_ + skoff;
    char* sAc = (char*)sA;
    char* sBc = (char*)sB;
    const int wb = w * 1024;
    for (int k0 = 0; k0 < D_; k0 += 32) {
        if (k0) __syncthreads();
        gload_lds16(ga + k0,            sAc + wb);
        gload_lds16(ga + 64 * D_ + k0,  sAc + 4096 + wb);
        gload_lds16(gb + k0,            sBc + wb);
        gload_lds16(gb + 64 * D_ + k0,  sBc + 4096 + wb);
        __syncthreads();
        bf16x8 af[4], bfr[4];
        #pragma unroll
        for (int i = 0; i < 4; i++) af[i]  = *(const bf16x8*)(sA + (wr + i*16 + cl) * 32 + 8 * gl);
        #pragma unroll
        for (int j = 0; j < 4; j++) bfr[j] = *(const bf16x8*)(sB + (wc + j*16 + cl) * 32 + 8 * gl);
        #pragma unroll
        for (int i = 0; i < 4; i++)
            #pragma unroll
            for (int j = 0; j < 4; j++)
                acc[i][j] = MFMA16(af[i], bfr[j], acc[i][j]);
    }
    #pragma unroll
    for (int i = 0; i < 4; i++) {
        #pragma unroll
        for (int j = 0; j < 4; j++) {
            const int gcol = n0 + wc + j * 16 + cl;
            const float bv = bias[gcol];
            #pragma unroll
            for (int r = 0; r < 4; r++) {
                const int grow = m0 + wr + i * 16 + gl * 4 + r;
                out[(long)grow * D_ + gcol] = acc[i][j][r] + bv;
            }
        }
    }
}

// ======= Flash attention v2: LDS-staged K/V, 4 waves/block share the KV stream =======
// Block: (bh, qt=4g..4g+3). Per 64-kv phase: stage K[64][64]+V^T[64][64] (coalesced
// global_load_lds, linear dest, (row&7)-XOR pre-swizzled source), double-buffered,
// counted vmcnt(4). Stage j+2 into buf[j&1] strictly after the BAR ending phase j reads.
__global__ __launch_bounds__(256, 2) void attn_kernel(const bf16* __restrict__ q,
        const bf16* __restrict__ k, const bf16* __restrict__ vT,
        bf16* __restrict__ y) {
    __shared__ __align__(16) char lds[32768];   // sK[2][8KB] @0, sV[2][8KB] @16384
    const int tid = threadIdx.x, wid = tid >> 6, lane = tid & 63;
    const int col = lane & 31, hi = lane >> 5;
    const int bid = blockIdx.x;
    const int xcd = bid & 7, idx = bid >> 3;
    const int bh = xcd + 8 * (idx & 3);
    const int sg = idx >> 2;                                   // 0..15
    const int g = (sg & 1) ? (sg >> 1) : (15 - (sg >> 1));     // big/small interleave
    const int qt = 4 * g + wid;
    const int qb = qt * 32;
    const int b = bh >> 4, h = bh & 15;
    const int NP = 2 * g + 2;              // phases streamed by the block
    const int nt64 = (qt >> 1) + 1;        // phases this wave participates in

    const bf16* qB = q  + (size_t)b * T_ * D_ + h * HD_;
    const bf16* kB = k  + (size_t)b * T_ * D_ + h * HD_;
    const bf16* vB = vT + (size_t)b * D_ * T_ + (size_t)h * HD_ * T_;

    // staging: lane covers (row = wid*8 + lane>>3, chunk = lane&7); dest linear lane*16
    const int sr = wid * 8 + (lane >> 3);
    const int sc = lane & 7;
    const bf16* kS0 = kB + (size_t)sr * D_ + 8 * (sc ^ (sr & 7));
    const bf16* kS1 = kS0 + (size_t)32 * D_;
    const bf16* vS0 = vB + (size_t)sr * T_ + 8 * (sc ^ (sr & 7));
    const bf16* vS1 = vS0 + (size_t)32 * T_;
    char* dK = lds + wid * 1024;
    char* dV = lds + 16384 + wid * 1024;

#define ASTG(J, BUF) do { \
    const size_t ko_ = (size_t)(J) * 64 * D_; \
    const size_t vo_ = (size_t)(J) * 64; \
    gload_lds16(kS0 + ko_, dK + (BUF) * 8192); \
    gload_lds16(kS1 + ko_, dK + (BUF) * 8192 + 4096); \
    gload_lds16(vS0 + vo_, dV + (BUF) * 8192); \
    gload_lds16(vS1 + vo_, dV + (BUF) * 8192 + 4096); } while (0)

    // Q fragments (already scaled by 1/8 in gemm5 epilogue)
    bf16x8 qf0, qf1, qf2, qf3;
    {
        const bf16* qp = qB + (size_t)(qb + col) * D_ + 8 * hi;
        qf0 = *(const bf16x8*)(qp);
        qf1 = *(const bf16x8*)(qp + 16);
        qf2 = *(const bf16x8*)(qp + 32);
        qf3 = *(const bf16x8*)(qp + 48);
    }

    f32x16 Od0, Od1;
    #pragma unroll
    for (int i = 0; i < 16; i++) { Od0[i] = 0.f; Od1[i] = 0.f; }
    float mrun = -INFINITY, lrun = 0.f;

    ASTG(0, 0);
    ASTG(1, 1);
    VMC(4);
    BAR();

    const int swz = col & 7;
    for (int j = 0; j < NP; ++j) {
        const int buf = j & 1;
        if (j < nt64) {
            const char* bK = lds + buf * 8192;
            const char* bV = lds + 16384 + buf * 8192;
            bf16x8 kf0[4], kf1[4], vf0[4], vf1[4];
            #pragma unroll
            for (int cs = 0; cs < 4; cs++) {
                const int ch = ((hi + 2 * cs) ^ swz) * 16;
                kf0[cs] = *(const bf16x8*)(bK + col * 128 + ch);
                kf1[cs] = *(const bf16x8*)(bK + (col + 32) * 128 + ch);
                vf0[cs] = *(const bf16x8*)(bV + col * 128 + ch);
                vf1[cs] = *(const bf16x8*)(bV + (col + 32) * 128 + ch);
            }
            f32x16 S0, S1;
            #pragma unroll
            for (int i = 0; i < 16; i++) { S0[i] = 0.f; S1[i] = 0.f; }
            S0 = MFMA32(kf0[0], qf0, S0); S0 = MFMA32(kf0[1], qf1, S0);
            S0 = MFMA32(kf0[2], qf2, S0); S0 = MFMA32(kf0[3], qf3, S0);
            S1 = MFMA32(kf1[0], qf0, S1); S1 = MFMA32(kf1[1], qf1, S1);
            S1 = MFMA32(kf1[2], qf2, S1); S1 = MFMA32(kf1[3], qf3, S1);
            float p[32];
            #pragma unroll
            for (int r = 0; r < 16; r++) { p[r] = S0[r]; p[16 + r] = S1[r]; }
            if (j == nt64 - 1) {       // diagonal phase: causal mask
                const int qr = qb + col;
                #pragma unroll
                for (int r = 0; r < 32; r++) {
                    const int kvl = 64 * j + 32 * (r >> 4)
                                  + (r & 3) + 8 * ((r & 15) >> 2) + 4 * hi;
                    if (kvl > qr) p[r] = -3.0e38f;
                }
            }
            float tm = p[0];
            #pragma unroll
            for (int r = 1; r < 32; r++) tm = fmaxf(tm, p[r]);
            tm = fmaxf(tm, __shfl_xor(tm, 32));
            if (!__all(tm <= mrun + 8.f)) {     // defer-max (THR=8)
                const float mn = fmaxf(mrun, tm);
                const float al = __expf(mrun - mn);
                lrun *= al;
                #pragma unroll
                for (int i = 0; i < 16; i++) { Od0[i] *= al; Od1[i] *= al; }
                mrun = mn;
            }
            float ts = 0.f;
            #pragma unroll
            for (int r = 0; r < 32; r++) { p[r] = __expf(p[r] - mrun); ts += p[r]; }
            ts += __shfl_xor(ts, 32);
            lrun += ts;
            bf16x8 pbf[4];
            #pragma unroll
            for (int t = 0; t < 2; t++) {
                const unsigned pw0 = pk2(p[16*t+0],  p[16*t+1]),  pw1 = pk2(p[16*t+2],  p[16*t+3]);
                const unsigned pw2 = pk2(p[16*t+4],  p[16*t+5]),  pw3 = pk2(p[16*t+6],  p[16*t+7]);
                const unsigned pw4 = pk2(p[16*t+8],  p[16*t+9]),  pw5 = pk2(p[16*t+10], p[16*t+11]);
                const unsigned pw6 = pk2(p[16*t+12], p[16*t+13]), pw7 = pk2(p[16*t+14], p[16*t+15]);
                const unsigned px0 = __shfl_xor((int)pw0, 32), px1 = __shfl_xor((int)pw1, 32);
                const unsigned px2 = __shfl_xor((int)pw2, 32), px3 = __shfl_xor((int)pw3, 32);
                const unsigned px4 = __shfl_xor((int)pw4, 32), px5 = __shfl_xor((int)pw5, 32);
                const unsigned px6 = __shfl_xor((int)pw6, 32), px7 = __shfl_xor((int)pw7, 32);
                const u32x4 c0 = hi ? (u32x4){px2, px3, pw2, pw3} : (u32x4){pw0, pw1, px0, px1};
                const u32x4 c1 = hi ? (u32x4){px6, px7, pw6, pw7} : (u32x4){pw4, pw5, px4, px5};
                pbf[2*t]   = __builtin_bit_cast(bf16x8, c0);
                pbf[2*t+1] = __builtin_bit_cast(bf16x8, c1);
            }
            #pragma unroll
            for (int f = 0; f < 4; f++) {
                Od0 = MFMA32(vf0[f], pbf[f], Od0);
                Od1 = MFMA32(vf1[f], pbf[f], Od1);
            }
        }
        BAR();                               // all waves done reading buf[j&1]
        if (j + 2 < NP) { ASTG(j + 2, buf); VMC(4); }
        else            { VMC(0); }
        BAR();                               // buf[(j+1)&1] staged
    }

    const float inv = 1.0f / lrun;
    bf16* yr = y + (size_t)(b * T_ + qb + col) * D_ + h * HD_;
    #pragma unroll
    for (int rg = 0; rg < 4; rg++) {
        const int d0 = 8 * rg + 4 * hi;
        uint2 s0 = { pk2(Od0[4*rg] * inv, Od0[4*rg+1] * inv), pk2(Od0[4*rg+2] * inv, Od0[4*rg+3] * inv) };
        *(uint2*)(yr + d0) = s0;
        uint2 s1 = { pk2(Od1[4*rg] * inv, Od1[4*rg+1] * inv), pk2(Od1[4*rg+2] * inv, Od1[4*rg+3] * inv) };
        *(uint2*)(yr + 32 + d0) = s1;
    }
#undef ASTG
}

// ---------------- gates ----------------
__global__ __launch_bounds__(256) void gate1_kernel(float* __restrict__ x,
        const float* __restrict__ z, const float* __restrict__ r,
        const float* __restrict__ xa) {
    const long i = ((long)blockIdx.x * 256 + threadIdx.x) * 4;
    float4 xv = *(const float4*)(x + i);
    const float4 zv = *(const float4*)(z + i);
    const float4 rv = *(const float4*)(r + i);
    const float4 av = *(const float4*)(xa + i);
    xv.x = (1.f - zv.x) * xv.x + zv.x * tanhf(rv.x * av.x);
    xv.y = (1.f - zv.y) * xv.y + zv.y * tanhf(rv.y * av.y);
    xv.z = (1.f - zv.z) * xv.z + zv.z * tanhf(rv.z * av.z);
    xv.w = (1.f - zv.w) * xv.w + zv.w * tanhf(rv.w * av.w);
    *(float4*)(x + i) = xv;
}

__global__ __launch_bounds__(256) void gate2_kernel(float* __restrict__ x,
        const float* __restrict__ z,
        const float* __restrict__ p0, const float* __restrict__ p1,
        const float* __restrict__ p2, const float* __restrict__ p3,
        const float* __restrict__ src, const float* __restrict__ b2) {
    const long i = ((long)blockIdx.x * 256 + threadIdx.x) * 4;
    float4 xv = *(const float4*)(x + i);
    const float4 zv = *(const float4*)(z + i);
    const float4 a0 = *(const float4*)(p0 + i);
    const float4 a1 = *(const float4*)(p1 + i);
    const float4 a2 = *(const float4*)(p2 + i);
    const float4 a3 = *(const float4*)(p3 + i);
    const float4 sv = *(const float4*)(src + i);
    const float4 bb = *(const float4*)(b2 + (i & 1023));
    const float mx = a0.x + a1.x + a2.x + a3.x + bb.x;
    const float my = a0.y + a1.y + a2.y + a3.y + bb.y;
    const float mz = a0.z + a1.z + a2.z + a3.z + bb.z;
    const float mw = a0.w + a1.w + a2.w + a3.w + bb.w;
    xv.x = (1.f - zv.x) * xv.x + zv.x * mx + sv.x;
    xv.y = (1.f - zv.y) * xv.y + zv.y * my + sv.y;
    xv.z = (1.f - zv.z) * xv.z + zv.z * mz + sv.z;
    xv.w = (1.f - zv.w) * xv.w + zv.w * mw + sv.w;
    *(float4*)(x + i) = xv;
}

extern "C" void kernel_launch(void* const* d_in, const int* in_sizes, int n_in,
                              void* d_out, int out_size, void* d_ws, size_t ws_size,
                              hipStream_t stream) {
    const float* seq   = (const float*)d_in[0];
    const float* Wq    = (const float*)d_in[1];  const float* bq = (const float*)d_in[2];
    const float* Wk    = (const float*)d_in[3];  const float* bk = (const float*)d_in[4];
    const float* Wv    = (const float*)d_in[5];  const float* bv = (const float*)d_in[6];
    const float* Wo    = (const float*)d_in[7];  const float* bo = (const float*)d_in[8];
    const float* Wz    = (const float*)d_in[9];  const float* bz = (const float*)d_in[10];
    const float* Wr    = (const float*)d_in[11]; const float* br = (const float*)d_in[12];
    const float* W1    = (const float*)d_in[13]; const float* b1 = (const float*)d_in[14];
    const float* W2    = (const float*)d_in[15]; const float* b2 = (const float*)d_in[16];
    const float* ln1w  = (const float*)d_in[17]; const float* ln1b = (const float*)d_in[18];
    const float* ln2w  = (const float*)d_in[19]; const float* ln2b = (const float*)d_in[20];
    const float* lnfw  = (const float*)d_in[21]; const float* lnfb = (const float*)d_in[22];

    char* ws = (char*)d_ws;
    float* x   = (float*)(ws);                       // 16 MB
    float* z   = (float*)(ws + ((size_t)16 << 20));  // 16 MB
    float* r   = (float*)(ws + ((size_t)32 << 20));  // 16 MB (W2 partial 1)
    float* xa  = (float*)(ws + ((size_t)48 << 20));  // 16 MB (x_attn; W2 partial 0)
    bf16*  xn  = (bf16*)(ws + ((size_t)64 << 20));   // 8 MB
    bf16*  qb_ = (bf16*)(ws + ((size_t)72 << 20));   // 8 MB
    bf16*  kb_ = (bf16*)(ws + ((size_t)80 << 20));   // 8 MB
    bf16*  vtb = (bf16*)(ws + ((size_t)88 << 20));   // 8 MB
    bf16*  yb  = (bf16*)(ws + ((size_t)96 << 20));   // 8 MB
    bf16*  h1  = (bf16*)(ws + ((size_t)104 << 20));  // 32 MB
    bf16*  wt  = (bf16*)(ws + ((size_t)136 << 20));  // 36 MB weight pool
    float* pt2 = (float*)(ws + ((size_t)172 << 20)); // 16 MB (W2 partial 2)
    float* pt3 = (float*)(ws + ((size_t)188 << 20)); // 16 MB (W2 partial 3)

    bf16* wto = wt + (5u << 20);
    bf16* wt1 = wt + (6u << 20);
    bf16* wt2 = wt + (10u << 20);

    hipMemcpyAsync(x, seq, (size_t)M_ * D_ * 4, hipMemcpyDeviceToDevice, stream);

    for (int i = 0; i < NL_; i++) {
        const long dd = (long)i * D_ * D_;
        wconv_all<<<14336, 256, 0, stream>>>(Wq + dd, Wk + dd, Wv + dd, Wz + dd,
                                             Wr + dd, Wo + dd,
                                             W1 + (long)i * D_ * DF_,
                                             W2 + (long)i * DF_ * D_, wt);
        ln_kernel<true><<<M_, 256, 0, stream>>>(x, ln1w + i * D_, ln1b + i * D_, xn);
        gemm5_k<<<640, 512, 0, stream>>>(xn, wt,
                bq + i * D_, bk + i * D_, bv + i * D_, bz + i * D_, br + i * D_,
                qb_, kb_, vtb, z, r);
        attn_kernel<<<512, 256, 0, stream>>>(qb_, kb_, vtb, yb);
        gemmWo_kernel<<<256, 256, 0, stream>>>(yb, wto, bo + i * D_, xa);
        gate1_kernel<<<(M_ * D_) / 1024, 256, 0, stream>>>(x, z, r, xa);
        ln_kernel<true><<<M_, 256, 0, stream>>>(x, ln2w + i * D_, ln2b + i * D_, xn);
        gemmG_k<<<512, 512, 0, stream>>>(xn, wt1, b1 + i * DF_, h1);
        gemmP_k<<<512, 512, 0, stream>>>(h1, wt2, xa, r, pt2, pt3);
        gate2_kernel<<<(M_ * D_) / 1024, 256, 0, stream>>>(x, z, xa, r, pt2, pt3, seq, b2 + i * D_);
    }
    ln_kernel<false><<<M_, 256, 0, stream>>>(x, lnfw, lnfb, d_out);
}

// Round 8
// 1792.573 us; speedup vs baseline: 2.6139x; 1.0012x over previous
//
#include <hip/hip_runtime.h>
#include <hip/hip_bf16.h>
#include <math.h>

#define B_ 2
#define T_ 2048
#define D_ 1024
#define H_ 16
#define NL_ 6
#define DF_ 4096
#define HD_ 64
#define M_ (B_*T_)

typedef __bf16 bf16;
typedef __attribute__((ext_vector_type(8))) __bf16 bf16x8;
typedef __attribute__((ext_vector_type(4))) float f32x4;
typedef __attribute__((ext_vector_type(16))) float f32x16;
typedef __attribute__((ext_vector_type(4))) unsigned u32x4;

#define BAR() __builtin_amdgcn_s_barrier()
#define LGKM0() asm volatile("s_waitcnt lgkmcnt(0)" ::: "memory")
#define VMC(n) asm volatile("s_waitcnt vmcnt(" #n ")" ::: "memory")

__device__ __forceinline__ void gload_lds16(const void* g, void* l) {
    __builtin_amdgcn_global_load_lds((const __attribute__((address_space(1))) void*)g,
                                     (__attribute__((address_space(3))) void*)l, 16, 0, 0);
}

__device__ __forceinline__ unsigned pk2(float a, float b) {
    bf16 lo = (bf16)a, hb = (bf16)b;
    return (unsigned)__builtin_bit_cast(unsigned short, lo) |
           ((unsigned)__builtin_bit_cast(unsigned short, hb) << 16);
}

// ---------------- LayerNorm ----------------
template<bool OUT_BF16>
__global__ __launch_bounds__(256) void ln_kernel(const float* __restrict__ x,
        const float* __restrict__ w, const float* __restrict__ b,
        void* __restrict__ out) {
    const int row = blockIdx.x;
    const int t = threadIdx.x;
    const float4 xv = *(const float4*)(x + (long)row * D_ + t * 4);
    float s  = xv.x + xv.y + xv.z + xv.w;
    float sq = xv.x*xv.x + xv.y*xv.y + xv.z*xv.z + xv.w*xv.w;
    #pragma unroll
    for (int m = 32; m; m >>= 1) { s += __shfl_xor(s, m); sq += __shfl_xor(sq, m); }
    __shared__ float red[8];
    const int wid = t >> 6, lid = t & 63;
    if (lid == 0) { red[wid] = s; red[wid + 4] = sq; }
    __syncthreads();
    s  = red[0] + red[1] + red[2] + red[3];
    sq = red[4] + red[5] + red[6] + red[7];
    const float mu   = s * (1.0f / D_);
    const float var  = sq * (1.0f / D_) - mu * mu;
    const float rstd = rsqrtf(var + 1e-5f);
    const float4 wv = *(const float4*)(w + t * 4);
    const float4 bv = *(const float4*)(b + t * 4);
    float o0 = (xv.x - mu) * rstd * wv.x + bv.x;
    float o1 = (xv.y - mu) * rstd * wv.y + bv.y;
    float o2 = (xv.z - mu) * rstd * wv.z + bv.z;
    float o3 = (xv.w - mu) * rstd * wv.w + bv.w;
    if (OUT_BF16) {
        bf16* o = (bf16*)out + (long)row * D_ + t * 4;
        o[0] = (bf16)o0; o[1] = (bf16)o1; o[2] = (bf16)o2; o[3] = (bf16)o3;
    } else {
        float* o = (float*)out + (long)row * D_ + t * 4;
        o[0] = o0; o[1] = o1; o[2] = o2; o[3] = o3;
    }
}

// ------------- merged weight convert+transpose for one layer -------------
__global__ __launch_bounds__(256) void wconv_all(
        const float* __restrict__ Wq, const float* __restrict__ Wk,
        const float* __restrict__ Wv, const float* __restrict__ Wz,
        const float* __restrict__ Wr, const float* __restrict__ Wo,
        const float* __restrict__ W1, const float* __restrict__ W2,
        bf16* __restrict__ wt) {
    __shared__ float s[32][33];
    const int bid = blockIdx.x;
    const float* src; bf16* dst; int t, K, nlg;
    if (bid < 6144) {
        const int m = bid >> 10; t = bid & 1023; K = 1024; nlg = 5;
        switch (m) {
            case 0: src = Wq; dst = wt; break;
            case 1: src = Wk; dst = wt + (1u << 20); break;
            case 2: src = Wv; dst = wt + (2u << 20); break;
            case 3: src = Wz; dst = wt + (3u << 20); break;
            case 4: src = Wr; dst = wt + (4u << 20); break;
            default: src = Wo; dst = wt + (5u << 20); break;
        }
    } else if (bid < 10240) {
        t = bid - 6144; K = 1024; nlg = 7; src = W1; dst = wt + (6u << 20);
    } else {
        t = bid - 10240; K = 4096; nlg = 5; src = W2; dst = wt + (10u << 20);
    }
    const int N = 1 << (nlg + 5);
    const int k0 = (t >> nlg) * 32, n0 = (t & ((1 << nlg) - 1)) * 32;
    const int c = threadIdx.x & 31, r8 = threadIdx.x >> 5;
    #pragma unroll
    for (int it = 0; it < 4; it++)
        s[r8 + it*8][c] = src[(long)(k0 + r8 + it*8) * N + n0 + c];
    __syncthreads();
    #pragma unroll
    for (int it = 0; it < 4; it++)
        dst[(long)(n0 + r8 + it*8) * K + k0 + c] = (bf16)s[c][r8 + it*8];
}

// =============== 256x128 2-phase GEMM core (BK=32, 8 waves, 48 KiB LDS) ===============
// 64-B rows: bank-group = row&1, so the conflict-free XOR is s(row) = (row>>1)&3
// (slot id over a quarter-wave = (cl&1,(cl>>1)&3) = cl&7 -> 8 slots x 2 lanes = free).
#define MFMA16(a, b, c) __builtin_amdgcn_mfma_f32_16x16x32_bf16(a, b, c, 0, 0, 0)
#define MFMA32(a, b, c) __builtin_amdgcn_mfma_f32_32x32x16_bf16(a, b, c, 0, 0, 0)

__device__ __forceinline__ void gemm128_core(const bf16* __restrict__ A, const bf16* __restrict__ Bt,
        const int Ks, const int NT, const int m0, const int n0, char* lds, f32x4 (&acc)[4][4]) {
    const int tid = threadIdx.x;
    const int lane = tid & 63, w = tid >> 6;
    const int wm = w >> 1, wn = w & 1;
    const int cl = lane & 15, gl = lane >> 4;
    const int srow = lane >> 2;
    const int sxc = (((lane & 3) ^ ((lane >> 3) & 3)) << 3);   // chunk ^= (row>>1)&3
    const bf16* pa0 = A  + (size_t)(m0 + w * 32 + srow) * Ks + sxc;
    const bf16* pa1 = pa0 + (size_t)16 * Ks;
    const bf16* pb  = Bt + (size_t)(n0 + w * 16 + srow) * Ks + sxc;
    char* laA = lds + w * 2048;
    char* laB = lds + 32768 + w * 1024;

#define STG(KT, BUF) do { \
    gload_lds16(pa0 + (size_t)(KT) * 32, laA + (BUF) * 16384); \
    gload_lds16(pa1 + (size_t)(KT) * 32, laA + (BUF) * 16384 + 1024); \
    gload_lds16(pb  + (size_t)(KT) * 32, laB + (BUF) * 8192); } while (0)

    STG(0, 0); STG(1, 1);
    VMC(3);
    BAR();

    const int xo  = ((gl ^ ((cl >> 1) & 3)) << 4);
    const int rdA = (wm * 64 + cl) * 64 + xo;
    const int rdB = (wn * 64 + cl) * 64 + xo;

    for (int kt = 0; kt < NT; ++kt) {
        const int buf = kt & 1;
        const char* sA = lds + buf * 16384;
        const char* sB = lds + 32768 + buf * 8192;
        bf16x8 a[4], b[4];
        #pragma unroll
        for (int mi = 0; mi < 4; mi++) a[mi] = *(const bf16x8*)(sA + rdA + mi * 1024);
        #pragma unroll
        for (int ni = 0; ni < 4; ni++) b[ni] = *(const bf16x8*)(sB + rdB + ni * 1024);
        BAR(); LGKM0();
        __builtin_amdgcn_s_setprio(1);
        #pragma unroll
        for (int mi = 0; mi < 2; mi++)
            #pragma unroll
            for (int ni = 0; ni < 4; ni++)
                acc[mi][ni] = MFMA16(a[mi], b[ni], acc[mi][ni]);
        __builtin_amdgcn_s_setprio(0);
        BAR();
        if (kt + 2 < NT) STG(kt + 2, buf);
        __builtin_amdgcn_s_setprio(1);
        #pragma unroll
        for (int mi = 2; mi < 4; mi++)
            #pragma unroll
            for (int ni = 0; ni < 4; ni++)
                acc[mi][ni] = MFMA16(a[mi], b[ni], acc[mi][ni]);
        __builtin_amdgcn_s_setprio(0);
        if (kt + 2 < NT)      { VMC(3); }
        else if (kt + 1 < NT) { VMC(0); }
        BAR();
    }
#undef STG
}

// ---- gemm5: xn[4096,1024] @ wt[5120,1024]^T, segmented epilogue. grid 640 ----
__global__ __launch_bounds__(512, 4) void gemm5_k(const bf16* __restrict__ A, const bf16* __restrict__ Bt,
        const float* __restrict__ bq, const float* __restrict__ bk, const float* __restrict__ bvv,
        const float* __restrict__ bz, const float* __restrict__ br,
        bf16* __restrict__ oq, bf16* __restrict__ ok, bf16* __restrict__ ov,
        float* __restrict__ oz, float* __restrict__ orr) {
    __shared__ __align__(16) char lds[49152];
    int bid = blockIdx.x;
    bid = (bid & 7) * 80 + (bid >> 3);
    const int m0 = (bid / 40) * 256, n0 = (bid % 40) * 128;
    f32x4 acc[4][4];
    #pragma unroll
    for (int i = 0; i < 4; i++)
        #pragma unroll
        for (int j = 0; j < 4; j++) acc[i][j] = (f32x4){0.f, 0.f, 0.f, 0.f};
    gemm128_core(A, Bt, 1024, 32, m0, n0, lds, acc);
    const int tid = threadIdx.x, lane = tid & 63, w = tid >> 6;
    const int wm = w >> 1, wn = w & 1, cl = lane & 15, gl = lane >> 4;
    const int seg = n0 >> 10;
    const int lc0 = (n0 & 1023) + wn * 64;
    const float* bias; int mode; void* outp;
    switch (seg) {
        case 0:  bias = bq;  mode = 0; outp = oq;  break;
        case 1:  bias = bk;  mode = 0; outp = ok;  break;
        case 2:  bias = bvv; mode = 1; outp = ov;  break;
        case 3:  bias = bz;  mode = 2; outp = oz;  break;
        default: bias = br;  mode = 2; outp = orr; break;
    }
    const float scl = (seg == 0) ? 0.125f : 1.0f;   // pre-scale Q for attention
    #pragma unroll
    for (int mi = 0; mi < 4; mi++) {
        #pragma unroll
        for (int ni = 0; ni < 4; ni++) {
            const int lcol = lc0 + ni * 16 + cl;
            const float bv = bias[lcol];
            #pragma unroll
            for (int r = 0; r < 4; r++) {
                const int row = m0 + wm * 64 + mi * 16 + gl * 4 + r;
                const float v = (acc[mi][ni][r] + bv) * scl;
                if (mode == 0) {
                    ((bf16*)outp)[(long)row * 1024 + lcol] = (bf16)v;
                } else if (mode == 1) {
                    ((bf16*)outp)[((long)(row >> 11) * 1024 + lcol) * T_ + (row & 2047)] = (bf16)v;
                } else {
                    ((float*)outp)[(long)row * 1024 + lcol] = 1.0f / (1.0f + __expf(-v));
                }
            }
        }
    }
}

// ---- W1: gelu -> bf16 h1. grid 512 ----
__global__ __launch_bounds__(512, 4) void gemmG_k(const bf16* __restrict__ A, const bf16* __restrict__ Bt,
        const float* __restrict__ bias, bf16* __restrict__ out) {
    __shared__ __align__(16) char lds[49152];
    int bid = blockIdx.x;
    bid = (bid & 7) * 64 + (bid >> 3);
    const int m0 = (bid >> 5) * 256, n0 = (bid & 31) * 128;
    f32x4 acc[4][4];
    #pragma unroll
    for (int i = 0; i < 4; i++)
        #pragma unroll
        for (int j = 0; j < 4; j++) acc[i][j] = (f32x4){0.f, 0.f, 0.f, 0.f};
    gemm128_core(A, Bt, 1024, 32, m0, n0, lds, acc);
    const int tid = threadIdx.x, lane = tid & 63, w = tid >> 6;
    const int wm = w >> 1, wn = w & 1, cl = lane & 15, gl = lane >> 4;
    #pragma unroll
    for (int mi = 0; mi < 4; mi++) {
        #pragma unroll
        for (int ni = 0; ni < 4; ni++) {
            const int col = n0 + wn * 64 + ni * 16 + cl;
            const float bv = bias[col];
            #pragma unroll
            for (int r = 0; r < 4; r++) {
                const int row = m0 + wm * 64 + mi * 16 + gl * 4 + r;
                float v = acc[mi][ni][r] + bv;
                v = 0.5f * v * (1.0f + erff(v * 0.70710678118f));
                out[(long)row * DF_ + col] = (bf16)v;
            }
        }
    }
}

// ---- W2 split-K=4 -> 4 f32 partials. grid 512 ----
__global__ __launch_bounds__(512, 4) void gemmP_k(const bf16* __restrict__ A, const bf16* __restrict__ Bt,
        float* __restrict__ p0, float* __restrict__ p1, float* __restrict__ p2, float* __restrict__ p3) {
    __shared__ __align__(16) char lds[49152];
    int bid = blockIdx.x;
    bid = (bid & 7) * 64 + (bid >> 3);
    const int mt = bid >> 5, s = (bid >> 3) & 3, ntl = bid & 7;
    const int m0 = mt * 256, n0 = ntl * 128;
    f32x4 acc[4][4];
    #pragma unroll
    for (int i = 0; i < 4; i++)
        #pragma unroll
        for (int j = 0; j < 4; j++) acc[i][j] = (f32x4){0.f, 0.f, 0.f, 0.f};
    gemm128_core(A + s * 1024, Bt + s * 1024, 4096, 32, m0, n0, lds, acc);
    float* outp = (s == 0) ? p0 : (s == 1) ? p1 : (s == 2) ? p2 : p3;
    const int tid = threadIdx.x, lane = tid & 63, w = tid >> 6;
    const int wm = w >> 1, wn = w & 1, cl = lane & 15, gl = lane >> 4;
    #pragma unroll
    for (int mi = 0; mi < 4; mi++) {
        #pragma unroll
        for (int ni = 0; ni < 4; ni++) {
            const int col = n0 + wn * 64 + ni * 16 + cl;
            #pragma unroll
            for (int r = 0; r < 4; r++) {
                const int row = m0 + wm * 64 + mi * 16 + gl * 4 + r;
                outp[(long)row * 1024 + col] = acc[mi][ni][r];
            }
        }
    }
}

// ---------------- Wo GEMM with fused gate1 epilogue (128^2, swizzle-fixed) ----------------
__global__ __launch_bounds__(256) void gemmWoG_kernel(const bf16* __restrict__ A,
        const bf16* __restrict__ Bt, const float* __restrict__ bias,
        float* __restrict__ x, const float* __restrict__ z, const float* __restrict__ rr) {
    __shared__ bf16 sA[128 * 32];
    __shared__ bf16 sB[128 * 32];
    const int tid = threadIdx.x;
    int bid = blockIdx.x;
    bid = (bid & 7) * 32 + (bid >> 3);
    const int m0 = (bid >> 3) * 128, n0 = (bid & 7) * 128;
    f32x4 acc[4][4];
    #pragma unroll
    for (int i = 0; i < 4; i++)
        #pragma unroll
        for (int j = 0; j < 4; j++) acc[i][j] = (f32x4){0.f, 0.f, 0.f, 0.f};
    const int lane = tid & 63, w = tid >> 6;
    const int wr = (w >> 1) * 64, wc = (w & 1) * 64;
    const int cl = lane & 15, gl = lane >> 4;
    const int srow = tid >> 2;
    const int skoff = (((tid & 3) ^ ((tid >> 3) & 3)) << 3);   // chunk ^= (row>>1)&3
    const bf16* ga = A  + (long)(m0 + srow) * D_ + skoff;
    const bf16* gb = Bt + (long)(n0 + srow) * D_ + skoff;
    char* sAc = (char*)sA;
    char* sBc = (char*)sB;
    const int wb = w * 1024;
    const int xo = ((gl ^ ((cl >> 1) & 3)) << 4);
    for (int k0 = 0; k0 < D_; k0 += 32) {
        if (k0) __syncthreads();
        gload_lds16(ga + k0,            sAc + wb);
        gload_lds16(ga + 64 * D_ + k0,  sAc + 4096 + wb);
        gload_lds16(gb + k0,            sBc + wb);
        gload_lds16(gb + 64 * D_ + k0,  sBc + 4096 + wb);
        __syncthreads();
        bf16x8 af[4], bfr[4];
        #pragma unroll
        for (int i = 0; i < 4; i++) af[i]  = *(const bf16x8*)(sAc + (wr + i*16 + cl) * 64 + xo);
        #pragma unroll
        for (int j = 0; j < 4; j++) bfr[j] = *(const bf16x8*)(sBc + (wc + j*16 + cl) * 64 + xo);
        #pragma unroll
        for (int i = 0; i < 4; i++)
            #pragma unroll
            for (int j = 0; j < 4; j++)
                acc[i][j] = MFMA16(af[i], bfr[j], acc[i][j]);
    }
    #pragma unroll
    for (int i = 0; i < 4; i++) {
        #pragma unroll
        for (int j = 0; j < 4; j++) {
            const int gcol = n0 + wc + j * 16 + cl;
            const float bv = bias[gcol];
            #pragma unroll
            for (int r = 0; r < 4; r++) {
                const int grow = m0 + wr + i * 16 + gl * 4 + r;
                const long idx = (long)grow * D_ + gcol;
                const float xa = acc[i][j][r] + bv;
                const float zv = z[idx];
                const float ht = tanhf(rr[idx] * xa);
                x[idx] = (1.f - zv) * x[idx] + zv * ht;
            }
        }
    }
}

// ======= Flash attention v2: LDS-staged K/V, 4 waves/block share the KV stream =======
__global__ __launch_bounds__(256, 2) void attn_kernel(const bf16* __restrict__ q,
        const bf16* __restrict__ k, const bf16* __restrict__ vT,
        bf16* __restrict__ y) {
    __shared__ __align__(16) char lds[32768];   // sK[2][8KB] @0, sV[2][8KB] @16384
    const int tid = threadIdx.x, wid = tid >> 6, lane = tid & 63;
    const int col = lane & 31, hi = lane >> 5;
    const int bid = blockIdx.x;
    const int xcd = bid & 7, idx = bid >> 3;
    const int bh = xcd + 8 * (idx & 3);
    const int sg = idx >> 2;                                   // 0..15
    const int g = (sg & 1) ? (sg >> 1) : (15 - (sg >> 1));     // big/small interleave
    const int qt = 4 * g + wid;
    const int qb = qt * 32;
    const int b = bh >> 4, h = bh & 15;
    const int NP = 2 * g + 2;              // phases streamed by the block
    const int nt64 = (qt >> 1) + 1;        // phases this wave participates in

    const bf16* qB = q  + (size_t)b * T_ * D_ + h * HD_;
    const bf16* kB = k  + (size_t)b * T_ * D_ + h * HD_;
    const bf16* vB = vT + (size_t)b * D_ * T_ + (size_t)h * HD_ * T_;

    const int sr = wid * 8 + (lane >> 3);
    const int sc = lane & 7;
    const bf16* kS0 = kB + (size_t)sr * D_ + 8 * (sc ^ (sr & 7));
    const bf16* kS1 = kS0 + (size_t)32 * D_;
    const bf16* vS0 = vB + (size_t)sr * T_ + 8 * (sc ^ (sr & 7));
    const bf16* vS1 = vS0 + (size_t)32 * T_;
    char* dK = lds + wid * 1024;
    char* dV = lds + 16384 + wid * 1024;

#define ASTG(J, BUF) do { \
    const size_t ko_ = (size_t)(J) * 64 * D_; \
    const size_t vo_ = (size_t)(J) * 64; \
    gload_lds16(kS0 + ko_, dK + (BUF) * 8192); \
    gload_lds16(kS1 + ko_, dK + (BUF) * 8192 + 4096); \
    gload_lds16(vS0 + vo_, dV + (BUF) * 8192); \
    gload_lds16(vS1 + vo_, dV + (BUF) * 8192 + 4096); } while (0)

    bf16x8 qf0, qf1, qf2, qf3;
    {
        const bf16* qp = qB + (size_t)(qb + col) * D_ + 8 * hi;
        qf0 = *(const bf16x8*)(qp);
        qf1 = *(const bf16x8*)(qp + 16);
        qf2 = *(const bf16x8*)(qp + 32);
        qf3 = *(const bf16x8*)(qp + 48);
    }

    f32x16 Od0, Od1;
    #pragma unroll
    for (int i = 0; i < 16; i++) { Od0[i] = 0.f; Od1[i] = 0.f; }
    float mrun = -INFINITY, lrun = 0.f;

    ASTG(0, 0);
    ASTG(1, 1);
    VMC(4);
    BAR();

    const int swz = col & 7;
    for (int j = 0; j < NP; ++j) {
        const int buf = j & 1;
        if (j < nt64) {
            const char* bK = lds + buf * 8192;
            const char* bV = lds + 16384 + buf * 8192;
            bf16x8 kf0[4], kf1[4], vf0[4], vf1[4];
            #pragma unroll
            for (int cs = 0; cs < 4; cs++) {
                const int ch = ((hi + 2 * cs) ^ swz) * 16;
                kf0[cs] = *(const bf16x8*)(bK + col * 128 + ch);
                kf1[cs] = *(const bf16x8*)(bK + (col + 32) * 128 + ch);
                vf0[cs] = *(const bf16x8*)(bV + col * 128 + ch);
                vf1[cs] = *(const bf16x8*)(bV + (col + 32) * 128 + ch);
            }
            f32x16 S0, S1;
            #pragma unroll
            for (int i = 0; i < 16; i++) { S0[i] = 0.f; S1[i] = 0.f; }
            S0 = MFMA32(kf0[0], qf0, S0); S0 = MFMA32(kf0[1], qf1, S0);
            S0 = MFMA32(kf0[2], qf2, S0); S0 = MFMA32(kf0[3], qf3, S0);
            S1 = MFMA32(kf1[0], qf0, S1); S1 = MFMA32(kf1[1], qf1, S1);
            S1 = MFMA32(kf1[2], qf2, S1); S1 = MFMA32(kf1[3], qf3, S1);
            float p[32];
            #pragma unroll
            for (int r = 0; r < 16; r++) { p[r] = S0[r]; p[16 + r] = S1[r]; }
            if (j == nt64 - 1) {
                const int qr = qb + col;
                #pragma unroll
                for (int r = 0; r < 32; r++) {
                    const int kvl = 64 * j + 32 * (r >> 4)
                                  + (r & 3) + 8 * ((r & 15) >> 2) + 4 * hi;
                    if (kvl > qr) p[r] = -3.0e38f;
                }
            }
            float tm = p[0];
            #pragma unroll
            for (int r = 1; r < 32; r++) tm = fmaxf(tm, p[r]);
            tm = fmaxf(tm, __shfl_xor(tm, 32));
            if (!__all(tm <= mrun + 8.f)) {
                const float mn = fmaxf(mrun, tm);
                const float al = __expf(mrun - mn);
                lrun *= al;
                #pragma unroll
                for (int i = 0; i < 16; i++) { Od0[i] *= al; Od1[i] *= al; }
                mrun = mn;
            }
            float ts = 0.f;
            #pragma unroll
            for (int r = 0; r < 32; r++) { p[r] = __expf(p[r] - mrun); ts += p[r]; }
            ts += __shfl_xor(ts, 32);
            lrun += ts;
            bf16x8 pbf[4];
            #pragma unroll
            for (int t = 0; t < 2; t++) {
                const unsigned pw0 = pk2(p[16*t+0],  p[16*t+1]),  pw1 = pk2(p[16*t+2],  p[16*t+3]);
                const unsigned pw2 = pk2(p[16*t+4],  p[16*t+5]),  pw3 = pk2(p[16*t+6],  p[16*t+7]);
                const unsigned pw4 = pk2(p[16*t+8],  p[16*t+9]),  pw5 = pk2(p[16*t+10], p[16*t+11]);
                const unsigned pw6 = pk2(p[16*t+12], p[16*t+13]), pw7 = pk2(p[16*t+14], p[16*t+15]);
                const unsigned px0 = __shfl_xor((int)pw0, 32), px1 = __shfl_xor((int)pw1, 32);
                const unsigned px2 = __shfl_xor((int)pw2, 32), px3 = __shfl_xor((int)pw3, 32);
                const unsigned px4 = __shfl_xor((int)pw4, 32), px5 = __shfl_xor((int)pw5, 32);
                const unsigned px6 = __shfl_xor((int)pw6, 32), px7 = __shfl_xor((int)pw7, 32);
                const u32x4 c0 = hi ? (u32x4){px2, px3, pw2, pw3} : (u32x4){pw0, pw1, px0, px1};
                const u32x4 c1 = hi ? (u32x4){px6, px7, pw6, pw7} : (u32x4){pw4, pw5, px4, px5};
                pbf[2*t]   = __builtin_bit_cast(bf16x8, c0);
                pbf[2*t+1] = __builtin_bit_cast(bf16x8, c1);
            }
            #pragma unroll
            for (int f = 0; f < 4; f++) {
                Od0 = MFMA32(vf0[f], pbf[f], Od0);
                Od1 = MFMA32(vf1[f], pbf[f], Od1);
            }
        }
        BAR();
        if (j + 2 < NP) { ASTG(j + 2, buf); VMC(4); }
        else            { VMC(0); }
        BAR();
    }

    const float inv = 1.0f / lrun;
    bf16* yr = y + (size_t)(b * T_ + qb + col) * D_ + h * HD_;
    #pragma unroll
    for (int rg = 0; rg < 4; rg++) {
        const int d0 = 8 * rg + 4 * hi;
        uint2 s0 = { pk2(Od0[4*rg] * inv, Od0[4*rg+1] * inv), pk2(Od0[4*rg+2] * inv, Od0[4*rg+3] * inv) };
        *(uint2*)(yr + d0) = s0;
        uint2 s1 = { pk2(Od1[4*rg] * inv, Od1[4*rg+1] * inv), pk2(Od1[4*rg+2] * inv, Od1[4*rg+3] * inv) };
        *(uint2*)(yr + 32 + d0) = s1;
    }
#undef ASTG
}

// ---------------- gate2 ----------------
__global__ __launch_bounds__(256) void gate2_kernel(float* __restrict__ x,
        const float* __restrict__ z,
        const float* __restrict__ p0, const float* __restrict__ p1,
        const float* __restrict__ p2, const float* __restrict__ p3,
        const float* __restrict__ src, const float* __restrict__ b2) {
    const long i = ((long)blockIdx.x * 256 + threadIdx.x) * 4;
    float4 xv = *(const float4*)(x + i);
    const float4 zv = *(const float4*)(z + i);
    const float4 a0 = *(const float4*)(p0 + i);
    const float4 a1 = *(const float4*)(p1 + i);
    const float4 a2 = *(const float4*)(p2 + i);
    const float4 a3 = *(const float4*)(p3 + i);
    const float4 sv = *(const float4*)(src + i);
    const float4 bb = *(const float4*)(b2 + (i & 1023));
    const float mx = a0.x + a1.x + a2.x + a3.x + bb.x;
    const float my = a0.y + a1.y + a2.y + a3.y + bb.y;
    const float mz = a0.z + a1.z + a2.z + a3.z + bb.z;
    const float mw = a0.w + a1.w + a2.w + a3.w + bb.w;
    xv.x = (1.f - zv.x) * xv.x + zv.x * mx + sv.x;
    xv.y = (1.f - zv.y) * xv.y + zv.y * my + sv.y;
    xv.z = (1.f - zv.z) * xv.z + zv.z * mz + sv.z;
    xv.w = (1.f - zv.w) * xv.w + zv.w * mw + sv.w;
    *(float4*)(x + i) = xv;
}

extern "C" void kernel_launch(void* const* d_in, const int* in_sizes, int n_in,
                              void* d_out, int out_size, void* d_ws, size_t ws_size,
                              hipStream_t stream) {
    const float* seq   = (const float*)d_in[0];
    const float* Wq    = (const float*)d_in[1];  const float* bq = (const float*)d_in[2];
    const float* Wk    = (const float*)d_in[3];  const float* bk = (const float*)d_in[4];
    const float* Wv    = (const float*)d_in[5];  const float* bv = (const float*)d_in[6];
    const float* Wo    = (const float*)d_in[7];  const float* bo = (const float*)d_in[8];
    const float* Wz    = (const float*)d_in[9];  const float* bz = (const float*)d_in[10];
    const float* Wr    = (const float*)d_in[11]; const float* br = (const float*)d_in[12];
    const float* W1    = (const float*)d_in[13]; const float* b1 = (const float*)d_in[14];
    const float* W2    = (const float*)d_in[15]; const float* b2 = (const float*)d_in[16];
    const float* ln1w  = (const float*)d_in[17]; const float* ln1b = (const float*)d_in[18];
    const float* ln2w  = (const float*)d_in[19]; const float* ln2b = (const float*)d_in[20];
    const float* lnfw  = (const float*)d_in[21]; const float* lnfb = (const float*)d_in[22];

    char* ws = (char*)d_ws;
    float* x   = (float*)(ws);                       // 16 MB
    float* z   = (float*)(ws + ((size_t)16 << 20));  // 16 MB
    float* r   = (float*)(ws + ((size_t)32 << 20));  // 16 MB (W2 partial 1)
    float* xa  = (float*)(ws + ((size_t)48 << 20));  // 16 MB (W2 partial 0)
    bf16*  xn  = (bf16*)(ws + ((size_t)64 << 20));   // 8 MB
    bf16*  qb_ = (bf16*)(ws + ((size_t)72 << 20));   // 8 MB
    bf16*  kb_ = (bf16*)(ws + ((size_t)80 << 20));   // 8 MB
    bf16*  vtb = (bf16*)(ws + ((size_t)88 << 20));   // 8 MB
    bf16*  yb  = (bf16*)(ws + ((size_t)96 << 20));   // 8 MB
    bf16*  h1  = (bf16*)(ws + ((size_t)104 << 20));  // 32 MB
    bf16*  wt  = (bf16*)(ws + ((size_t)136 << 20));  // 36 MB weight pool
    float* pt2 = (float*)(ws + ((size_t)172 << 20)); // 16 MB (W2 partial 2)
    float* pt3 = (float*)(ws + ((size_t)188 << 20)); // 16 MB (W2 partial 3)

    bf16* wto = wt + (5u << 20);
    bf16* wt1 = wt + (6u << 20);
    bf16* wt2 = wt + (10u << 20);

    hipMemcpyAsync(x, seq, (size_t)M_ * D_ * 4, hipMemcpyDeviceToDevice, stream);

    for (int i = 0; i < NL_; i++) {
        const long dd = (long)i * D_ * D_;
        wconv_all<<<14336, 256, 0, stream>>>(Wq + dd, Wk + dd, Wv + dd, Wz + dd,
                                             Wr + dd, Wo + dd,
                                             W1 + (long)i * D_ * DF_,
                                             W2 + (long)i * DF_ * D_, wt);
        ln_kernel<true><<<M_, 256, 0, stream>>>(x, ln1w + i * D_, ln1b + i * D_, xn);
        gemm5_k<<<640, 512, 0, stream>>>(xn, wt,
                bq + i * D_, bk + i * D_, bv + i * D_, bz + i * D_, br + i * D_,
                qb_, kb_, vtb, z, r);
        attn_kernel<<<512, 256, 0, stream>>>(qb_, kb_, vtb, yb);
        gemmWoG_kernel<<<256, 256, 0, stream>>>(yb, wto, bo + i * D_, x, z, r);
        ln_kernel<true><<<M_, 256, 0, stream>>>(x, ln2w + i * D_, ln2b + i * D_, xn);
        gemmG_k<<<512, 512, 0, stream>>>(xn, wt1, b1 + i * DF_, h1);
        gemmP_k<<<512, 512, 0, stream>>>(h1, wt2, xa, r, pt2, pt3);
        gate2_kernel<<<(M_ * D_) / 1024, 256, 0, stream>>>(x, z, xa, r, pt2, pt3, seq, b2 + i * D_);
    }
    ln_kernel<false><<<M_, 256, 0, stream>>>(x, lnfw, lnfb, d_out);
}

// Round 10
// 1760.854 us; speedup vs baseline: 2.6609x; 1.0180x over previous
//
#include <hip/hip_runtime.h>
#include <hip/hip_bf16.h>
#include <math.h>

#define B_ 2
#define T_ 2048
#define D_ 1024
#define H_ 16
#define NL_ 6
#define DF_ 4096
#define HD_ 64
#define M_ (B_*T_)

typedef __bf16 bf16;
typedef __attribute__((ext_vector_type(8))) __bf16 bf16x8;
typedef __attribute__((ext_vector_type(4))) float f32x4;
typedef __attribute__((ext_vector_type(16))) float f32x16;
typedef __attribute__((ext_vector_type(4))) unsigned u32x4;

#define BAR() __builtin_amdgcn_s_barrier()
#define LGKM0() asm volatile("s_waitcnt lgkmcnt(0)" ::: "memory")
#define VMC(n) asm volatile("s_waitcnt vmcnt(" #n ")" ::: "memory")

__device__ __forceinline__ void gload_lds16(const void* g, void* l) {
    __builtin_amdgcn_global_load_lds((const __attribute__((address_space(1))) void*)g,
                                     (__attribute__((address_space(3))) void*)l, 16, 0, 0);
}

__device__ __forceinline__ unsigned pk2(float a, float b) {
    bf16 lo = (bf16)a, hb = (bf16)b;
    return (unsigned)__builtin_bit_cast(unsigned short, lo) |
           ((unsigned)__builtin_bit_cast(unsigned short, hb) << 16);
}

// ---------------- LayerNorm ----------------
template<bool OUT_BF16>
__global__ __launch_bounds__(256) void ln_kernel(const float* __restrict__ x,
        const float* __restrict__ w, const float* __restrict__ b,
        void* __restrict__ out) {
    const int row = blockIdx.x;
    const int t = threadIdx.x;
    const float4 xv = *(const float4*)(x + (long)row * D_ + t * 4);
    float s  = xv.x + xv.y + xv.z + xv.w;
    float sq = xv.x*xv.x + xv.y*xv.y + xv.z*xv.z + xv.w*xv.w;
    #pragma unroll
    for (int m = 32; m; m >>= 1) { s += __shfl_xor(s, m); sq += __shfl_xor(sq, m); }
    __shared__ float red[8];
    const int wid = t >> 6, lid = t & 63;
    if (lid == 0) { red[wid] = s; red[wid + 4] = sq; }
    __syncthreads();
    s  = red[0] + red[1] + red[2] + red[3];
    sq = red[4] + red[5] + red[6] + red[7];
    const float mu   = s * (1.0f / D_);
    const float var  = sq * (1.0f / D_) - mu * mu;
    const float rstd = rsqrtf(var + 1e-5f);
    const float4 wv = *(const float4*)(w + t * 4);
    const float4 bv = *(const float4*)(b + t * 4);
    float o0 = (xv.x - mu) * rstd * wv.x + bv.x;
    float o1 = (xv.y - mu) * rstd * wv.y + bv.y;
    float o2 = (xv.z - mu) * rstd * wv.z + bv.z;
    float o3 = (xv.w - mu) * rstd * wv.w + bv.w;
    if (OUT_BF16) {
        bf16* o = (bf16*)out + (long)row * D_ + t * 4;
        o[0] = (bf16)o0; o[1] = (bf16)o1; o[2] = (bf16)o2; o[3] = (bf16)o3;
    } else {
        float* o = (float*)out + (long)row * D_ + t * 4;
        o[0] = o0; o[1] = o1; o[2] = o2; o[3] = o3;
    }
}

// ------------- merged weight convert+transpose for one layer -------------
__global__ __launch_bounds__(256) void wconv_all(
        const float* __restrict__ Wq, const float* __restrict__ Wk,
        const float* __restrict__ Wv, const float* __restrict__ Wz,
        const float* __restrict__ Wr, const float* __restrict__ Wo,
        const float* __restrict__ W1, const float* __restrict__ W2,
        bf16* __restrict__ wt) {
    __shared__ float s[32][33];
    const int bid = blockIdx.x;
    const float* src; bf16* dst; int t, K, nlg;
    if (bid < 6144) {
        const int m = bid >> 10; t = bid & 1023; K = 1024; nlg = 5;
        switch (m) {
            case 0: src = Wq; dst = wt; break;
            case 1: src = Wk; dst = wt + (1u << 20); break;
            case 2: src = Wv; dst = wt + (2u << 20); break;
            case 3: src = Wz; dst = wt + (3u << 20); break;
            case 4: src = Wr; dst = wt + (4u << 20); break;
            default: src = Wo; dst = wt + (5u << 20); break;
        }
    } else if (bid < 10240) {
        t = bid - 6144; K = 1024; nlg = 7; src = W1; dst = wt + (6u << 20);
    } else {
        t = bid - 10240; K = 4096; nlg = 5; src = W2; dst = wt + (10u << 20);
    }
    const int N = 1 << (nlg + 5);
    const int k0 = (t >> nlg) * 32, n0 = (t & ((1 << nlg) - 1)) * 32;
    const int c = threadIdx.x & 31, r8 = threadIdx.x >> 5;
    #pragma unroll
    for (int it = 0; it < 4; it++)
        s[r8 + it*8][c] = src[(long)(k0 + r8 + it*8) * N + n0 + c];
    __syncthreads();
    #pragma unroll
    for (int it = 0; it < 4; it++)
        dst[(long)(n0 + r8 + it*8) * K + k0 + c] = (bf16)s[c][r8 + it*8];
}

// =============== 256x128 GEMM core v3 (BK=32, 8 waves, 48 KiB LDS, 2 BAR/kt) ===============
#define MFMA16(a, b, c) __builtin_amdgcn_mfma_f32_16x16x32_bf16(a, b, c, 0, 0, 0)
#define MFMA32(a, b, c) __builtin_amdgcn_mfma_f32_32x32x16_bf16(a, b, c, 0, 0, 0)

__device__ __forceinline__ void gemm128_core(const bf16* __restrict__ A, const bf16* __restrict__ Bt,
        const int Ks, const int NT, const int m0, const int n0, char* lds, f32x4 (&acc)[4][4]) {
    const int tid = threadIdx.x;
    const int lane = tid & 63, w = tid >> 6;
    const int wm = w >> 1, wn = w & 1;
    const int cl = lane & 15, gl = lane >> 4;
    const int srow = lane >> 2;
    const int sxc = (((lane & 3) ^ ((lane >> 3) & 3)) << 3);   // chunk ^= (row>>1)&3
    const bf16* pa0 = A  + (size_t)(m0 + w * 32 + srow) * Ks + sxc;
    const bf16* pa1 = pa0 + (size_t)16 * Ks;
    const bf16* pb  = Bt + (size_t)(n0 + w * 16 + srow) * Ks + sxc;
    char* laA = lds + w * 2048;
    char* laB = lds + 32768 + w * 1024;

#define STG(KT, BUF) do { \
    gload_lds16(pa0 + (size_t)(KT) * 32, laA + (BUF) * 16384); \
    gload_lds16(pa1 + (size_t)(KT) * 32, laA + (BUF) * 16384 + 1024); \
    gload_lds16(pb  + (size_t)(KT) * 32, laB + (BUF) * 8192); } while (0)

    STG(0, 0); STG(1, 1);
    VMC(3);

    const int xo  = ((gl ^ ((cl >> 1) & 3)) << 4);
    const int rdA = (wm * 64 + cl) * 64 + xo;
    const int rdB = (wn * 64 + cl) * 64 + xo;

    for (int kt = 0; kt < NT; ++kt) {
        const int buf = kt & 1;
        const char* sA = lds + buf * 16384;
        const char* sB = lds + 32768 + buf * 8192;
        BAR();                                   // buf[kt&1] staged (VMC at prev iter end)
        bf16x8 a[4], b[4];
        #pragma unroll
        for (int mi = 0; mi < 4; mi++) a[mi] = *(const bf16x8*)(sA + rdA + mi * 1024);
        #pragma unroll
        for (int ni = 0; ni < 4; ni++) b[ni] = *(const bf16x8*)(sB + rdB + ni * 1024);
        LGKM0();
        BAR();                                   // all waves' reads retired -> safe to restage
        if (kt + 2 < NT) STG(kt + 2, buf);
        __builtin_amdgcn_s_setprio(1);
        #pragma unroll
        for (int mi = 0; mi < 4; mi++)
            #pragma unroll
            for (int ni = 0; ni < 4; ni++)
                acc[mi][ni] = MFMA16(a[mi], b[ni], acc[mi][ni]);
        __builtin_amdgcn_s_setprio(0);
        if (kt + 2 < NT)      { VMC(3); }
        else if (kt + 1 < NT) { VMC(0); }
    }
#undef STG
}

// ---- gemm5: xn[4096,1024] @ wt[5120,1024]^T, segmented epilogue. grid 640 ----
__global__ __launch_bounds__(512, 4) void gemm5_k(const bf16* __restrict__ A, const bf16* __restrict__ Bt,
        const float* __restrict__ bq, const float* __restrict__ bk, const float* __restrict__ bvv,
        const float* __restrict__ bz, const float* __restrict__ br,
        bf16* __restrict__ oq, bf16* __restrict__ ok, bf16* __restrict__ ov,
        float* __restrict__ oz, float* __restrict__ orr) {
    __shared__ __align__(16) char lds[49152];
    int bid = blockIdx.x;
    bid = (bid & 7) * 80 + (bid >> 3);
    const int m0 = (bid / 40) * 256, n0 = (bid % 40) * 128;
    f32x4 acc[4][4];
    #pragma unroll
    for (int i = 0; i < 4; i++)
        #pragma unroll
        for (int j = 0; j < 4; j++) acc[i][j] = (f32x4){0.f, 0.f, 0.f, 0.f};
    gemm128_core(A, Bt, 1024, 32, m0, n0, lds, acc);
    const int tid = threadIdx.x, lane = tid & 63, w = tid >> 6;
    const int wm = w >> 1, wn = w & 1, cl = lane & 15, gl = lane >> 4;
    const int seg = n0 >> 10;
    const int lc0 = (n0 & 1023) + wn * 64;
    const float* bias; int mode; void* outp;
    switch (seg) {
        case 0:  bias = bq;  mode = 0; outp = oq;  break;
        case 1:  bias = bk;  mode = 0; outp = ok;  break;
        case 2:  bias = bvv; mode = 1; outp = ov;  break;
        case 3:  bias = bz;  mode = 2; outp = oz;  break;
        default: bias = br;  mode = 2; outp = orr; break;
    }
    const float scl = (seg == 0) ? 0.125f : 1.0f;   // pre-scale Q for attention
    #pragma unroll
    for (int mi = 0; mi < 4; mi++) {
        #pragma unroll
        for (int ni = 0; ni < 4; ni++) {
            const int lcol = lc0 + ni * 16 + cl;
            const float bv = bias[lcol];
            #pragma unroll
            for (int r = 0; r < 4; r++) {
                const int row = m0 + wm * 64 + mi * 16 + gl * 4 + r;
                const float v = (acc[mi][ni][r] + bv) * scl;
                if (mode == 0) {
                    ((bf16*)outp)[(long)row * 1024 + lcol] = (bf16)v;
                } else if (mode == 1) {
                    ((bf16*)outp)[((long)(row >> 11) * 1024 + lcol) * T_ + (row & 2047)] = (bf16)v;
                } else {
                    ((float*)outp)[(long)row * 1024 + lcol] = 1.0f / (1.0f + __expf(-v));
                }
            }
        }
    }
}

// ---- W1: gelu -> bf16 h1. grid 512 ----
__global__ __launch_bounds__(512, 4) void gemmG_k(const bf16* __restrict__ A, const bf16* __restrict__ Bt,
        const float* __restrict__ bias, bf16* __restrict__ out) {
    __shared__ __align__(16) char lds[49152];
    int bid = blockIdx.x;
    bid = (bid & 7) * 64 + (bid >> 3);
    const int m0 = (bid >> 5) * 256, n0 = (bid & 31) * 128;
    f32x4 acc[4][4];
    #pragma unroll
    for (int i = 0; i < 4; i++)
        #pragma unroll
        for (int j = 0; j < 4; j++) acc[i][j] = (f32x4){0.f, 0.f, 0.f, 0.f};
    gemm128_core(A, Bt, 1024, 32, m0, n0, lds, acc);
    const int tid = threadIdx.x, lane = tid & 63, w = tid >> 6;
    const int wm = w >> 1, wn = w & 1, cl = lane & 15, gl = lane >> 4;
    #pragma unroll
    for (int mi = 0; mi < 4; mi++) {
        #pragma unroll
        for (int ni = 0; ni < 4; ni++) {
            const int col = n0 + wn * 64 + ni * 16 + cl;
            const float bv = bias[col];
            #pragma unroll
            for (int r = 0; r < 4; r++) {
                const int row = m0 + wm * 64 + mi * 16 + gl * 4 + r;
                float v = acc[mi][ni][r] + bv;
                v = 0.5f * v * (1.0f + erff(v * 0.70710678118f));
                out[(long)row * DF_ + col] = (bf16)v;
            }
        }
    }
}

// ---- W2 split-K=4: h1[4096,4096] @ wt2[1024,4096]^T -> 4 f32 partials. grid 512 ----
// (reverted to round-8 decomposition: mt=bid>>5 in [0,16), s=(bid>>3)&3, ntl=bid&7)
__global__ __launch_bounds__(512, 4) void gemmP_k(const bf16* __restrict__ A, const bf16* __restrict__ Bt,
        float* __restrict__ p0, float* __restrict__ p1, float* __restrict__ p2, float* __restrict__ p3) {
    __shared__ __align__(16) char lds[49152];
    int bid = blockIdx.x;
    bid = (bid & 7) * 64 + (bid >> 3);
    const int mt = bid >> 5, s = (bid >> 3) & 3, ntl = bid & 7;
    const int m0 = mt * 256, n0 = ntl * 128;
    f32x4 acc[4][4];
    #pragma unroll
    for (int i = 0; i < 4; i++)
        #pragma unroll
        for (int j = 0; j < 4; j++) acc[i][j] = (f32x4){0.f, 0.f, 0.f, 0.f};
    gemm128_core(A + s * 1024, Bt + s * 1024, 4096, 32, m0, n0, lds, acc);
    float* outp = (s == 0) ? p0 : (s == 1) ? p1 : (s == 2) ? p2 : p3;
    const int tid = threadIdx.x, lane = tid & 63, w = tid >> 6;
    const int wm = w >> 1, wn = w & 1, cl = lane & 15, gl = lane >> 4;
    #pragma unroll
    for (int mi = 0; mi < 4; mi++) {
        #pragma unroll
        for (int ni = 0; ni < 4; ni++) {
            const int col = n0 + wn * 64 + ni * 16 + cl;
            #pragma unroll
            for (int r = 0; r < 4; r++) {
                const int row = m0 + wm * 64 + mi * 16 + gl * 4 + r;
                outp[(long)row * 1024 + col] = acc[mi][ni][r];
            }
        }
    }
}

// ---------------- Wo GEMM with fused gate1 epilogue (128^2) ----------------
__global__ __launch_bounds__(256) void gemmWoG_kernel(const bf16* __restrict__ A,
        const bf16* __restrict__ Bt, const float* __restrict__ bias,
        float* __restrict__ x, const float* __restrict__ z, const float* __restrict__ rr) {
    __shared__ bf16 sA[128 * 32];
    __shared__ bf16 sB[128 * 32];
    const int tid = threadIdx.x;
    int bid = blockIdx.x;
    bid = (bid & 7) * 32 + (bid >> 3);
    const int m0 = (bid >> 3) * 128, n0 = (bid & 7) * 128;
    f32x4 acc[4][4];
    #pragma unroll
    for (int i = 0; i < 4; i++)
        #pragma unroll
        for (int j = 0; j < 4; j++) acc[i][j] = (f32x4){0.f, 0.f, 0.f, 0.f};
    const int lane = tid & 63, w = tid >> 6;
    const int wr = (w >> 1) * 64, wc = (w & 1) * 64;
    const int cl = lane & 15, gl = lane >> 4;
    const int srow = tid >> 2;
    const int skoff = (((tid & 3) ^ ((tid >> 3) & 3)) << 3);
    const bf16* ga = A  + (long)(m0 + srow) * D_ + skoff;
    const bf16* gb = Bt + (long)(n0 + srow) * D_ + skoff;
    char* sAc = (char*)sA;
    char* sBc = (char*)sB;
    const int wb = w * 1024;
    const int xo = ((gl ^ ((cl >> 1) & 3)) << 4);
    for (int k0 = 0; k0 < D_; k0 += 32) {
        if (k0) __syncthreads();
        gload_lds16(ga + k0,            sAc + wb);
        gload_lds16(ga + 64 * D_ + k0,  sAc + 4096 + wb);
        gload_lds16(gb + k0,            sBc + wb);
        gload_lds16(gb + 64 * D_ + k0,  sBc + 4096 + wb);
        __syncthreads();
        bf16x8 af[4], bfr[4];
        #pragma unroll
        for (int i = 0; i < 4; i++) af[i]  = *(const bf16x8*)(sAc + (wr + i*16 + cl) * 64 + xo);
        #pragma unroll
        for (int j = 0; j < 4; j++) bfr[j] = *(const bf16x8*)(sBc + (wc + j*16 + cl) * 64 + xo);
        #pragma unroll
        for (int i = 0; i < 4; i++)
            #pragma unroll
            for (int j = 0; j < 4; j++)
                acc[i][j] = MFMA16(af[i], bfr[j], acc[i][j]);
    }
    #pragma unroll
    for (int i = 0; i < 4; i++) {
        #pragma unroll
        for (int j = 0; j < 4; j++) {
            const int gcol = n0 + wc + j * 16 + cl;
            const float bv = bias[gcol];
            #pragma unroll
            for (int r = 0; r < 4; r++) {
                const int grow = m0 + wr + i * 16 + gl * 4 + r;
                const long idx = (long)grow * D_ + gcol;
                const float xa = acc[i][j][r] + bv;
                const float zv = z[idx];
                const float ht = tanhf(rr[idx] * xa);
                x[idx] = (1.f - zv) * x[idx] + zv * ht;
            }
        }
    }
}

// ======= Flash attention v2 (unchanged) =======
__global__ __launch_bounds__(256, 2) void attn_kernel(const bf16* __restrict__ q,
        const bf16* __restrict__ k, const bf16* __restrict__ vT,
        bf16* __restrict__ y) {
    __shared__ __align__(16) char lds[32768];
    const int tid = threadIdx.x, wid = tid >> 6, lane = tid & 63;
    const int col = lane & 31, hi = lane >> 5;
    const int bid = blockIdx.x;
    const int xcd = bid & 7, idx = bid >> 3;
    const int bh = xcd + 8 * (idx & 3);
    const int sg = idx >> 2;
    const int g = (sg & 1) ? (sg >> 1) : (15 - (sg >> 1));
    const int qt = 4 * g + wid;
    const int qb = qt * 32;
    const int b = bh >> 4, h = bh & 15;
    const int NP = 2 * g + 2;
    const int nt64 = (qt >> 1) + 1;

    const bf16* qB = q  + (size_t)b * T_ * D_ + h * HD_;
    const bf16* kB = k  + (size_t)b * T_ * D_ + h * HD_;
    const bf16* vB = vT + (size_t)b * D_ * T_ + (size_t)h * HD_ * T_;

    const int sr = wid * 8 + (lane >> 3);
    const int sc = lane & 7;
    const bf16* kS0 = kB + (size_t)sr * D_ + 8 * (sc ^ (sr & 7));
    const bf16* kS1 = kS0 + (size_t)32 * D_;
    const bf16* vS0 = vB + (size_t)sr * T_ + 8 * (sc ^ (sr & 7));
    const bf16* vS1 = vS0 + (size_t)32 * T_;
    char* dK = lds + wid * 1024;
    char* dV = lds + 16384 + wid * 1024;

#define ASTG(J, BUF) do { \
    const size_t ko_ = (size_t)(J) * 64 * D_; \
    const size_t vo_ = (size_t)(J) * 64; \
    gload_lds16(kS0 + ko_, dK + (BUF) * 8192); \
    gload_lds16(kS1 + ko_, dK + (BUF) * 8192 + 4096); \
    gload_lds16(vS0 + vo_, dV + (BUF) * 8192); \
    gload_lds16(vS1 + vo_, dV + (BUF) * 8192 + 4096); } while (0)

    bf16x8 qf0, qf1, qf2, qf3;
    {
        const bf16* qp = qB + (size_t)(qb + col) * D_ + 8 * hi;
        qf0 = *(const bf16x8*)(qp);
        qf1 = *(const bf16x8*)(qp + 16);
        qf2 = *(const bf16x8*)(qp + 32);
        qf3 = *(const bf16x8*)(qp + 48);
    }

    f32x16 Od0, Od1;
    #pragma unroll
    for (int i = 0; i < 16; i++) { Od0[i] = 0.f; Od1[i] = 0.f; }
    float mrun = -INFINITY, lrun = 0.f;

    ASTG(0, 0);
    ASTG(1, 1);
    VMC(4);
    BAR();

    const int swz = col & 7;
    for (int j = 0; j < NP; ++j) {
        const int buf = j & 1;
        if (j < nt64) {
            const char* bK = lds + buf * 8192;
            const char* bV = lds + 16384 + buf * 8192;
            bf16x8 kf0[4], kf1[4], vf0[4], vf1[4];
            #pragma unroll
            for (int cs = 0; cs < 4; cs++) {
                const int ch = ((hi + 2 * cs) ^ swz) * 16;
                kf0[cs] = *(const bf16x8*)(bK + col * 128 + ch);
                kf1[cs] = *(const bf16x8*)(bK + (col + 32) * 128 + ch);
                vf0[cs] = *(const bf16x8*)(bV + col * 128 + ch);
                vf1[cs] = *(const bf16x8*)(bV + (col + 32) * 128 + ch);
            }
            f32x16 S0, S1;
            #pragma unroll
            for (int i = 0; i < 16; i++) { S0[i] = 0.f; S1[i] = 0.f; }
            S0 = MFMA32(kf0[0], qf0, S0); S0 = MFMA32(kf0[1], qf1, S0);
            S0 = MFMA32(kf0[2], qf2, S0); S0 = MFMA32(kf0[3], qf3, S0);
            S1 = MFMA32(kf1[0], qf0, S1); S1 = MFMA32(kf1[1], qf1, S1);
            S1 = MFMA32(kf1[2], qf2, S1); S1 = MFMA32(kf1[3], qf3, S1);
            float p[32];
            #pragma unroll
            for (int r = 0; r < 16; r++) { p[r] = S0[r]; p[16 + r] = S1[r]; }
            if (j == nt64 - 1) {
                const int qr = qb + col;
                #pragma unroll
                for (int r = 0; r < 32; r++) {
                    const int kvl = 64 * j + 32 * (r >> 4)
                                  + (r & 3) + 8 * ((r & 15) >> 2) + 4 * hi;
                    if (kvl > qr) p[r] = -3.0e38f;
                }
            }
            float tm = p[0];
            #pragma unroll
            for (int r = 1; r < 32; r++) tm = fmaxf(tm, p[r]);
            tm = fmaxf(tm, __shfl_xor(tm, 32));
            if (!__all(tm <= mrun + 8.f)) {
                const float mn = fmaxf(mrun, tm);
                const float al = __expf(mrun - mn);
                lrun *= al;
                #pragma unroll
                for (int i = 0; i < 16; i++) { Od0[i] *= al; Od1[i] *= al; }
                mrun = mn;
            }
            float ts = 0.f;
            #pragma unroll
            for (int r = 0; r < 32; r++) { p[r] = __expf(p[r] - mrun); ts += p[r]; }
            ts += __shfl_xor(ts, 32);
            lrun += ts;
            bf16x8 pbf[4];
            #pragma unroll
            for (int t = 0; t < 2; t++) {
                const unsigned pw0 = pk2(p[16*t+0],  p[16*t+1]),  pw1 = pk2(p[16*t+2],  p[16*t+3]);
                const unsigned pw2 = pk2(p[16*t+4],  p[16*t+5]),  pw3 = pk2(p[16*t+6],  p[16*t+7]);
                const unsigned pw4 = pk2(p[16*t+8],  p[16*t+9]),  pw5 = pk2(p[16*t+10], p[16*t+11]);
                const unsigned pw6 = pk2(p[16*t+12], p[16*t+13]), pw7 = pk2(p[16*t+14], p[16*t+15]);
                const unsigned px0 = __shfl_xor((int)pw0, 32), px1 = __shfl_xor((int)pw1, 32);
                const unsigned px2 = __shfl_xor((int)pw2, 32), px3 = __shfl_xor((int)pw3, 32);
                const unsigned px4 = __shfl_xor((int)pw4, 32), px5 = __shfl_xor((int)pw5, 32);
                const unsigned px6 = __shfl_xor((int)pw6, 32), px7 = __shfl_xor((int)pw7, 32);
                const u32x4 c0 = hi ? (u32x4){px2, px3, pw2, pw3} : (u32x4){pw0, pw1, px0, px1};
                const u32x4 c1 = hi ? (u32x4){px6, px7, pw6, pw7} : (u32x4){pw4, pw5, px4, px5};
                pbf[2*t]   = __builtin_bit_cast(bf16x8, c0);
                pbf[2*t+1] = __builtin_bit_cast(bf16x8, c1);
            }
            #pragma unroll
            for (int f = 0; f < 4; f++) {
                Od0 = MFMA32(vf0[f], pbf[f], Od0);
                Od1 = MFMA32(vf1[f], pbf[f], Od1);
            }
        }
        BAR();
        if (j + 2 < NP) { ASTG(j + 2, buf); VMC(4); }
        else            { VMC(0); }
        BAR();
    }

    const float inv = 1.0f / lrun;
    bf16* yr = y + (size_t)(b * T_ + qb + col) * D_ + h * HD_;
    #pragma unroll
    for (int rg = 0; rg < 4; rg++) {
        const int d0 = 8 * rg + 4 * hi;
        uint2 s0 = { pk2(Od0[4*rg] * inv, Od0[4*rg+1] * inv), pk2(Od0[4*rg+2] * inv, Od0[4*rg+3] * inv) };
        *(uint2*)(yr + d0) = s0;
        uint2 s1 = { pk2(Od1[4*rg] * inv, Od1[4*rg+1] * inv), pk2(Od1[4*rg+2] * inv, Od1[4*rg+3] * inv) };
        *(uint2*)(yr + 32 + d0) = s1;
    }
#undef ASTG
}

// ---------------- gate2 (4 partials) + optional fused ln1 of next layer ----------------
template<bool LN>
__global__ __launch_bounds__(256) void gate2ln_kernel(float* __restrict__ x,
        const float* __restrict__ z,
        const float* __restrict__ p0, const float* __restrict__ p1,
        const float* __restrict__ p2, const float* __restrict__ p3,
        const float* __restrict__ src, const float* __restrict__ b2,
        const float* __restrict__ lw, const float* __restrict__ lb,
        bf16* __restrict__ xn) {
    const int row = blockIdx.x, t = threadIdx.x;
    const long i = (long)row * D_ + t * 4;
    float4 xv = *(const float4*)(x + i);
    const float4 zv = *(const float4*)(z + i);
    const float4 a0 = *(const float4*)(p0 + i);
    const float4 a1 = *(const float4*)(p1 + i);
    const float4 a2 = *(const float4*)(p2 + i);
    const float4 a3 = *(const float4*)(p3 + i);
    const float4 sv = *(const float4*)(src + i);
    const float4 bb = *(const float4*)(b2 + t * 4);
    xv.x = (1.f - zv.x) * xv.x + zv.x * (a0.x + a1.x + a2.x + a3.x + bb.x) + sv.x;
    xv.y = (1.f - zv.y) * xv.y + zv.y * (a0.y + a1.y + a2.y + a3.y + bb.y) + sv.y;
    xv.z = (1.f - zv.z) * xv.z + zv.z * (a0.z + a1.z + a2.z + a3.z + bb.z) + sv.z;
    xv.w = (1.f - zv.w) * xv.w + zv.w * (a0.w + a1.w + a2.w + a3.w + bb.w) + sv.w;
    *(float4*)(x + i) = xv;
    if (LN) {
        float s  = xv.x + xv.y + xv.z + xv.w;
        float sq = xv.x*xv.x + xv.y*xv.y + xv.z*xv.z + xv.w*xv.w;
        #pragma unroll
        for (int m = 32; m; m >>= 1) { s += __shfl_xor(s, m); sq += __shfl_xor(sq, m); }
        __shared__ float red[8];
        const int wid = t >> 6, lid = t & 63;
        if (lid == 0) { red[wid] = s; red[wid + 4] = sq; }
        __syncthreads();
        s  = red[0] + red[1] + red[2] + red[3];
        sq = red[4] + red[5] + red[6] + red[7];
        const float mu   = s * (1.0f / D_);
        const float var  = sq * (1.0f / D_) - mu * mu;
        const float rstd = rsqrtf(var + 1e-5f);
        const float4 wv = *(const float4*)(lw + t * 4);
        const float4 bv = *(const float4*)(lb + t * 4);
        bf16* o = xn + i;
        o[0] = (bf16)((xv.x - mu) * rstd * wv.x + bv.x);
        o[1] = (bf16)((xv.y - mu) * rstd * wv.y + bv.y);
        o[2] = (bf16)((xv.z - mu) * rstd * wv.z + bv.z);
        o[3] = (bf16)((xv.w - mu) * rstd * wv.w + bv.w);
    }
}

extern "C" void kernel_launch(void* const* d_in, const int* in_sizes, int n_in,
                              void* d_out, int out_size, void* d_ws, size_t ws_size,
                              hipStream_t stream) {
    const float* seq   = (const float*)d_in[0];
    const float* Wq    = (const float*)d_in[1];  const float* bq = (const float*)d_in[2];
    const float* Wk    = (const float*)d_in[3];  const float* bk = (const float*)d_in[4];
    const float* Wv    = (const float*)d_in[5];  const float* bv = (const float*)d_in[6];
    const float* Wo    = (const float*)d_in[7];  const float* bo = (const float*)d_in[8];
    const float* Wz    = (const float*)d_in[9];  const float* bz = (const float*)d_in[10];
    const float* Wr    = (const float*)d_in[11]; const float* br = (const float*)d_in[12];
    const float* W1    = (const float*)d_in[13]; const float* b1 = (const float*)d_in[14];
    const float* W2    = (const float*)d_in[15]; const float* b2 = (const float*)d_in[16];
    const float* ln1w  = (const float*)d_in[17]; const float* ln1b = (const float*)d_in[18];
    const float* ln2w  = (const float*)d_in[19]; const float* ln2b = (const float*)d_in[20];
    const float* lnfw  = (const float*)d_in[21]; const float* lnfb = (const float*)d_in[22];

    char* ws = (char*)d_ws;
    float* x   = (float*)(ws);                       // 16 MB
    float* z   = (float*)(ws + ((size_t)16 << 20));  // 16 MB
    float* r   = (float*)(ws + ((size_t)32 << 20));  // 16 MB (W2 partial 1)
    float* xa  = (float*)(ws + ((size_t)48 << 20));  // 16 MB (W2 partial 0)
    bf16*  xn  = (bf16*)(ws + ((size_t)64 << 20));   // 8 MB
    bf16*  qb_ = (bf16*)(ws + ((size_t)72 << 20));   // 8 MB
    bf16*  kb_ = (bf16*)(ws + ((size_t)80 << 20));   // 8 MB
    bf16*  vtb = (bf16*)(ws + ((size_t)88 << 20));   // 8 MB
    bf16*  yb  = (bf16*)(ws + ((size_t)96 << 20));   // 8 MB
    bf16*  h1  = (bf16*)(ws + ((size_t)104 << 20));  // 32 MB
    bf16*  wt  = (bf16*)(ws + ((size_t)136 << 20));  // 36 MB weight pool
    float* pt2 = (float*)(ws + ((size_t)172 << 20)); // 16 MB (W2 partial 2)
    float* pt3 = (float*)(ws + ((size_t)188 << 20)); // 16 MB (W2 partial 3)

    bf16* wto = wt + (5u << 20);
    bf16* wt1 = wt + (6u << 20);
    bf16* wt2 = wt + (10u << 20);

    hipMemcpyAsync(x, seq, (size_t)M_ * D_ * 4, hipMemcpyDeviceToDevice, stream);

    for (int i = 0; i < NL_; i++) {
        const long dd = (long)i * D_ * D_;
        wconv_all<<<14336, 256, 0, stream>>>(Wq + dd, Wk + dd, Wv + dd, Wz + dd,
                                             Wr + dd, Wo + dd,
                                             W1 + (long)i * D_ * DF_,
                                             W2 + (long)i * DF_ * D_, wt);
        if (i == 0)
            ln_kernel<true><<<M_, 256, 0, stream>>>(x, ln1w, ln1b, xn);
        gemm5_k<<<640, 512, 0, stream>>>(xn, wt,
                bq + i * D_, bk + i * D_, bv + i * D_, bz + i * D_, br + i * D_,
                qb_, kb_, vtb, z, r);
        attn_kernel<<<512, 256, 0, stream>>>(qb_, kb_, vtb, yb);
        gemmWoG_kernel<<<256, 256, 0, stream>>>(yb, wto, bo + i * D_, x, z, r);
        ln_kernel<true><<<M_, 256, 0, stream>>>(x, ln2w + i * D_, ln2b + i * D_, xn);
        gemmG_k<<<512, 512, 0, stream>>>(xn, wt1, b1 + i * DF_, h1);
        gemmP_k<<<512, 512, 0, stream>>>(h1, wt2, xa, r, pt2, pt3);
        if (i + 1 < NL_)
            gate2ln_kernel<true><<<M_, 256, 0, stream>>>(x, z, xa, r, pt2, pt3, seq, b2 + i * D_,
                    ln1w + (i + 1) * D_, ln1b + (i + 1) * D_, xn);
        else
            gate2ln_kernel<false><<<M_, 256, 0, stream>>>(x, z, xa, r, pt2, pt3, seq, b2 + i * D_,
                    nullptr, nullptr, nullptr);
    }
    ln_kernel<false><<<M_, 256, 0, stream>>>(x, lnfw, lnfb, d_out);
}